// Round 3
// baseline (4147.465 us; speedup 1.0000x reference)
//
#include <hip/hip_runtime.h>
#include <cstdint>
#include <cstddef>

#define TT 128
#define HID 256
#define GG4 1024
#define GG3 768
#define MAXLV 64
#define NBS 32   // lstm blocks per direction

__device__ __forceinline__ float sigf(float x){ return 1.f/(1.f+__expf(-x)); }
__device__ __forceinline__ float tanh_(float x){
  float cx = fminf(fmaxf(x,-15.f),15.f);
  float e = __expf(2.f*cx);
  return (e-1.f)/(e+1.f);
}

// Inter-block barrier (tree kernel): fresh zeroed counter per use, bounded spin.
__device__ __forceinline__ void grp_barrier(int* cnt, int expected){
  __syncthreads();
  if (threadIdx.x == 0){
    __hip_atomic_fetch_add(cnt, 1, __ATOMIC_ACQ_REL, __HIP_MEMORY_SCOPE_AGENT);
    long it = 0;
    while (__hip_atomic_load(cnt, __ATOMIC_RELAXED, __HIP_MEMORY_SCOPE_AGENT) < expected){
      __builtin_amdgcn_s_sleep(1);
      if (++it > 60000000L) break;
    }
    __builtin_amdgcn_fence(__ATOMIC_ACQUIRE, "agent");
  }
  __syncthreads();
}

// ---------------- embedding gather: x[m][e] = emb[ids[m]][e] ----------------
__global__ __launch_bounds__(256) void gather_x_kernel(
    const int* __restrict__ ids, const float* __restrict__ emb, float* __restrict__ x)
{
  int it = blockIdx.x*256 + threadIdx.x;        // item = m*75 + q  (300 = 75 float4)
  if (it >= 8192*75) return;
  int m = it / 75, q = (it % 75) * 4;
  int id = ids[m];
  *(float4*)&x[(size_t)m*300 + q] = *(const float4*)&emb[(size_t)id*300 + q];
}

// ---------------- tiled GEMM 128x64, 8x4/thread: C[m][n] = A[m]·W[n] (+bias) -
// PERM: out row = (m%128)*64 + m/128   (lay xg out as [t][b][gates])
template<bool PERM, bool BIAS>
__global__ __launch_bounds__(256) void gemm_kernel(
    const float* __restrict__ A, const float* __restrict__ W,
    const float* __restrict__ bias, float* __restrict__ C,
    int M, int Nn, int K)
{
  __shared__ float As[16][128];
  __shared__ float Ws[16][64];
  const int tid = threadIdx.x;
  const int m0 = blockIdx.x * 128, n0 = blockIdx.y * 64;
  const int tx = tid & 15, ty = tid >> 4;       // out cols tx*4, rows ty*8
  const int arow = tid >> 1, akof = (tid & 1) << 3;   // A stage: 2 float4
  const int wrow = tid >> 2, wkof = (tid & 3) << 2;   // W stage: 1 float4
  float acc[8][4] = {};
  for (int k0 = 0; k0 < K; k0 += 16) {
    float a_[8], w_[4];
    {
      const int gm = m0 + arow;
#pragma unroll
      for (int j = 0; j < 8; j++) {
        const int kk = k0 + akof + j;
        a_[j] = (gm < M && kk < K) ? A[(size_t)gm*K + kk] : 0.f;
      }
      const int gn = n0 + wrow;
#pragma unroll
      for (int j = 0; j < 4; j++) {
        const int kk = k0 + wkof + j;
        w_[j] = (gn < Nn && kk < K) ? W[(size_t)gn*K + kk] : 0.f;
      }
    }
    __syncthreads();
#pragma unroll
    for (int j = 0; j < 8; j++) As[akof + j][arow] = a_[j];
#pragma unroll
    for (int j = 0; j < 4; j++) Ws[wkof + j][wrow] = w_[j];
    __syncthreads();
#pragma unroll
    for (int k = 0; k < 16; k++) {
      const float4 b  = *(const float4*)&Ws[k][tx << 2];
      const float4 a0 = *(const float4*)&As[k][ty << 3];
      const float4 a1 = *(const float4*)&As[k][(ty << 3) + 4];
      const float av[8] = {a0.x,a0.y,a0.z,a0.w,a1.x,a1.y,a1.z,a1.w};
      const float bv[4] = {b.x,b.y,b.z,b.w};
#pragma unroll
      for (int i = 0; i < 8; i++)
#pragma unroll
        for (int j = 0; j < 4; j++) acc[i][j] += av[i]*bv[j];
    }
  }
  float4 bv4 = make_float4(0,0,0,0);
  if (BIAS) bv4 = *(const float4*)&bias[n0 + (tx<<2)];
#pragma unroll
  for (int i = 0; i < 8; i++) {
    int gm = m0 + (ty<<3) + i;
    if (gm >= M) continue;
    int orow = PERM ? (((gm & 127) << 6) | (gm >> 7)) : gm;
    float4 o = make_float4(acc[i][0]+bv4.x, acc[i][1]+bv4.y, acc[i][2]+bv4.z, acc[i][3]+bv4.w);
    *(float4*)&C[(size_t)orow*Nn + n0 + (tx<<2)] = o;
  }
}

// ---------------- bidirectional LSTM recurrence ------------------------------
// 64 blocks: dir = blk>>5, slice = blk&31 owns 8 hidden units.
// h exchange buffers TRANSPOSED: hT[slab][k][r] (k = hidden unit, r = batch).
// fwd: read slab t, write slab t+1 (slab0 = 0). bwd: read slab t+1, write t.
// Sync: per-block flag (padded line), wave0 polls all 32 flags in parallel.
__global__ __launch_bounds__(256) void lstm_kernel(
    const float* __restrict__ xgf, const float* __restrict__ xgb,
    const float* __restrict__ whhf, const float* __restrict__ whhb,
    const int* __restrict__ lengths,
    float* __restrict__ hTf, float* __restrict__ hTb,
    int* __restrict__ flags)
{
  const int dir = blockIdx.x >> 5;
  const int sl  = blockIdx.x & 31;
  const float* __restrict__ xg  = dir ? xgb : xgf;
  const float* __restrict__ whh = dir ? whhb : whhf;
  float* __restrict__ hT = dir ? hTb : hTf;
  int* fbase  = flags + dir * (NBS * 32);      // 32 ints (128B) per flag
  int* myflag = fbase + sl * 32;
  const int tid = threadIdx.x;
  const int r  = tid & 63;          // batch row = lane
  const int u2 = tid >> 6;          // 0..3 (wave-uniform)
  const int u0 = sl << 3;
  const int ua = u0 + (u2 << 1);    // first of this thread's 2 units

  extern __shared__ float smem[];   // wl[32*256] (32KB) + hs[256*64] (64KB)
  float* wl = smem;
  float* hs = smem + 32*256;

  for (int i = tid; i < 32*64; i += 256) {     // weights -> LDS
    const int row = i >> 6, q = (i & 63) << 2;
    const int g = row >> 3, uu = row & 7;
    *(float4*)&wl[row*256 + q] = *(const float4*)&whh[(size_t)((g << 8) + u0 + uu)*256 + q];
  }
  __syncthreads();

  const int len_r = lengths[r];
  float c0 = 0.f, c1 = 0.f;
  for (int s = 0; s < TT; s++) {
    const int t   = dir ? (TT - 1 - s) : s;
    const int rsl = dir ? (t + 1) : t;      // read slab
    const int wsl = dir ? t : (t + 1);      // write slab
    // ---- wait for all blocks of this direction to have finished step s-1 ----
    if (s > 0) {
      if (tid < 64) {
        long guard = 0;
        for (;;) {
          int v = (tid < NBS) ? __hip_atomic_load(&fbase[tid << 5], __ATOMIC_RELAXED,
                                                  __HIP_MEMORY_SCOPE_AGENT) : s;
          if (__all(v >= s)) break;
          __builtin_amdgcn_s_sleep(2);
          if (++guard > 4000000L) break;
        }
        __builtin_amdgcn_fence(__ATOMIC_ACQUIRE, "agent");
      }
      __syncthreads();
    }
    // ---- stage h slab (64KB) into LDS, coalesced ----
    {
      const float4* src = (const float4*)(hT + (size_t)rsl*16384);
      float4* dst = (float4*)hs;
#pragma unroll
      for (int j = 0; j < 16; j++) {
        const int idx4 = j*256 + tid;
        dst[idx4] = src[idx4];
      }
    }
    __syncthreads();
    // ---- GEMV slice: 8 gate rows (2 units x 4 gates) for batch r ----
    float acc[8] = {0,0,0,0,0,0,0,0};
#pragma unroll 2
    for (int k4 = 0; k4 < 64; k4++) {
      const int kb = k4 << 2;
      const float hv0 = hs[(kb+0)*64 + r];
      const float hv1 = hs[(kb+1)*64 + r];
      const float hv2 = hs[(kb+2)*64 + r];
      const float hv3 = hs[(kb+3)*64 + r];
#pragma unroll
      for (int g = 0; g < 4; g++) {
        const float4 wa = *(const float4*)&wl[((g<<3) + (u2<<1) + 0)*256 + kb];
        const float4 wb = *(const float4*)&wl[((g<<3) + (u2<<1) + 1)*256 + kb];
        acc[(g<<1)+0] += hv0*wa.x + hv1*wa.y + hv2*wa.z + hv3*wa.w;
        acc[(g<<1)+1] += hv0*wb.x + hv1*wb.y + hv2*wb.z + hv3*wb.w;
      }
    }
    const bool act = dir ? (t < len_r) : true;
    if (act) {
      const float* __restrict__ xrow = xg + ((size_t)t*64 + r)*GG4;
      const float2 xi = *(const float2*)&xrow[0*256 + ua];
      const float2 xf = *(const float2*)&xrow[1*256 + ua];
      const float2 xu = *(const float2*)&xrow[2*256 + ua];
      const float2 xo = *(const float2*)&xrow[3*256 + ua];
      c0 = sigf(xf.x + acc[2])*c0 + sigf(xi.x + acc[0])*tanh_(xu.x + acc[4]);
      c1 = sigf(xf.y + acc[3])*c1 + sigf(xi.y + acc[1])*tanh_(xu.y + acc[5]);
      const float h0 = sigf(xo.x + acc[6])*tanh_(c0);
      const float h1 = sigf(xo.y + acc[7])*tanh_(c1);
      hT[((size_t)wsl*256 + ua    )*64 + r] = h0;   // coalesced across lanes r
      hT[((size_t)wsl*256 + ua + 1)*64 + r] = h1;
    }
    __syncthreads();   // all waves' stores drained (waitcnt before barrier)
    if (tid == 0)
      __hip_atomic_store(myflag, s + 1, __ATOMIC_RELEASE, __HIP_MEMORY_SCOPE_AGENT);
  }
}

// ---------------- hx = concat(h_f[tok], h_b[tok]) from transposed hT ---------
__global__ __launch_bounds__(256) void gather_hx_kernel(
    const int* __restrict__ tok, const float* __restrict__ hTf,
    const float* __restrict__ hTb, float* __restrict__ hx, int Nn)
{
  int it = blockIdx.x*256 + threadIdx.x;        // item = n*512 + c
  if (it >= Nn*512) return;
  int n = it >> 9, c = it & 511;
  int tk = tok[n];
  int b = tk >> 7, t = tk & 127;
  float v;
  if (c < 256) v = hTf[((size_t)(t+1)*256 + c)*64 + b];
  else         v = hTb[((size_t)t*256 + (c-256))*64 + b];
  hx[(size_t)n*512 + c] = v;
}

// ---------------- counting sort of edges by child level ----------------------
__global__ __launch_bounds__(1024) void sort_edges_kernel(
    const int* __restrict__ child_idx, const int* __restrict__ node_level,
    int* __restrict__ elist, int* __restrict__ lvloff, int E)
{
  __shared__ int hist[MAXLV];
  __shared__ int cur[MAXLV];
  int tid = threadIdx.x;
  if (tid < MAXLV) hist[tid] = 0;
  __syncthreads();
  for (int e = tid; e < E; e += 1024) {
    int lv = node_level[child_idx[e]];
    lv = lv < MAXLV-1 ? lv : MAXLV-1;
    atomicAdd(&hist[lv], 1);
  }
  __syncthreads();
  if (tid == 0) {
    int s = 0;
    for (int l = 0; l < MAXLV; l++) { cur[l] = s; lvloff[l] = s; s += hist[l]; }
    lvloff[MAXLV] = s;
  }
  __syncthreads();
  for (int e = tid; e < E; e += 1024) {
    int lv = node_level[child_idx[e]];
    lv = lv < MAXLV-1 ? lv : MAXLV-1;
    int pos = atomicAdd(&cur[lv], 1);
    elist[pos] = e;
  }
}

// ---------------- tree (ChildSum-ish) level loop -----------------------------
__global__ __launch_bounds__(256) void tree_kernel(
    const int* __restrict__ nlv_ptr, const int* __restrict__ node_level,
    const int* __restrict__ child_idx, const int* __restrict__ parent_idx,
    const int* __restrict__ elist, const int* __restrict__ lvloff,
    const float* __restrict__ Uiou, const float* __restrict__ Uf,
    const float* __restrict__ biou, const float* __restrict__ buf_,
    float* __restrict__ iou, float* __restrict__ cnode,
    float* __restrict__ cred, float* __restrict__ hout,
    int* __restrict__ cnt, int Nn)
{
  int n_lv = nlv_ptr[0];
  if (n_lv > MAXLV) n_lv = MAXLV;
  const int tid = threadIdx.x;
  __shared__ float hs[8][256];
  __shared__ float cs[8][256];
  __shared__ int pidx[8];
  for (int l = 0; l < n_lv; l++) {
    for (int it = blockIdx.x*256 + tid; it < Nn*64; it += gridDim.x*256) {
      const int n = it >> 6, q = (it & 63) << 2;
      if (node_level[n] != l) continue;
      const float4 iv = *(const float4*)&iou[(size_t)n*GG3 + q];
      const float4 ov = *(const float4*)&iou[(size_t)n*GG3 + 256 + q];
      const float4 uv = *(const float4*)&iou[(size_t)n*GG3 + 512 + q];
      const float4 bi = *(const float4*)&biou[q];
      const float4 bo = *(const float4*)&biou[256 + q];
      const float4 bu = *(const float4*)&biou[512 + q];
      const float4 cr = *(const float4*)&cred[(size_t)n*HID + q];
      float cn[4], hn[4];
      cn[0] = sigf(iv.x+bi.x)*tanh_(uv.x+bu.x) + cr.x;
      cn[1] = sigf(iv.y+bi.y)*tanh_(uv.y+bu.y) + cr.y;
      cn[2] = sigf(iv.z+bi.z)*tanh_(uv.z+bu.z) + cr.z;
      cn[3] = sigf(iv.w+bi.w)*tanh_(uv.w+bu.w) + cr.w;
      hn[0] = sigf(ov.x+bo.x)*tanh_(cn[0]);
      hn[1] = sigf(ov.y+bo.y)*tanh_(cn[1]);
      hn[2] = sigf(ov.z+bo.z)*tanh_(cn[2]);
      hn[3] = sigf(ov.w+bo.w)*tanh_(cn[3]);
      *(float4*)&cnode[(size_t)n*HID + q] = make_float4(cn[0],cn[1],cn[2],cn[3]);
      *(float4*)&hout [(size_t)n*HID + q] = make_float4(hn[0],hn[1],hn[2],hn[3]);
    }
    grp_barrier(&cnt[2*l], gridDim.x);
    const int e0 = lvloff[l], e1 = lvloff[l+1];
    const int nb = (e1 - e0 + 7) >> 3;
    for (int bat = blockIdx.x; bat < nb; bat += gridDim.x) {
      const int base = e0 + (bat << 3);
      const int c8 = (e1 - base) < 8 ? (e1 - base) : 8;
      __syncthreads();
      for (int li = tid; li < 1024; li += 256) {
        const int j = li >> 7, q = li & 127;
        if (j < c8) {
          const int e = elist[base + j];
          const int ch = child_idx[e];
          if (q < 64) *(float4*)&hs[j][q<<2]      = *(const float4*)&hout [(size_t)ch*HID + (q<<2)];
          else        *(float4*)&cs[j][(q-64)<<2] = *(const float4*)&cnode[(size_t)ch*HID + ((q-64)<<2)];
        }
      }
      if (tid < 8) pidx[tid] = (tid < c8) ? parent_idx[elist[base + tid]] : -1;
      __syncthreads();
      float acc[8][4] = {};
      const int qq = tid;
      const float* __restrict__ w0 = (qq < 192)
          ? (Uiou + (size_t)(qq<<2)*HID)
          : (Uf   + (size_t)((qq-192)<<2)*HID);
#pragma unroll 2
      for (int k4 = 0; k4 < 64; k4++) {
        const int kof = k4 << 2;
        const float4 a0 = *(const float4*)&w0[kof];
        const float4 a1 = *(const float4*)&w0[HID   + kof];
        const float4 a2 = *(const float4*)&w0[2*HID + kof];
        const float4 a3 = *(const float4*)&w0[3*HID + kof];
#pragma unroll
        for (int j = 0; j < 8; j++) {
          const float4 hv = *(const float4*)&hs[j][kof];
          acc[j][0] += hv.x*a0.x + hv.y*a0.y + hv.z*a0.z + hv.w*a0.w;
          acc[j][1] += hv.x*a1.x + hv.y*a1.y + hv.z*a1.z + hv.w*a1.w;
          acc[j][2] += hv.x*a2.x + hv.y*a2.y + hv.z*a2.z + hv.w*a2.w;
          acc[j][3] += hv.x*a3.x + hv.y*a3.y + hv.z*a3.z + hv.w*a3.w;
        }
      }
      if (qq < 192) {
#pragma unroll
        for (int j = 0; j < 8; j++) {
          const int p = pidx[j];
          if (p < 0) continue;
          float* dst = &iou[(size_t)p*GG3 + (qq<<2)];
          unsafeAtomicAdd(dst+0, acc[j][0]);
          unsafeAtomicAdd(dst+1, acc[j][1]);
          unsafeAtomicAdd(dst+2, acc[j][2]);
          unsafeAtomicAdd(dst+3, acc[j][3]);
        }
      } else {
        const int r0 = (qq-192) << 2;
        const float4 bv = *(const float4*)&buf_[r0];
#pragma unroll
        for (int j = 0; j < 8; j++) {
          const int p = pidx[j];
          if (p < 0) continue;
          float* dst = &cred[(size_t)p*HID + r0];
          unsafeAtomicAdd(dst+0, sigf(acc[j][0]+bv.x)*cs[j][r0+0]);
          unsafeAtomicAdd(dst+1, sigf(acc[j][1]+bv.y)*cs[j][r0+1]);
          unsafeAtomicAdd(dst+2, sigf(acc[j][2]+bv.z)*cs[j][r0+2]);
          unsafeAtomicAdd(dst+3, sigf(acc[j][3]+bv.w)*cs[j][r0+3]);
        }
      }
    }
    grp_barrier(&cnt[2*l+1], gridDim.x);
  }
}

// ---------------- launch ------------------------------------------------------
extern "C" void kernel_launch(void* const* d_in, const int* in_sizes, int n_in,
                              void* d_out, int out_size, void* d_ws, size_t ws_size,
                              hipStream_t stream)
{
  const int*   embed_ids = (const int*)d_in[0];
  const int*   lengths   = (const int*)d_in[1];
  const int*   child_idx = (const int*)d_in[2];
  const int*   parent_idx= (const int*)d_in[3];
  const int*   tok_idx   = (const int*)d_in[4];
  const int*   node_level= (const int*)d_in[5];
  const int*   nlv       = (const int*)d_in[6];
  const float* emb  = (const float*)d_in[7];
  const float* wihf = (const float*)d_in[8];
  const float* whhf = (const float*)d_in[9];
  const float* bf   = (const float*)d_in[10];
  const float* wihb = (const float*)d_in[11];
  const float* whhb = (const float*)d_in[12];
  const float* bb   = (const float*)d_in[13];
  const float* Wiou = (const float*)d_in[14];
  const float* Uiou = (const float*)d_in[15];
  const float* biou = (const float*)d_in[16];
  const float* Uf   = (const float*)d_in[17];
  const float* buf_ = (const float*)d_in[18];
  const int E  = in_sizes[2];
  const int Nn = in_sizes[4];
  float* hout = (float*)d_out;

  char* w = (char*)d_ws;
  size_t off = 0;
  auto take = [&](size_t bytes) -> char* {
    char* p = w + off;
    off += (bytes + 255) & ~(size_t)255;
    return p;
  };
  int*   bar   = (int*)  take(16384);                      // zeroed: lstm flags (8KB) + tree cnt
  float* hTf   = (float*)take((size_t)129*256*64*4);       // zeroed (transposed)
  float* hTb   = (float*)take((size_t)129*256*64*4);       // zeroed (transposed)
  float* cred  = (float*)take((size_t)Nn*HID*4);           // zeroed
  size_t zero_end = off;
  float* x     = (float*)take((size_t)8192*300*4);
  float* xgf   = (float*)take((size_t)8192*1024*4);
  float* xgb   = (float*)take((size_t)8192*1024*4);
  float* hx    = (float*)take((size_t)Nn*512*4);
  float* iou   = (float*)take((size_t)Nn*GG3*4);
  float* cnode = (float*)take((size_t)Nn*HID*4);
  int*   elist = (int*)  take((size_t)E*4);
  int*   lvloff= (int*)  take((size_t)(MAXLV+1)*4);
  (void)ws_size; (void)n_in; (void)out_size;

  hipMemsetAsync(d_ws, 0, zero_end, stream);
  gather_x_kernel<<<(8192*75 + 255)/256, 256, 0, stream>>>(embed_ids, emb, x);
  gemm_kernel<true,true><<<dim3(8192/128, 1024/64), 256, 0, stream>>>(x, wihf, bf, xgf, 8192, 1024, 300);
  gemm_kernel<true,true><<<dim3(8192/128, 1024/64), 256, 0, stream>>>(x, wihb, bb, xgb, 8192, 1024, 300);
  lstm_kernel<<<64, 256, 98304, stream>>>(xgf, xgb, whhf, whhb, lengths, hTf, hTb, bar);
  gather_hx_kernel<<<(Nn*512 + 255)/256, 256, 0, stream>>>(tok_idx, hTf, hTb, hx, Nn);
  gemm_kernel<false,false><<<dim3((Nn+127)/128, GG3/64), 256, 0, stream>>>(hx, Wiou, nullptr, iou, Nn, GG3, 512);
  sort_edges_kernel<<<1, 1024, 0, stream>>>(child_idx, node_level, elist, lvloff, E);
  tree_kernel<<<64, 256, 0, stream>>>(nlv, node_level, child_idx, parent_idx, elist, lvloff,
                                      Uiou, Uf, biou, buf_, iou, cnode, cred, hout, bar + 4096, Nn);
}

// Round 4
// 2735.532 us; speedup vs baseline: 1.5161x; 1.5161x over previous
//
#include <hip/hip_runtime.h>
#include <cstdint>
#include <cstddef>

#define TT 128
#define HID 256
#define GG4 1024
#define GG3 768
#define MAXLV 64

__device__ __forceinline__ float sigf(float x){ return 1.f/(1.f+__expf(-x)); }
__device__ __forceinline__ float tanh_(float x){
  float cx = fminf(fmaxf(x,-15.f),15.f);
  float e = __expf(2.f*cx);
  return (e-1.f)/(e+1.f);
}

// ---------------- embedding gather: x[m][e] = emb[ids[m]][e] ----------------
__global__ __launch_bounds__(256) void gather_x_kernel(
    const int* __restrict__ ids, const float* __restrict__ emb, float* __restrict__ x)
{
  int it = blockIdx.x*256 + threadIdx.x;        // item = m*75 + q  (300 = 75 float4)
  if (it >= 8192*75) return;
  int m = it / 75, q = (it % 75) * 4;
  int id = ids[m];
  *(float4*)&x[(size_t)m*300 + q] = *(const float4*)&emb[(size_t)id*300 + q];
}

// ---------------- tiled GEMM 128x64, 8x4/thread: C[m][n] = A[m]·W[n] (+bias) -
template<bool BIAS>
__global__ __launch_bounds__(256) void gemm_kernel(
    const float* __restrict__ A, const float* __restrict__ W,
    const float* __restrict__ bias, float* __restrict__ C,
    int M, int Nn, int K)
{
  __shared__ float As[16][128];
  __shared__ float Ws[16][64];
  const int tid = threadIdx.x;
  const int m0 = blockIdx.x * 128, n0 = blockIdx.y * 64;
  const int tx = tid & 15, ty = tid >> 4;       // out cols tx*4, rows ty*8
  const int arow = tid >> 1, akof = (tid & 1) << 3;   // A stage
  const int wrow = tid >> 2, wkof = (tid & 3) << 2;   // W stage
  float acc[8][4] = {};
  for (int k0 = 0; k0 < K; k0 += 16) {
    float a_[8], w_[4];
    {
      const int gm = m0 + arow;
#pragma unroll
      for (int j = 0; j < 8; j++) {
        const int kk = k0 + akof + j;
        a_[j] = (gm < M && kk < K) ? A[(size_t)gm*K + kk] : 0.f;
      }
      const int gn = n0 + wrow;
#pragma unroll
      for (int j = 0; j < 4; j++) {
        const int kk = k0 + wkof + j;
        w_[j] = (gn < Nn && kk < K) ? W[(size_t)gn*K + kk] : 0.f;
      }
    }
    __syncthreads();
#pragma unroll
    for (int j = 0; j < 8; j++) As[akof + j][arow] = a_[j];
#pragma unroll
    for (int j = 0; j < 4; j++) Ws[wkof + j][wrow] = w_[j];
    __syncthreads();
#pragma unroll
    for (int k = 0; k < 16; k++) {
      const float4 b  = *(const float4*)&Ws[k][tx << 2];
      const float4 a0 = *(const float4*)&As[k][ty << 3];
      const float4 a1 = *(const float4*)&As[k][(ty << 3) + 4];
      const float av[8] = {a0.x,a0.y,a0.z,a0.w,a1.x,a1.y,a1.z,a1.w};
      const float bv[4] = {b.x,b.y,b.z,b.w};
#pragma unroll
      for (int i = 0; i < 8; i++)
#pragma unroll
        for (int j = 0; j < 4; j++) acc[i][j] += av[i]*bv[j];
    }
  }
  float4 bv4 = make_float4(0,0,0,0);
  if (BIAS) bv4 = *(const float4*)&bias[n0 + (tx<<2)];
#pragma unroll
  for (int i = 0; i < 8; i++) {
    int gm = m0 + (ty<<3) + i;
    if (gm >= M) continue;
    float4 o = make_float4(acc[i][0]+bv4.x, acc[i][1]+bv4.y, acc[i][2]+bv4.z, acc[i][3]+bv4.w);
    *(float4*)&C[(size_t)gm*Nn + n0 + (tx<<2)] = o;
  }
}

// ---------------- Whh transpose: WT4[k4][g] = W[g][4k4..4k4+3] --------------
__global__ __launch_bounds__(256) void transpose_w_kernel(
    const float* __restrict__ whhf, const float* __restrict__ whhb,
    float* __restrict__ wtf, float* __restrict__ wtb)
{
  int it = blockIdx.x*256 + threadIdx.x;  // dir(1) | g(10) | k4(6)
  if (it >= 2*1024*64) return;
  int dir = it >> 16, rem = it & 65535;
  int g = rem >> 6, k4 = rem & 63;
  const float* w = dir ? whhb : whhf;
  float*      wt = dir ? wtb  : wtf;
  float4 v = *(const float4*)&w[(size_t)g*HID + (k4 << 2)];
  *(float4*)&wt[((size_t)(k4 << 10) + g) * 4] = v;
}

// ---------------- batch-split bidirectional LSTM (NO inter-block sync) ------
// 64 blocks x 512 threads. dir = (blockIdx%8)>>2 (XCD-grouped so each XCD's L2
// caches one 1MB WT matrix). Block owns batch rows 2p, 2p+1 for its direction.
// Thread tid: gate-rows g0=tid, g1=tid+512. half0 (tid<256): i,g of unit u=tid;
// half1: f,o of unit u=tid-256. h kept in LDS, c in half0 registers.
// h output: hs[b][t][u] (natural layout for gather).
__global__ __launch_bounds__(512, 1) void lstm_kernel(
    const float* __restrict__ xgf, const float* __restrict__ xgb,
    const float* __restrict__ wtf, const float* __restrict__ wtb,
    const int* __restrict__ lengths,
    float* __restrict__ hsf, float* __restrict__ hsb)
{
  const int idx8 = blockIdx.x & 7;
  const int grp  = blockIdx.x >> 3;         // 0..7
  const int dir  = idx8 >> 2;
  const int p    = grp * 4 + (idx8 & 3);    // 0..31
  const int r0 = 2*p, r1 = 2*p + 1;
  const float* __restrict__ xg = dir ? xgb : xgf;
  const float4* __restrict__ wt = (const float4*)(dir ? wtb : wtf);
  float* __restrict__ hs = dir ? hsb : hsf;
  const int tid = threadIdx.x;
  const int u   = tid & 255;
  const int half = tid >> 8;

  __shared__ float hbuf[2][256];
  __shared__ float ex[2][2][256];           // [f/o][row][unit]
  if (tid < 256) { hbuf[0][tid] = 0.f; hbuf[1][tid] = 0.f; }
  __syncthreads();

  const int len0 = lengths[r0], len1 = lengths[r1];
  const int smax = len0 > len1 ? len0 : len1;
  float c0 = 0.f, c1 = 0.f;
  const float4* w0p = wt + tid;             // g0
  const float4* w1p = wt + tid + 512;       // g1

  for (int s = 0; s < smax; s++) {
    const bool a0 = s < len0, a1 = s < len1;
    const int t0_ = dir ? (len0 - 1 - s) : s;
    const int t1_ = dir ? (len1 - 1 - s) : s;
    float acc00 = 0.f, acc01 = 0.f, acc10 = 0.f, acc11 = 0.f;
#pragma unroll 8
    for (int k4 = 0; k4 < 64; k4++) {
      const float4 w0 = w0p[(size_t)k4 << 10];
      const float4 w1 = w1p[(size_t)k4 << 10];
      const float4 h0 = *(const float4*)&hbuf[0][k4 << 2];
      const float4 h1 = *(const float4*)&hbuf[1][k4 << 2];
      acc00 += w0.x*h0.x + w0.y*h0.y + w0.z*h0.z + w0.w*h0.w;
      acc01 += w0.x*h1.x + w0.y*h1.y + w0.z*h1.z + w0.w*h1.w;
      acc10 += w1.x*h0.x + w1.y*h0.y + w1.z*h0.z + w1.w*h0.w;
      acc11 += w1.x*h1.x + w1.y*h1.y + w1.z*h1.z + w1.w*h1.w;
    }
    float x00 = 0.f, x01 = 0.f, x10 = 0.f, x11 = 0.f;
    if (a0) { const float* xr = xg + ((size_t)r0*TT + t0_)*GG4;
              x00 = xr[tid]; x10 = xr[tid + 512]; }
    if (a1) { const float* xr = xg + ((size_t)r1*TT + t1_)*GG4;
              x01 = xr[tid]; x11 = xr[tid + 512]; }
    __syncthreads();                         // h reads done
    if (half == 1) {                         // publish f,o pre-activations
      ex[0][0][u] = acc00 + x00;  ex[0][1][u] = acc01 + x01;
      ex[1][0][u] = acc10 + x10;  ex[1][1][u] = acc11 + x11;
    }
    __syncthreads();
    if (half == 0) {
      if (a0) {
        const float ig = sigf(acc00 + x00), gg = tanh_(acc10 + x10);
        c0 = sigf(ex[0][0][u])*c0 + ig*gg;
        const float h = sigf(ex[1][0][u])*tanh_(c0);
        hbuf[0][u] = h;
        hs[((size_t)r0*TT + t0_)*HID + u] = h;
      }
      if (a1) {
        const float ig = sigf(acc01 + x01), gg = tanh_(acc11 + x11);
        c1 = sigf(ex[0][1][u])*c1 + ig*gg;
        const float h = sigf(ex[1][1][u])*tanh_(c1);
        hbuf[1][u] = h;
        hs[((size_t)r1*TT + t1_)*HID + u] = h;
      }
    }
    __syncthreads();                         // h ready for next step
  }
}

// ---------------- hx = concat(h_f[tok], h_b[tok]) ---------------------------
__global__ __launch_bounds__(256) void gather_hx_kernel(
    const int* __restrict__ tok, const float* __restrict__ hsf,
    const float* __restrict__ hsb, float* __restrict__ hx, int Nn)
{
  int it = blockIdx.x*256 + threadIdx.x;     // item = n*128 + q
  if (it >= Nn*128) return;
  int n = it >> 7, q = it & 127;
  int tk = tok[n];
  int b = tk >> 7, t = tk & 127;
  float4 v;
  if (q < 64) v = *(const float4*)&hsf[((size_t)b*TT + t)*HID + (q<<2)];
  else        v = *(const float4*)&hsb[((size_t)b*TT + t)*HID + ((q-64)<<2)];
  *(float4*)&hx[(size_t)n*512 + (q<<2)] = v;
}

// ---------------- counting sort: edges AND nodes by level -------------------
__global__ __launch_bounds__(1024) void sort_kernel(
    const int* __restrict__ child_idx, const int* __restrict__ node_level,
    int* __restrict__ elist, int* __restrict__ lvloff,
    int* __restrict__ nlist, int* __restrict__ nlvloff, int E, int Nn)
{
  __shared__ int ehist[MAXLV], ecur[MAXLV], nhist[MAXLV], ncur[MAXLV];
  int tid = threadIdx.x;
  if (tid < MAXLV) { ehist[tid] = 0; nhist[tid] = 0; }
  __syncthreads();
  for (int e = tid; e < E; e += 1024) {
    int lv = node_level[child_idx[e]];
    lv = lv < MAXLV-1 ? lv : MAXLV-1;
    atomicAdd(&ehist[lv], 1);
  }
  for (int n = tid; n < Nn; n += 1024) {
    int lv = node_level[n];
    lv = lv < MAXLV-1 ? lv : MAXLV-1;
    atomicAdd(&nhist[lv], 1);
  }
  __syncthreads();
  if (tid == 0) {
    int s = 0, t = 0;
    for (int l = 0; l < MAXLV; l++) {
      ecur[l] = s; lvloff[l] = s; s += ehist[l];
      ncur[l] = t; nlvloff[l] = t; t += nhist[l];
    }
    lvloff[MAXLV] = s; nlvloff[MAXLV] = t;
  }
  __syncthreads();
  for (int e = tid; e < E; e += 1024) {
    int lv = node_level[child_idx[e]];
    lv = lv < MAXLV-1 ? lv : MAXLV-1;
    elist[atomicAdd(&ecur[lv], 1)] = e;
  }
  for (int n = tid; n < Nn; n += 1024) {
    int lv = node_level[n];
    lv = lv < MAXLV-1 ? lv : MAXLV-1;
    nlist[atomicAdd(&ncur[lv], 1)] = n;
  }
}

// ---------------- tree level loop with epoch-flag barrier -------------------
__device__ __forceinline__ void tree_barrier(int* flags, int nb, int epoch){
  __syncthreads();
  if (threadIdx.x == 0)
    __hip_atomic_store(&flags[blockIdx.x << 5], epoch, __ATOMIC_RELEASE,
                       __HIP_MEMORY_SCOPE_AGENT);
  if (threadIdx.x < 64) {
    long guard = 0;
    for (;;) {
      int v = ((int)threadIdx.x < nb)
        ? __hip_atomic_load(&flags[threadIdx.x << 5], __ATOMIC_RELAXED,
                            __HIP_MEMORY_SCOPE_AGENT) : epoch;
      if (__all(v >= epoch)) break;
      __builtin_amdgcn_s_sleep(1);
      if (++guard > 30000000L) break;
    }
    __builtin_amdgcn_fence(__ATOMIC_ACQUIRE, "agent");
  }
  __syncthreads();
}

__global__ __launch_bounds__(256) void tree_kernel(
    const int* __restrict__ nlv_ptr, const int* __restrict__ node_level,
    const int* __restrict__ child_idx, const int* __restrict__ parent_idx,
    const int* __restrict__ elist, const int* __restrict__ lvloff,
    const int* __restrict__ nlist, const int* __restrict__ nlvloff,
    const float* __restrict__ Uiou, const float* __restrict__ Uf,
    const float* __restrict__ biou, const float* __restrict__ buf_,
    float* __restrict__ iou, float* __restrict__ cnode,
    float* __restrict__ cred, float* __restrict__ hout,
    int* __restrict__ flags, int Nn)
{
  int n_lv = nlv_ptr[0];
  if (n_lv > MAXLV) n_lv = MAXLV;
  const int tid = threadIdx.x;
  __shared__ float hs[8][256];
  __shared__ float cs[8][256];
  __shared__ int pidx[8];
  int ep = 1;
  for (int l = 0; l < n_lv; l++) {
    // Phase A: apply node func for level-l nodes only (sorted list)
    const int na = nlvloff[l], nbnd = nlvloff[l+1];
    for (int it = blockIdx.x*256 + tid; it < (nbnd-na)*64; it += gridDim.x*256) {
      const int n = nlist[na + (it >> 6)];
      const int q = (it & 63) << 2;
      const float4 iv = *(const float4*)&iou[(size_t)n*GG3 + q];
      const float4 ov = *(const float4*)&iou[(size_t)n*GG3 + 256 + q];
      const float4 uv = *(const float4*)&iou[(size_t)n*GG3 + 512 + q];
      const float4 bi = *(const float4*)&biou[q];
      const float4 bo = *(const float4*)&biou[256 + q];
      const float4 bu = *(const float4*)&biou[512 + q];
      const float4 cr = *(const float4*)&cred[(size_t)n*HID + q];
      float cn[4], hn[4];
      cn[0] = sigf(iv.x+bi.x)*tanh_(uv.x+bu.x) + cr.x;
      cn[1] = sigf(iv.y+bi.y)*tanh_(uv.y+bu.y) + cr.y;
      cn[2] = sigf(iv.z+bi.z)*tanh_(uv.z+bu.z) + cr.z;
      cn[3] = sigf(iv.w+bi.w)*tanh_(uv.w+bu.w) + cr.w;
      hn[0] = sigf(ov.x+bo.x)*tanh_(cn[0]);
      hn[1] = sigf(ov.y+bo.y)*tanh_(cn[1]);
      hn[2] = sigf(ov.z+bo.z)*tanh_(cn[2]);
      hn[3] = sigf(ov.w+bo.w)*tanh_(cn[3]);
      *(float4*)&cnode[(size_t)n*HID + q] = make_float4(cn[0],cn[1],cn[2],cn[3]);
      *(float4*)&hout [(size_t)n*HID + q] = make_float4(hn[0],hn[1],hn[2],hn[3]);
    }
    tree_barrier(flags, gridDim.x, ep++);
    // Phase B: messages from level-l children to parents
    const int e0 = lvloff[l], e1 = lvloff[l+1];
    const int nb = (e1 - e0 + 7) >> 3;
    for (int bat = blockIdx.x; bat < nb; bat += gridDim.x) {
      const int base = e0 + (bat << 3);
      const int c8 = (e1 - base) < 8 ? (e1 - base) : 8;
      __syncthreads();
      for (int li = tid; li < 1024; li += 256) {
        const int j = li >> 7, q = li & 127;
        if (j < c8) {
          const int e = elist[base + j];
          const int ch = child_idx[e];
          if (q < 64) *(float4*)&hs[j][q<<2]      = *(const float4*)&hout [(size_t)ch*HID + (q<<2)];
          else        *(float4*)&cs[j][(q-64)<<2] = *(const float4*)&cnode[(size_t)ch*HID + ((q-64)<<2)];
        }
      }
      if (tid < 8) pidx[tid] = (tid < c8) ? parent_idx[elist[base + tid]] : -1;
      __syncthreads();
      float acc[8][4] = {};
      const int qq = tid;
      const float* __restrict__ w0 = (qq < 192)
          ? (Uiou + (size_t)(qq<<2)*HID)
          : (Uf   + (size_t)((qq-192)<<2)*HID);
#pragma unroll 2
      for (int k4 = 0; k4 < 64; k4++) {
        const int kof = k4 << 2;
        const float4 a0 = *(const float4*)&w0[kof];
        const float4 a1 = *(const float4*)&w0[HID   + kof];
        const float4 a2 = *(const float4*)&w0[2*HID + kof];
        const float4 a3 = *(const float4*)&w0[3*HID + kof];
#pragma unroll
        for (int j = 0; j < 8; j++) {
          const float4 hv = *(const float4*)&hs[j][kof];
          acc[j][0] += hv.x*a0.x + hv.y*a0.y + hv.z*a0.z + hv.w*a0.w;
          acc[j][1] += hv.x*a1.x + hv.y*a1.y + hv.z*a1.z + hv.w*a1.w;
          acc[j][2] += hv.x*a2.x + hv.y*a2.y + hv.z*a2.z + hv.w*a2.w;
          acc[j][3] += hv.x*a3.x + hv.y*a3.y + hv.z*a3.z + hv.w*a3.w;
        }
      }
      if (qq < 192) {
#pragma unroll
        for (int j = 0; j < 8; j++) {
          const int p = pidx[j];
          if (p < 0) continue;
          float* dst = &iou[(size_t)p*GG3 + (qq<<2)];
          unsafeAtomicAdd(dst+0, acc[j][0]);
          unsafeAtomicAdd(dst+1, acc[j][1]);
          unsafeAtomicAdd(dst+2, acc[j][2]);
          unsafeAtomicAdd(dst+3, acc[j][3]);
        }
      } else {
        const int r0 = (qq-192) << 2;
        const float4 bv = *(const float4*)&buf_[r0];
#pragma unroll
        for (int j = 0; j < 8; j++) {
          const int p = pidx[j];
          if (p < 0) continue;
          float* dst = &cred[(size_t)p*HID + r0];
          unsafeAtomicAdd(dst+0, sigf(acc[j][0]+bv.x)*cs[j][r0+0]);
          unsafeAtomicAdd(dst+1, sigf(acc[j][1]+bv.y)*cs[j][r0+1]);
          unsafeAtomicAdd(dst+2, sigf(acc[j][2]+bv.z)*cs[j][r0+2]);
          unsafeAtomicAdd(dst+3, sigf(acc[j][3]+bv.w)*cs[j][r0+3]);
        }
      }
    }
    tree_barrier(flags, gridDim.x, ep++);
  }
}

// ---------------- launch ------------------------------------------------------
extern "C" void kernel_launch(void* const* d_in, const int* in_sizes, int n_in,
                              void* d_out, int out_size, void* d_ws, size_t ws_size,
                              hipStream_t stream)
{
  const int*   embed_ids = (const int*)d_in[0];
  const int*   lengths   = (const int*)d_in[1];
  const int*   child_idx = (const int*)d_in[2];
  const int*   parent_idx= (const int*)d_in[3];
  const int*   tok_idx   = (const int*)d_in[4];
  const int*   node_level= (const int*)d_in[5];
  const int*   nlv       = (const int*)d_in[6];
  const float* emb  = (const float*)d_in[7];
  const float* wihf = (const float*)d_in[8];
  const float* whhf = (const float*)d_in[9];
  const float* bf   = (const float*)d_in[10];
  const float* wihb = (const float*)d_in[11];
  const float* whhb = (const float*)d_in[12];
  const float* bb   = (const float*)d_in[13];
  const float* Wiou = (const float*)d_in[14];
  const float* Uiou = (const float*)d_in[15];
  const float* biou = (const float*)d_in[16];
  const float* Uf   = (const float*)d_in[17];
  const float* buf_ = (const float*)d_in[18];
  const int E  = in_sizes[2];
  const int Nn = in_sizes[4];
  float* hout = (float*)d_out;

  char* w = (char*)d_ws;
  size_t off = 0;
  auto take = [&](size_t bytes) -> char* {
    char* p = w + off;
    off += (bytes + 255) & ~(size_t)255;
    return p;
  };
  int*   flags = (int*)  take(8192);                       // zeroed: tree barrier flags
  float* cred  = (float*)take((size_t)Nn*HID*4);           // zeroed
  size_t zero_end = off;
  float* x     = (float*)take((size_t)8192*300*4);
  float* xgf   = (float*)take((size_t)8192*1024*4);
  float* xgb   = (float*)take((size_t)8192*1024*4);
  float* wtf   = (float*)take((size_t)64*1024*16);
  float* wtb   = (float*)take((size_t)64*1024*16);
  float* hsf   = (float*)take((size_t)64*128*256*4);
  float* hsb   = (float*)take((size_t)64*128*256*4);
  float* hx    = (float*)take((size_t)Nn*512*4);
  float* iou   = (float*)take((size_t)Nn*GG3*4);
  float* cnode = (float*)take((size_t)Nn*HID*4);
  int*   elist = (int*)  take((size_t)E*4);
  int*   lvloff= (int*)  take((size_t)(MAXLV+1)*4);
  int*   nlist = (int*)  take((size_t)Nn*4);
  int*   nlvloff=(int*)  take((size_t)(MAXLV+1)*4);
  (void)ws_size; (void)n_in; (void)out_size;

  hipMemsetAsync(d_ws, 0, zero_end, stream);
  gather_x_kernel<<<(8192*75 + 255)/256, 256, 0, stream>>>(embed_ids, emb, x);
  gemm_kernel<true><<<dim3(8192/128, 1024/64), 256, 0, stream>>>(x, wihf, bf, xgf, 8192, 1024, 300);
  gemm_kernel<true><<<dim3(8192/128, 1024/64), 256, 0, stream>>>(x, wihb, bb, xgb, 8192, 1024, 300);
  transpose_w_kernel<<<(2*1024*64 + 255)/256, 256, 0, stream>>>(whhf, whhb, wtf, wtb);
  lstm_kernel<<<64, 512, 0, stream>>>(xgf, xgb, wtf, wtb, lengths, hsf, hsb);
  gather_hx_kernel<<<(Nn*128 + 255)/256, 256, 0, stream>>>(tok_idx, hsf, hsb, hx, Nn);
  gemm_kernel<false><<<dim3((Nn+127)/128, GG3/64), 256, 0, stream>>>(hx, Wiou, nullptr, iou, Nn, GG3, 512);
  sort_kernel<<<1, 1024, 0, stream>>>(child_idx, node_level, elist, lvloff, nlist, nlvloff, E, Nn);
  tree_kernel<<<64, 256, 0, stream>>>(nlv, node_level, child_idx, parent_idx, elist, lvloff,
                                      nlist, nlvloff, Uiou, Uf, biou, buf_,
                                      iou, cnode, cred, hout, flags, Nn);
}

// Round 5
// 2573.338 us; speedup vs baseline: 1.6117x; 1.0630x over previous
//
#include <hip/hip_runtime.h>
#include <cstdint>
#include <cstddef>

#define TT 128
#define HID 256
#define GG4 1024
#define GG3 768
#define MAXLV 64

__device__ __forceinline__ float sigf(float x){ return 1.f/(1.f+__expf(-x)); }
__device__ __forceinline__ float tanh_(float x){
  float cx = fminf(fmaxf(x,-15.f),15.f);
  float e = __expf(2.f*cx);
  return (e-1.f)/(e+1.f);
}

// ---------------- embedding gather: x[m][e] = emb[ids[m]][e] ----------------
__global__ __launch_bounds__(256) void gather_x_kernel(
    const int* __restrict__ ids, const float* __restrict__ emb, float* __restrict__ x)
{
  int it = blockIdx.x*256 + threadIdx.x;        // item = m*75 + q  (300 = 75 float4)
  if (it >= 8192*75) return;
  int m = it / 75, q = (it % 75) * 4;
  int id = ids[m];
  *(float4*)&x[(size_t)m*300 + q] = *(const float4*)&emb[(size_t)id*300 + q];
}

// ---------------- tiled GEMM 128x128, 8x8/thread: C[m][n] = A[m]·W[n] (+bias)
// Requires Nn % 128 == 0 (true for 1024, 768). M guarded.
template<bool BIAS>
__global__ __launch_bounds__(256) void gemm_kernel(
    const float* __restrict__ A, const float* __restrict__ W,
    const float* __restrict__ bias, float* __restrict__ C,
    int M, int Nn, int K)
{
  __shared__ float As[16][132];
  __shared__ float Ws[16][132];
  const int tid = threadIdx.x;
  const int m0 = blockIdx.x * 128, n0 = blockIdx.y * 128;
  const int tx = tid & 15, ty = tid >> 4;             // out: rows ty*8, cols tx*8
  const int srow = tid >> 1, skof = (tid & 1) << 3;   // staging: 2 thr/row, 8 k each
  float acc[8][8] = {};
  for (int k0 = 0; k0 < K; k0 += 16) {
    float a_[8], w_[8];
    const int gm = m0 + srow, gn = n0 + srow;
#pragma unroll
    for (int j = 0; j < 8; j++) {
      const int kk = k0 + skof + j;
      a_[j] = (gm < M && kk < K) ? A[(size_t)gm*K + kk] : 0.f;
      w_[j] = (kk < K) ? W[(size_t)gn*K + kk] : 0.f;
    }
    __syncthreads();
#pragma unroll
    for (int j = 0; j < 8; j++) { As[skof+j][srow] = a_[j]; Ws[skof+j][srow] = w_[j]; }
    __syncthreads();
#pragma unroll
    for (int k = 0; k < 16; k++) {
      const float4 a0 = *(const float4*)&As[k][ty << 3];
      const float4 a1 = *(const float4*)&As[k][(ty << 3) + 4];
      const float4 b0 = *(const float4*)&Ws[k][tx << 3];
      const float4 b1 = *(const float4*)&Ws[k][(tx << 3) + 4];
      const float av[8] = {a0.x,a0.y,a0.z,a0.w,a1.x,a1.y,a1.z,a1.w};
      const float bv[8] = {b0.x,b0.y,b0.z,b0.w,b1.x,b1.y,b1.z,b1.w};
#pragma unroll
      for (int i = 0; i < 8; i++)
#pragma unroll
        for (int j = 0; j < 8; j++) acc[i][j] += av[i]*bv[j];
    }
  }
  float bvv[8] = {0,0,0,0,0,0,0,0};
  if (BIAS) {
#pragma unroll
    for (int j = 0; j < 8; j++) bvv[j] = bias[n0 + (tx<<3) + j];
  }
#pragma unroll
  for (int i = 0; i < 8; i++) {
    const int gm = m0 + (ty<<3) + i;
    if (gm >= M) continue;
    float4 o0 = make_float4(acc[i][0]+bvv[0], acc[i][1]+bvv[1], acc[i][2]+bvv[2], acc[i][3]+bvv[3]);
    float4 o1 = make_float4(acc[i][4]+bvv[4], acc[i][5]+bvv[5], acc[i][6]+bvv[6], acc[i][7]+bvv[7]);
    *(float4*)&C[(size_t)gm*Nn + n0 + (tx<<3)]     = o0;
    *(float4*)&C[(size_t)gm*Nn + n0 + (tx<<3) + 4] = o1;
  }
}

// ---------------- Whh transpose: WT4[k4][g] = W[g][4k4..4k4+3] --------------
__global__ __launch_bounds__(256) void transpose_w_kernel(
    const float* __restrict__ whhf, const float* __restrict__ whhb,
    float* __restrict__ wtf, float* __restrict__ wtb)
{
  int it = blockIdx.x*256 + threadIdx.x;  // dir(1) | g(10) | k4(6)
  if (it >= 2*1024*64) return;
  int dir = it >> 16, rem = it & 65535;
  int g = rem >> 6, k4 = rem & 63;
  const float* w = dir ? whhb : whhf;
  float*      wt = dir ? wtb  : wtf;
  float4 v = *(const float4*)&w[(size_t)g*HID + (k4 << 2)];
  *(float4*)&wt[((size_t)(k4 << 10) + g) * 4] = v;
}

// ---------------- batch-split bidirectional LSTM (no inter-block sync) ------
// 64 blocks x 1024 threads. XCD-grouped: dir = ((blk&7)>>2) so XCDs 0-3 run fwd
// (share 1MB wtf in L2), XCDs 4-7 run bwd. Block owns batch rows 2p, 2p+1.
// Thread tid = gate row (gate = tid>>8, unit u = tid&255). c held by gate-0
// threads; h in LDS + streamed to hs[b][t][u].
__global__ __launch_bounds__(1024, 1) void lstm_kernel(
    const float* __restrict__ xgf, const float* __restrict__ xgb,
    const float* __restrict__ wtf, const float* __restrict__ wtb,
    const int* __restrict__ lengths,
    float* __restrict__ hsf, float* __restrict__ hsb)
{
  const int b8  = blockIdx.x & 7;
  const int dir = b8 >> 2;
  const int p   = (blockIdx.x >> 3) * 4 + (b8 & 3);   // 0..31
  const int r0 = 2*p, r1 = r0 + 1;
  const float* __restrict__ xg = dir ? xgb : xgf;
  const float4* __restrict__ wp = (const float4*)(dir ? wtb : wtf) + threadIdx.x;
  float* __restrict__ hs = dir ? hsb : hsf;
  const int tid = threadIdx.x;
  const int u = tid & 255, gate = tid >> 8;

  __shared__ float hbuf[2][256];
  __shared__ float ex[4][2][256];
  if (tid < 512) hbuf[tid >> 8][tid & 255] = 0.f;
  __syncthreads();

  const int len0 = lengths[r0], len1 = lengths[r1];   // len0 >= len1
  float c0 = 0.f, c1 = 0.f;
  for (int s = 0; s < len0; s++) {
    const bool a1 = s < len1;
    const int t0 = dir ? (len0 - 1 - s) : s;
    const int t1 = dir ? (len1 - 1 - s) : s;
    const float x0 = xg[((size_t)r0*TT + t0)*GG4 + tid];
    const float x1 = a1 ? xg[((size_t)r1*TT + t1)*GG4 + tid] : 0.f;
    float acc0 = 0.f, acc1 = 0.f;
#pragma unroll 8
    for (int k4 = 0; k4 < 64; k4++) {
      const float4 w  = wp[(size_t)k4 << 10];
      const float4 h0 = *(const float4*)&hbuf[0][k4 << 2];
      const float4 h1 = *(const float4*)&hbuf[1][k4 << 2];
      acc0 += w.x*h0.x + w.y*h0.y + w.z*h0.z + w.w*h0.w;
      acc1 += w.x*h1.x + w.y*h1.y + w.z*h1.z + w.w*h1.w;
    }
    __syncthreads();                       // hbuf reads done
    ex[gate][0][u] = acc0 + x0;
    ex[gate][1][u] = acc1 + x1;
    __syncthreads();                       // gate pre-acts published
    if (gate == 0) {
      {
        const float ig = sigf(ex[0][0][u]);
        const float fg = sigf(ex[1][0][u]);
        const float gg = tanh_(ex[2][0][u]);
        const float og = sigf(ex[3][0][u]);
        c0 = fg*c0 + ig*gg;
        const float h = og*tanh_(c0);
        hbuf[0][u] = h;
        hs[((size_t)r0*TT + t0)*HID + u] = h;
      }
      if (a1) {
        const float ig = sigf(ex[0][1][u]);
        const float fg = sigf(ex[1][1][u]);
        const float gg = tanh_(ex[2][1][u]);
        const float og = sigf(ex[3][1][u]);
        c1 = fg*c1 + ig*gg;
        const float h = og*tanh_(c1);
        hbuf[1][u] = h;
        hs[((size_t)r1*TT + t1)*HID + u] = h;
      }
    }
    __syncthreads();                       // new h visible to all waves
  }
}

// ---------------- hx = concat(h_f[tok], h_b[tok]) ---------------------------
__global__ __launch_bounds__(256) void gather_hx_kernel(
    const int* __restrict__ tok, const float* __restrict__ hsf,
    const float* __restrict__ hsb, float* __restrict__ hx, int Nn)
{
  int it = blockIdx.x*256 + threadIdx.x;     // item = n*128 + q
  if (it >= Nn*128) return;
  int n = it >> 7, q = it & 127;
  int tk = tok[n];
  int b = tk >> 7, t = tk & 127;
  float4 v;
  if (q < 64) v = *(const float4*)&hsf[((size_t)b*TT + t)*HID + (q<<2)];
  else        v = *(const float4*)&hsb[((size_t)b*TT + t)*HID + ((q-64)<<2)];
  *(float4*)&hx[(size_t)n*512 + (q<<2)] = v;
}

// ---------------- counting sort: edges AND nodes by level -------------------
__global__ __launch_bounds__(1024) void sort_kernel(
    const int* __restrict__ child_idx, const int* __restrict__ node_level,
    int* __restrict__ elist, int* __restrict__ lvloff,
    int* __restrict__ nlist, int* __restrict__ nlvloff, int E, int Nn)
{
  __shared__ int ehist[MAXLV], ecur[MAXLV], nhist[MAXLV], ncur[MAXLV];
  int tid = threadIdx.x;
  if (tid < MAXLV) { ehist[tid] = 0; nhist[tid] = 0; }
  __syncthreads();
  for (int e = tid; e < E; e += 1024) {
    int lv = node_level[child_idx[e]];
    lv = lv < MAXLV-1 ? lv : MAXLV-1;
    atomicAdd(&ehist[lv], 1);
  }
  for (int n = tid; n < Nn; n += 1024) {
    int lv = node_level[n];
    lv = lv < MAXLV-1 ? lv : MAXLV-1;
    atomicAdd(&nhist[lv], 1);
  }
  __syncthreads();
  if (tid == 0) {
    int s = 0, t = 0;
    for (int l = 0; l < MAXLV; l++) {
      ecur[l] = s; lvloff[l] = s; s += ehist[l];
      ncur[l] = t; nlvloff[l] = t; t += nhist[l];
    }
    lvloff[MAXLV] = s; nlvloff[MAXLV] = t;
  }
  __syncthreads();
  for (int e = tid; e < E; e += 1024) {
    int lv = node_level[child_idx[e]];
    lv = lv < MAXLV-1 ? lv : MAXLV-1;
    elist[atomicAdd(&ecur[lv], 1)] = e;
  }
  for (int n = tid; n < Nn; n += 1024) {
    int lv = node_level[n];
    lv = lv < MAXLV-1 ? lv : MAXLV-1;
    nlist[atomicAdd(&ncur[lv], 1)] = n;
  }
}

// ---------------- tree level loop with epoch-flag barrier -------------------
__device__ __forceinline__ void tree_barrier(int* flags, int nb, int epoch){
  __syncthreads();
  if (threadIdx.x == 0)
    __hip_atomic_store(&flags[blockIdx.x << 5], epoch, __ATOMIC_RELEASE,
                       __HIP_MEMORY_SCOPE_AGENT);
  if (threadIdx.x < 64) {
    long guard = 0;
    for (;;) {
      int v = ((int)threadIdx.x < nb)
        ? __hip_atomic_load(&flags[threadIdx.x << 5], __ATOMIC_RELAXED,
                            __HIP_MEMORY_SCOPE_AGENT) : epoch;
      if (__all(v >= epoch)) break;
      __builtin_amdgcn_s_sleep(1);
      if (++guard > 30000000L) break;
    }
    __builtin_amdgcn_fence(__ATOMIC_ACQUIRE, "agent");
  }
  __syncthreads();
}

__global__ __launch_bounds__(256) void tree_kernel(
    const int* __restrict__ nlv_ptr, const int* __restrict__ node_level,
    const int* __restrict__ child_idx, const int* __restrict__ parent_idx,
    const int* __restrict__ elist, const int* __restrict__ lvloff,
    const int* __restrict__ nlist, const int* __restrict__ nlvloff,
    const float* __restrict__ Uiou, const float* __restrict__ Uf,
    const float* __restrict__ biou, const float* __restrict__ buf_,
    float* __restrict__ iou, float* __restrict__ cnode,
    float* __restrict__ cred, float* __restrict__ hout,
    int* __restrict__ flags, int Nn)
{
  int n_lv = nlv_ptr[0];
  if (n_lv > MAXLV) n_lv = MAXLV;
  const int tid = threadIdx.x;
  __shared__ float hs[8][256];
  __shared__ float cs[8][256];
  __shared__ int pidx[8];
  int ep = 1;
  for (int l = 0; l < n_lv; l++) {
    const int na = nlvloff[l], nbnd = nlvloff[l+1];
    for (int it = blockIdx.x*256 + tid; it < (nbnd-na)*64; it += gridDim.x*256) {
      const int n = nlist[na + (it >> 6)];
      const int q = (it & 63) << 2;
      const float4 iv = *(const float4*)&iou[(size_t)n*GG3 + q];
      const float4 ov = *(const float4*)&iou[(size_t)n*GG3 + 256 + q];
      const float4 uv = *(const float4*)&iou[(size_t)n*GG3 + 512 + q];
      const float4 bi = *(const float4*)&biou[q];
      const float4 bo = *(const float4*)&biou[256 + q];
      const float4 bu = *(const float4*)&biou[512 + q];
      const float4 cr = *(const float4*)&cred[(size_t)n*HID + q];
      float cn[4], hn[4];
      cn[0] = sigf(iv.x+bi.x)*tanh_(uv.x+bu.x) + cr.x;
      cn[1] = sigf(iv.y+bi.y)*tanh_(uv.y+bu.y) + cr.y;
      cn[2] = sigf(iv.z+bi.z)*tanh_(uv.z+bu.z) + cr.z;
      cn[3] = sigf(iv.w+bi.w)*tanh_(uv.w+bu.w) + cr.w;
      hn[0] = sigf(ov.x+bo.x)*tanh_(cn[0]);
      hn[1] = sigf(ov.y+bo.y)*tanh_(cn[1]);
      hn[2] = sigf(ov.z+bo.z)*tanh_(cn[2]);
      hn[3] = sigf(ov.w+bo.w)*tanh_(cn[3]);
      *(float4*)&cnode[(size_t)n*HID + q] = make_float4(cn[0],cn[1],cn[2],cn[3]);
      *(float4*)&hout [(size_t)n*HID + q] = make_float4(hn[0],hn[1],hn[2],hn[3]);
    }
    tree_barrier(flags, gridDim.x, ep++);
    const int e0 = lvloff[l], e1 = lvloff[l+1];
    const int nb = (e1 - e0 + 7) >> 3;
    for (int bat = blockIdx.x; bat < nb; bat += gridDim.x) {
      const int base = e0 + (bat << 3);
      const int c8 = (e1 - base) < 8 ? (e1 - base) : 8;
      __syncthreads();
      for (int li = tid; li < 1024; li += 256) {
        const int j = li >> 7, q = li & 127;
        if (j < c8) {
          const int e = elist[base + j];
          const int ch = child_idx[e];
          if (q < 64) *(float4*)&hs[j][q<<2]      = *(const float4*)&hout [(size_t)ch*HID + (q<<2)];
          else        *(float4*)&cs[j][(q-64)<<2] = *(const float4*)&cnode[(size_t)ch*HID + ((q-64)<<2)];
        }
      }
      if (tid < 8) pidx[tid] = (tid < c8) ? parent_idx[elist[base + tid]] : -1;
      __syncthreads();
      float acc[8][4] = {};
      const int qq = tid;
      const float* __restrict__ w0 = (qq < 192)
          ? (Uiou + (size_t)(qq<<2)*HID)
          : (Uf   + (size_t)((qq-192)<<2)*HID);
#pragma unroll 2
      for (int k4 = 0; k4 < 64; k4++) {
        const int kof = k4 << 2;
        const float4 a0 = *(const float4*)&w0[kof];
        const float4 a1 = *(const float4*)&w0[HID   + kof];
        const float4 a2 = *(const float4*)&w0[2*HID + kof];
        const float4 a3 = *(const float4*)&w0[3*HID + kof];
#pragma unroll
        for (int j = 0; j < 8; j++) {
          const float4 hv = *(const float4*)&hs[j][kof];
          acc[j][0] += hv.x*a0.x + hv.y*a0.y + hv.z*a0.z + hv.w*a0.w;
          acc[j][1] += hv.x*a1.x + hv.y*a1.y + hv.z*a1.z + hv.w*a1.w;
          acc[j][2] += hv.x*a2.x + hv.y*a2.y + hv.z*a2.z + hv.w*a2.w;
          acc[j][3] += hv.x*a3.x + hv.y*a3.y + hv.z*a3.z + hv.w*a3.w;
        }
      }
      if (qq < 192) {
#pragma unroll
        for (int j = 0; j < 8; j++) {
          const int p = pidx[j];
          if (p < 0) continue;
          float* dst = &iou[(size_t)p*GG3 + (qq<<2)];
          unsafeAtomicAdd(dst+0, acc[j][0]);
          unsafeAtomicAdd(dst+1, acc[j][1]);
          unsafeAtomicAdd(dst+2, acc[j][2]);
          unsafeAtomicAdd(dst+3, acc[j][3]);
        }
      } else {
        const int r0 = (qq-192) << 2;
        const float4 bv = *(const float4*)&buf_[r0];
#pragma unroll
        for (int j = 0; j < 8; j++) {
          const int p = pidx[j];
          if (p < 0) continue;
          float* dst = &cred[(size_t)p*HID + r0];
          unsafeAtomicAdd(dst+0, sigf(acc[j][0]+bv.x)*cs[j][r0+0]);
          unsafeAtomicAdd(dst+1, sigf(acc[j][1]+bv.y)*cs[j][r0+1]);
          unsafeAtomicAdd(dst+2, sigf(acc[j][2]+bv.z)*cs[j][r0+2]);
          unsafeAtomicAdd(dst+3, sigf(acc[j][3]+bv.w)*cs[j][r0+3]);
        }
      }
    }
    tree_barrier(flags, gridDim.x, ep++);
  }
}

// ---------------- launch ------------------------------------------------------
extern "C" void kernel_launch(void* const* d_in, const int* in_sizes, int n_in,
                              void* d_out, int out_size, void* d_ws, size_t ws_size,
                              hipStream_t stream)
{
  const int*   embed_ids = (const int*)d_in[0];
  const int*   lengths   = (const int*)d_in[1];
  const int*   child_idx = (const int*)d_in[2];
  const int*   parent_idx= (const int*)d_in[3];
  const int*   tok_idx   = (const int*)d_in[4];
  const int*   node_level= (const int*)d_in[5];
  const int*   nlv       = (const int*)d_in[6];
  const float* emb  = (const float*)d_in[7];
  const float* wihf = (const float*)d_in[8];
  const float* whhf = (const float*)d_in[9];
  const float* bf   = (const float*)d_in[10];
  const float* wihb = (const float*)d_in[11];
  const float* whhb = (const float*)d_in[12];
  const float* bb   = (const float*)d_in[13];
  const float* Wiou = (const float*)d_in[14];
  const float* Uiou = (const float*)d_in[15];
  const float* biou = (const float*)d_in[16];
  const float* Uf   = (const float*)d_in[17];
  const float* buf_ = (const float*)d_in[18];
  const int E  = in_sizes[2];
  const int Nn = in_sizes[4];
  float* hout = (float*)d_out;

  char* w = (char*)d_ws;
  size_t off = 0;
  auto take = [&](size_t bytes) -> char* {
    char* p = w + off;
    off += (bytes + 255) & ~(size_t)255;
    return p;
  };
  int*   flags = (int*)  take(8192);                       // zeroed: tree barrier flags
  float* cred  = (float*)take((size_t)Nn*HID*4);           // zeroed
  size_t zero_end = off;
  float* x     = (float*)take((size_t)8192*300*4);
  float* xgf   = (float*)take((size_t)8192*1024*4);
  float* xgb   = (float*)take((size_t)8192*1024*4);
  float* wtf   = (float*)take((size_t)64*1024*16);
  float* wtb   = (float*)take((size_t)64*1024*16);
  float* hsf   = (float*)take((size_t)64*128*256*4);
  float* hsb   = (float*)take((size_t)64*128*256*4);
  float* hx    = (float*)take((size_t)Nn*512*4);
  float* iou   = (float*)take((size_t)Nn*GG3*4);
  float* cnode = (float*)take((size_t)Nn*HID*4);
  int*   elist = (int*)  take((size_t)E*4);
  int*   lvloff= (int*)  take((size_t)(MAXLV+1)*4);
  int*   nlist = (int*)  take((size_t)Nn*4);
  int*   nlvloff=(int*)  take((size_t)(MAXLV+1)*4);
  (void)ws_size; (void)n_in; (void)out_size;

  hipMemsetAsync(d_ws, 0, zero_end, stream);
  gather_x_kernel<<<(8192*75 + 255)/256, 256, 0, stream>>>(embed_ids, emb, x);
  gemm_kernel<true><<<dim3(8192/128, 1024/128), 256, 0, stream>>>(x, wihf, bf, xgf, 8192, 1024, 300);
  gemm_kernel<true><<<dim3(8192/128, 1024/128), 256, 0, stream>>>(x, wihb, bb, xgb, 8192, 1024, 300);
  transpose_w_kernel<<<(2*1024*64 + 255)/256, 256, 0, stream>>>(whhf, whhb, wtf, wtb);
  lstm_kernel<<<64, 1024, 0, stream>>>(xgf, xgb, wtf, wtb, lengths, hsf, hsb);
  gather_hx_kernel<<<(Nn*128 + 255)/256, 256, 0, stream>>>(tok_idx, hsf, hsb, hx, Nn);
  gemm_kernel<false><<<dim3((Nn+127)/128, GG3/128), 256, 0, stream>>>(hx, Wiou, nullptr, iou, Nn, GG3, 512);
  sort_kernel<<<1, 1024, 0, stream>>>(child_idx, node_level, elist, lvloff, nlist, nlvloff, E, Nn);
  tree_kernel<<<64, 256, 0, stream>>>(nlv, node_level, child_idx, parent_idx, elist, lvloff,
                                      nlist, nlvloff, Uiou, Uf, biou, buf_,
                                      iou, cnode, cred, hout, flags, Nn);
}

// Round 6
// 2287.155 us; speedup vs baseline: 1.8134x; 1.1251x over previous
//
#include <hip/hip_runtime.h>
#include <hip/hip_fp16.h>
#include <cstdint>
#include <cstddef>

#define TT 128
#define HID 256
#define GG4 1024
#define GG3 768
#define MAXLV 64

__device__ __forceinline__ float sigf(float x){ return 1.f/(1.f+__expf(-x)); }
__device__ __forceinline__ float tanh_(float x){
  float cx = fminf(fmaxf(x,-15.f),15.f);
  float e = __expf(2.f*cx);
  return (e-1.f)/(e+1.f);
}

// ---------------- embedding gather: x[m][e] = emb[ids[m]][e] ----------------
__global__ __launch_bounds__(256) void gather_x_kernel(
    const int* __restrict__ ids, const float* __restrict__ emb, float* __restrict__ x)
{
  int it = blockIdx.x*256 + threadIdx.x;        // item = m*75 + q  (300 = 75 float4)
  if (it >= 8192*75) return;
  int m = it / 75, q = (it % 75) * 4;
  int id = ids[m];
  *(float4*)&x[(size_t)m*300 + q] = *(const float4*)&emb[(size_t)id*300 + q];
}

// ---------------- tiled GEMM 128x128, 8x8/thread: C[m][n] = A[m]·W[n] (+bias)
template<bool BIAS>
__global__ __launch_bounds__(256) void gemm_kernel(
    const float* __restrict__ A, const float* __restrict__ W,
    const float* __restrict__ bias, float* __restrict__ C,
    int M, int Nn, int K)
{
  __shared__ float As[16][132];
  __shared__ float Ws[16][132];
  const int tid = threadIdx.x;
  const int m0 = blockIdx.x * 128, n0 = blockIdx.y * 128;
  const int tx = tid & 15, ty = tid >> 4;
  const int srow = tid >> 1, skof = (tid & 1) << 3;
  float acc[8][8] = {};
  for (int k0 = 0; k0 < K; k0 += 16) {
    float a_[8], w_[8];
    const int gm = m0 + srow, gn = n0 + srow;
#pragma unroll
    for (int j = 0; j < 8; j++) {
      const int kk = k0 + skof + j;
      a_[j] = (gm < M && kk < K) ? A[(size_t)gm*K + kk] : 0.f;
      w_[j] = (kk < K) ? W[(size_t)gn*K + kk] : 0.f;
    }
    __syncthreads();
#pragma unroll
    for (int j = 0; j < 8; j++) { As[skof+j][srow] = a_[j]; Ws[skof+j][srow] = w_[j]; }
    __syncthreads();
#pragma unroll
    for (int k = 0; k < 16; k++) {
      const float4 a0 = *(const float4*)&As[k][ty << 3];
      const float4 a1 = *(const float4*)&As[k][(ty << 3) + 4];
      const float4 b0 = *(const float4*)&Ws[k][tx << 3];
      const float4 b1 = *(const float4*)&Ws[k][(tx << 3) + 4];
      const float av[8] = {a0.x,a0.y,a0.z,a0.w,a1.x,a1.y,a1.z,a1.w};
      const float bv[8] = {b0.x,b0.y,b0.z,b0.w,b1.x,b1.y,b1.z,b1.w};
#pragma unroll
      for (int i = 0; i < 8; i++)
#pragma unroll
        for (int j = 0; j < 8; j++) acc[i][j] += av[i]*bv[j];
    }
  }
  float bvv[8] = {0,0,0,0,0,0,0,0};
  if (BIAS) {
#pragma unroll
    for (int j = 0; j < 8; j++) bvv[j] = bias[n0 + (tx<<3) + j];
  }
#pragma unroll
  for (int i = 0; i < 8; i++) {
    const int gm = m0 + (ty<<3) + i;
    if (gm >= M) continue;
    float4 o0 = make_float4(acc[i][0]+bvv[0], acc[i][1]+bvv[1], acc[i][2]+bvv[2], acc[i][3]+bvv[3]);
    float4 o1 = make_float4(acc[i][4]+bvv[4], acc[i][5]+bvv[5], acc[i][6]+bvv[6], acc[i][7]+bvv[7]);
    *(float4*)&C[(size_t)gm*Nn + n0 + (tx<<3)]     = o0;
    *(float4*)&C[(size_t)gm*Nn + n0 + (tx<<3) + 4] = o1;
  }
}

// ---------------- Whh transpose + f16: wt[k4][g][0..3] = half(W[g][4k4+i]) --
__global__ __launch_bounds__(256) void transpose_w_kernel(
    const float* __restrict__ whhf, const float* __restrict__ whhb,
    ushort* __restrict__ wtf, ushort* __restrict__ wtb)
{
  int it = blockIdx.x*256 + threadIdx.x;  // dir(1) | g(10) | k4(6)
  if (it >= 2*1024*64) return;
  int dir = it >> 16, rem = it & 65535;
  int g = rem >> 6, k4 = rem & 63;
  const float* w = dir ? whhb : whhf;
  ushort*     wt = dir ? wtb  : wtf;
  float4 v = *(const float4*)&w[(size_t)g*HID + (k4 << 2)];
  __half h0 = __float2half(v.x), h1 = __float2half(v.y);
  __half h2 = __float2half(v.z), h3 = __float2half(v.w);
  ushort4 pk;
  pk.x = *(ushort*)&h0; pk.y = *(ushort*)&h1; pk.z = *(ushort*)&h2; pk.w = *(ushort*)&h3;
  *(ushort4*)&wt[((size_t)(k4 << 10) + g) * 4] = pk;
}

// ---------------- batch-split bidirectional LSTM (no inter-block sync) ------
// 64 blocks x 1024 threads; dir = ((blk&7)>>2) XCD-grouped. 2 batch rows/block.
// f16 weights streamed from L2 (512KB/step/CU).
__global__ __launch_bounds__(1024, 1) void lstm_kernel(
    const float* __restrict__ xgf, const float* __restrict__ xgb,
    const ushort* __restrict__ wtf, const ushort* __restrict__ wtb,
    const int* __restrict__ lengths,
    float* __restrict__ hsf, float* __restrict__ hsb)
{
  const int b8  = blockIdx.x & 7;
  const int dir = b8 >> 2;
  const int p   = (blockIdx.x >> 3) * 4 + (b8 & 3);   // 0..31
  const int r0 = 2*p, r1 = r0 + 1;
  const float* __restrict__ xg = dir ? xgb : xgf;
  const uint2* __restrict__ wp = (const uint2*)(dir ? wtb : wtf) + threadIdx.x;
  float* __restrict__ hs = dir ? hsb : hsf;
  const int tid = threadIdx.x;
  const int u = tid & 255, gate = tid >> 8;

  __shared__ float hbuf[2][256];
  __shared__ float ex[4][2][256];
  if (tid < 512) hbuf[tid >> 8][tid & 255] = 0.f;
  __syncthreads();

  const int len0 = lengths[r0], len1 = lengths[r1];   // len0 >= len1
  float c0 = 0.f, c1 = 0.f;
  for (int s = 0; s < len0; s++) {
    const bool a1 = s < len1;
    const int t0 = dir ? (len0 - 1 - s) : s;
    const int t1 = dir ? (len1 - 1 - s) : s;
    const float x0 = xg[((size_t)r0*TT + t0)*GG4 + tid];
    const float x1 = a1 ? xg[((size_t)r1*TT + t1)*GG4 + tid] : 0.f;
    float acc0 = 0.f, acc1 = 0.f;
#pragma unroll 8
    for (int k4 = 0; k4 < 64; k4++) {
      uint2 wv = wp[(size_t)k4 << 10];
      const __half2 pa = *reinterpret_cast<const __half2*>(&wv.x);
      const __half2 pb = *reinterpret_cast<const __half2*>(&wv.y);
      const float2 wA = __half22float2(pa);
      const float2 wB = __half22float2(pb);
      const float4 h0 = *(const float4*)&hbuf[0][k4 << 2];
      const float4 h1 = *(const float4*)&hbuf[1][k4 << 2];
      acc0 += wA.x*h0.x + wA.y*h0.y + wB.x*h0.z + wB.y*h0.w;
      acc1 += wA.x*h1.x + wA.y*h1.y + wB.x*h1.z + wB.y*h1.w;
    }
    __syncthreads();                       // hbuf reads done
    ex[gate][0][u] = acc0 + x0;
    ex[gate][1][u] = acc1 + x1;
    __syncthreads();                       // gate pre-acts published
    if (gate == 0) {
      {
        const float ig = sigf(ex[0][0][u]);
        const float fg = sigf(ex[1][0][u]);
        const float gg = tanh_(ex[2][0][u]);
        const float og = sigf(ex[3][0][u]);
        c0 = fg*c0 + ig*gg;
        const float h = og*tanh_(c0);
        hbuf[0][u] = h;
        hs[((size_t)r0*TT + t0)*HID + u] = h;
      }
      if (a1) {
        const float ig = sigf(ex[0][1][u]);
        const float fg = sigf(ex[1][1][u]);
        const float gg = tanh_(ex[2][1][u]);
        const float og = sigf(ex[3][1][u]);
        c1 = fg*c1 + ig*gg;
        const float h = og*tanh_(c1);
        hbuf[1][u] = h;
        hs[((size_t)r1*TT + t1)*HID + u] = h;
      }
    }
    __syncthreads();                       // new h visible to all waves
  }
}

// ---------------- hx = concat(h_f[tok], h_b[tok]) ---------------------------
__global__ __launch_bounds__(256) void gather_hx_kernel(
    const int* __restrict__ tok, const float* __restrict__ hsf,
    const float* __restrict__ hsb, float* __restrict__ hx, int Nn)
{
  int it = blockIdx.x*256 + threadIdx.x;     // item = n*128 + q
  if (it >= Nn*128) return;
  int n = it >> 7, q = it & 127;
  int tk = tok[n];
  int b = tk >> 7, t = tk & 127;
  float4 v;
  if (q < 64) v = *(const float4*)&hsf[((size_t)b*TT + t)*HID + (q<<2)];
  else        v = *(const float4*)&hsb[((size_t)b*TT + t)*HID + ((q-64)<<2)];
  *(float4*)&hx[(size_t)n*512 + (q<<2)] = v;
}

// ---------------- UT[k][r] = (r<768 ? Uiou[r][k] : Uf[r-768][k]) ------------
__global__ __launch_bounds__(256) void ut_kernel(
    const float* __restrict__ Uiou, const float* __restrict__ Uf,
    float* __restrict__ UT)
{
  int idx = blockIdx.x*256 + threadIdx.x;
  if (idx >= 256*1024) return;
  int k = idx >> 10, r = idx & 1023;
  UT[idx] = (r < 768) ? Uiou[(size_t)r*HID + k] : Uf[(size_t)(r-768)*HID + k];
}

// ---------------- node sort by level + children CSR by parent ---------------
__global__ __launch_bounds__(1024) void sort_kernel(
    const int* __restrict__ child_idx, const int* __restrict__ parent_idx,
    const int* __restrict__ node_level,
    int* __restrict__ nlist, int* __restrict__ nlvloff,
    int* __restrict__ choff, int* __restrict__ chlist,
    int* __restrict__ deg /* zeroed; reused as cursor */, int E, int Nn)
{
  __shared__ int nhist[MAXLV], ncur[MAXLV];
  __shared__ int part[1024];
  const int tid = threadIdx.x;
  if (tid < MAXLV) nhist[tid] = 0;
  __syncthreads();
  for (int n = tid; n < Nn; n += 1024) {
    int lv = node_level[n]; lv = lv < MAXLV-1 ? lv : MAXLV-1;
    atomicAdd(&nhist[lv], 1);
  }
  for (int e = tid; e < E; e += 1024) atomicAdd(&deg[parent_idx[e]], 1);
  __syncthreads();
  if (tid == 0) {
    int t = 0;
    for (int l = 0; l < MAXLV; l++) { ncur[l] = t; nlvloff[l] = t; t += nhist[l]; }
    nlvloff[MAXLV] = t;
  }
  __syncthreads();
  for (int n = tid; n < Nn; n += 1024) {
    int lv = node_level[n]; lv = lv < MAXLV-1 ? lv : MAXLV-1;
    nlist[atomicAdd(&ncur[lv], 1)] = n;
  }
  __syncthreads();
  // exclusive scan of deg -> choff (chunked Hillis-Steele)
  int loc[8]; int s = 0;
#pragma unroll
  for (int m = 0; m < 8; m++) {
    const int i = tid*8 + m;
    loc[m] = s;
    s += (i < Nn) ? deg[i] : 0;
  }
  part[tid] = s;
  __syncthreads();
  for (int off = 1; off < 1024; off <<= 1) {
    int v = (tid >= off) ? part[tid - off] : 0;
    __syncthreads();
    part[tid] += v;
    __syncthreads();
  }
  const int pre = (tid > 0) ? part[tid-1] : 0;
#pragma unroll
  for (int m = 0; m < 8; m++) {
    const int i = tid*8 + m;
    if (i < Nn) { choff[i] = pre + loc[m]; }
  }
  if (tid == 1023) choff[Nn] = part[1023];
  __syncthreads();
#pragma unroll
  for (int m = 0; m < 8; m++) {           // cursor = choff copy (deg reused)
    const int i = tid*8 + m;
    if (i < Nn) deg[i] = pre + loc[m];
  }
  __syncthreads();
  for (int e = tid; e < E; e += 1024) {
    int pos = atomicAdd(&deg[parent_idx[e]], 1);
    chlist[pos] = child_idx[e];
  }
}

// ---------------- tree: gather-based level loop (NO atomics) ----------------
// 256 blocks x 256 threads. Per level l (1 phase pair):
//  A: per 16-node group: acc = iou_base + sum children um ; cred = sum fm ;
//     apply -> c,h (written to cnode/hout)
//  B: per (16-node group, 256-row group): emit um = U_iou·h (rows<768),
//     fm = sig(Uf·h + b_uf)*c (rows>=768). Tiled GEMM, UT k-major.
__device__ __forceinline__ void tree_barrier(int* flags, int epoch){
  __syncthreads();
  if (threadIdx.x == 0)
    __hip_atomic_store(&flags[blockIdx.x << 5], epoch, __ATOMIC_RELEASE,
                       __HIP_MEMORY_SCOPE_AGENT);
  if (threadIdx.x < 64) {
    long guard = 0;
    for (;;) {
      int mn = 0x7fffffff;
#pragma unroll
      for (int i = 0; i < 4; i++) {
        int v = __hip_atomic_load(&flags[(threadIdx.x + (i << 6)) << 5],
                                  __ATOMIC_RELAXED, __HIP_MEMORY_SCOPE_AGENT);
        mn = mn < v ? mn : v;
      }
      if (__all(mn >= epoch)) break;
      __builtin_amdgcn_s_sleep(1);
      if (++guard > 30000000L) break;
    }
    __builtin_amdgcn_fence(__ATOMIC_ACQUIRE, "agent");
  }
  __syncthreads();
}

__global__ __launch_bounds__(256) void tree_kernel(
    const int* __restrict__ nlv_ptr,
    const int* __restrict__ nlist, const int* __restrict__ nlvloff,
    const int* __restrict__ choff, const int* __restrict__ chlist,
    const float* __restrict__ UT,
    const float* __restrict__ biou, const float* __restrict__ buf_,
    const float* __restrict__ iou,
    float* __restrict__ um, float* __restrict__ fm,
    float* __restrict__ cnode, float* __restrict__ hout,
    int* __restrict__ flags)
{
  int n_lv = nlv_ptr[0];
  if (n_lv > MAXLV) n_lv = MAXLV;
  const int tid = threadIdx.x;
  __shared__ float tlds[16*1040];          // A: acc[16][1040] ; B: hl[16][260]
  __shared__ int nids[16];
  int ep = 1;
  for (int l = 0; l < n_lv; l++) {
    const int na = nlvloff[l];
    const int nL = nlvloff[l+1] - na;
    const int ngs = (nL + 15) >> 4;
    // ---------------- Phase A: gather + apply ----------------
    for (int ng = blockIdx.x; ng < ngs; ng += gridDim.x) {
      __syncthreads();
      const int j = tid >> 4, q = tid & 15;
      const int jn = (ng << 4) + j;
      const int n = (jn < nL) ? nlist[na + jn] : -1;
      float* accj = tlds + j*1040;
      if (n >= 0) {
#pragma unroll
        for (int it = 0; it < 12; ++it) {
          const int d = it*64 + (q << 2);
          *(float4*)&accj[d] = *(const float4*)&iou[(size_t)n*GG3 + d];
        }
#pragma unroll
        for (int it = 0; it < 4; ++it) {
          const int d = 768 + it*64 + (q << 2);
          *(float4*)&accj[d] = make_float4(0.f,0.f,0.f,0.f);
        }
        const int e0 = choff[n], e1 = choff[n+1];
        for (int e = e0; e < e1; ++e) {
          const int ch = chlist[e];
          const float* umc = um + (size_t)ch*GG3;
          const float* fmc = fm + (size_t)ch*HID;
#pragma unroll
          for (int it = 0; it < 12; ++it) {
            const int d = it*64 + (q << 2);
            const float4 v = *(const float4*)&umc[d];
            float4 a = *(float4*)&accj[d];
            a.x += v.x; a.y += v.y; a.z += v.z; a.w += v.w;
            *(float4*)&accj[d] = a;
          }
#pragma unroll
          for (int it = 0; it < 4; ++it) {
            const int d = it*64 + (q << 2);
            const float4 v = *(const float4*)&fmc[d];
            float4 a = *(float4*)&accj[768 + d];
            a.x += v.x; a.y += v.y; a.z += v.z; a.w += v.w;
            *(float4*)&accj[768 + d] = a;
          }
        }
      }
      __syncthreads();
      if (n >= 0) {
#pragma unroll
        for (int k = 0; k < 16; ++k) {
          const int u = q + (k << 4);
          const float i_ = accj[u]       + biou[u];
          const float o_ = accj[256 + u] + biou[256 + u];
          const float uu = accj[512 + u] + biou[512 + u];
          const float cr = accj[768 + u];
          const float cv = sigf(i_)*tanh_(uu) + cr;
          const float hv = sigf(o_)*tanh_(cv);
          cnode[(size_t)n*HID + u] = cv;
          hout [(size_t)n*HID + u] = hv;
        }
      }
    }
    tree_barrier(flags, ep++);
    // ---------------- Phase B: emit messages (tiled GEMM) ----------------
    float* hl = tlds;                       // [16][260]
    const int tiles = ngs << 2;
    for (int tl = blockIdx.x; tl < tiles; tl += gridDim.x) {
      const int ng = tl >> 2, rg = tl & 3;
      __syncthreads();
      if (tid < 16) {
        const int jn = (ng << 4) + tid;
        nids[tid] = (jn < nL) ? nlist[na + jn] : -1;
      }
      __syncthreads();
#pragma unroll
      for (int it = 0; it < 4; ++it) {
        const int idx = it*256 + tid;
        const int jj = idx >> 6, d = (idx & 63) << 2;
        const int n2 = nids[jj];
        float4 v = make_float4(0.f,0.f,0.f,0.f);
        if (n2 >= 0) v = *(const float4*)&hout[(size_t)n2*HID + d];
        *(float4*)&hl[jj*260 + d] = v;
      }
      __syncthreads();
      const int lane = tid & 63, j0 = (tid >> 6) << 2;
      float acc[4][4] = {};
      for (int k4 = 0; k4 < 64; ++k4) {
        const int kb = k4 << 2;
        const float4 hv0 = *(const float4*)&hl[(j0+0)*260 + kb];
        const float4 hv1 = *(const float4*)&hl[(j0+1)*260 + kb];
        const float4 hv2 = *(const float4*)&hl[(j0+2)*260 + kb];
        const float4 hv3 = *(const float4*)&hl[(j0+3)*260 + kb];
#pragma unroll
        for (int i = 0; i < 4; ++i) {
          const float* ur = UT + ((size_t)kb << 10) + (rg << 8) + lane + (i << 6);
          const float w0 = ur[0], w1 = ur[1024], w2 = ur[2048], w3 = ur[3072];
          acc[i][0] += w0*hv0.x + w1*hv0.y + w2*hv0.z + w3*hv0.w;
          acc[i][1] += w0*hv1.x + w1*hv1.y + w2*hv1.z + w3*hv1.w;
          acc[i][2] += w0*hv2.x + w1*hv2.y + w2*hv2.z + w3*hv2.w;
          acc[i][3] += w0*hv3.x + w1*hv3.y + w2*hv3.z + w3*hv3.w;
        }
      }
      if (rg < 3) {
#pragma unroll
        for (int i = 0; i < 4; ++i) {
          const int row = (rg << 8) + lane + (i << 6);
#pragma unroll
          for (int jj = 0; jj < 4; ++jj) {
            const int n2 = nids[j0 + jj];
            if (n2 >= 0) um[(size_t)n2*GG3 + row] = acc[i][jj];
          }
        }
      } else {
#pragma unroll
        for (int i = 0; i < 4; ++i) {
          const int fr = lane + (i << 6);
          const float b = buf_[fr];
#pragma unroll
          for (int jj = 0; jj < 4; ++jj) {
            const int n2 = nids[j0 + jj];
            if (n2 >= 0)
              fm[(size_t)n2*HID + fr] =
                sigf(acc[i][jj] + b) * cnode[(size_t)n2*HID + fr];
          }
        }
      }
    }
    tree_barrier(flags, ep++);
  }
}

// ---------------- launch ------------------------------------------------------
extern "C" void kernel_launch(void* const* d_in, const int* in_sizes, int n_in,
                              void* d_out, int out_size, void* d_ws, size_t ws_size,
                              hipStream_t stream)
{
  const int*   embed_ids = (const int*)d_in[0];
  const int*   lengths   = (const int*)d_in[1];
  const int*   child_idx = (const int*)d_in[2];
  const int*   parent_idx= (const int*)d_in[3];
  const int*   tok_idx   = (const int*)d_in[4];
  const int*   node_level= (const int*)d_in[5];
  const int*   nlv       = (const int*)d_in[6];
  const float* emb  = (const float*)d_in[7];
  const float* wihf = (const float*)d_in[8];
  const float* whhf = (const float*)d_in[9];
  const float* bf   = (const float*)d_in[10];
  const float* wihb = (const float*)d_in[11];
  const float* whhb = (const float*)d_in[12];
  const float* bb   = (const float*)d_in[13];
  const float* Wiou = (const float*)d_in[14];
  const float* Uiou = (const float*)d_in[15];
  const float* biou = (const float*)d_in[16];
  const float* Uf   = (const float*)d_in[17];
  const float* buf_ = (const float*)d_in[18];
  const int E  = in_sizes[2];
  const int Nn = in_sizes[4];
  float* hout = (float*)d_out;

  char* w = (char*)d_ws;
  size_t off = 0;
  auto take = [&](size_t bytes) -> char* {
    char* p = w + off;
    off += (bytes + 255) & ~(size_t)255;
    return p;
  };
  int*    flags = (int*)   take(32768);                    // zeroed: tree barrier
  int*    deg   = (int*)   take((size_t)(Nn+1)*4);         // zeroed: CSR degree/cursor
  size_t zero_end = off;
  float*  x     = (float*) take((size_t)8192*300*4);
  float*  xgf   = (float*) take((size_t)8192*1024*4);
  float*  xgb   = (float*) take((size_t)8192*1024*4);
  ushort* wtf   = (ushort*)take((size_t)64*1024*4*2);      // f16
  ushort* wtb   = (ushort*)take((size_t)64*1024*4*2);
  float*  hsf   = (float*) take((size_t)64*128*256*4);
  float*  hsb   = (float*) take((size_t)64*128*256*4);
  float*  hx    = (float*) take((size_t)Nn*512*4);
  float*  iou   = (float*) take((size_t)Nn*GG3*4);
  float*  um    = (float*) take((size_t)Nn*GG3*4);
  float*  fm    = (float*) take((size_t)Nn*HID*4);
  float*  cnode = (float*) take((size_t)Nn*HID*4);
  float*  UT    = (float*) take((size_t)256*1024*4);
  int*    nlist = (int*)   take((size_t)Nn*4);
  int*    nlvloff=(int*)   take((size_t)(MAXLV+1)*4);
  int*    choff = (int*)   take((size_t)(Nn+1)*4);
  int*    chlist= (int*)   take((size_t)(E>0?E:1)*4);
  (void)ws_size; (void)n_in; (void)out_size; (void)node_level;

  hipMemsetAsync(d_ws, 0, zero_end, stream);
  gather_x_kernel<<<(8192*75 + 255)/256, 256, 0, stream>>>(embed_ids, emb, x);
  gemm_kernel<true><<<dim3(8192/128, 1024/128), 256, 0, stream>>>(x, wihf, bf, xgf, 8192, 1024, 300);
  gemm_kernel<true><<<dim3(8192/128, 1024/128), 256, 0, stream>>>(x, wihb, bb, xgb, 8192, 1024, 300);
  transpose_w_kernel<<<(2*1024*64 + 255)/256, 256, 0, stream>>>(whhf, whhb, wtf, wtb);
  lstm_kernel<<<64, 1024, 0, stream>>>(xgf, xgb, wtf, wtb, lengths, hsf, hsb);
  gather_hx_kernel<<<(Nn*128 + 255)/256, 256, 0, stream>>>(tok_idx, hsf, hsb, hx, Nn);
  gemm_kernel<false><<<dim3((Nn+127)/128, GG3/128), 256, 0, stream>>>(hx, Wiou, nullptr, iou, Nn, GG3, 512);
  ut_kernel<<<(256*1024 + 255)/256, 256, 0, stream>>>(Uiou, Uf, UT);
  sort_kernel<<<1, 1024, 0, stream>>>(child_idx, parent_idx, node_level,
                                      nlist, nlvloff, choff, chlist, deg, E, Nn);
  tree_kernel<<<256, 256, 0, stream>>>(nlv, nlist, nlvloff, choff, chlist, UT,
                                       biou, buf_, iou, um, fm, cnode, hout, flags);
}

// Round 10
// 1741.804 us; speedup vs baseline: 2.3811x; 1.3131x over previous
//
#include <hip/hip_runtime.h>
#include <hip/hip_fp16.h>
#include <cstdint>
#include <cstddef>

#define TT 128
#define HID 256
#define GG4 1024
#define GG3 768
#define MAXLV 64

typedef _Float16 f16x2 __attribute__((ext_vector_type(2)));
typedef _Float16 f16x8 __attribute__((ext_vector_type(8)));

union f16x8u { f16x8 v; f16x2 p[4]; };

__device__ __forceinline__ float sigf(float x){ return 1.f/(1.f+__expf(-x)); }
__device__ __forceinline__ float tanh_(float x){
  float cx = fminf(fmaxf(x,-15.f),15.f);
  float e = __expf(2.f*cx);
  return (e-1.f)/(e+1.f);
}

__device__ __forceinline__ float dot2(f16x2 a, f16x2 b, float c){
#if __has_builtin(__builtin_amdgcn_fdot2)
  return __builtin_amdgcn_fdot2(a, b, c, false);
#else
  return c + (float)a[0]*(float)b[0] + (float)a[1]*(float)b[1];
#endif
}

// ---------------- embedding gather: x[m][e] = emb[ids[m]][e] ----------------
__global__ __launch_bounds__(256) void gather_x_kernel(
    const int* __restrict__ ids, const float* __restrict__ emb, float* __restrict__ x)
{
  int it = blockIdx.x*256 + threadIdx.x;        // item = m*75 + q  (300 = 75 float4)
  if (it >= 8192*75) return;
  int m = it / 75, q = (it % 75) * 4;
  int id = ids[m];
  *(float4*)&x[(size_t)m*300 + q] = *(const float4*)&emb[(size_t)id*300 + q];
}

// ---------------- tiled GEMM 128x128, 8x8/thread: C[m][n] = A[m]·W[n] (+bias)
template<bool BIAS>
__global__ __launch_bounds__(256) void gemm_kernel(
    const float* __restrict__ A, const float* __restrict__ W,
    const float* __restrict__ bias, float* __restrict__ C,
    int M, int Nn, int K)
{
  __shared__ float As[16][132];
  __shared__ float Ws[16][132];
  const int tid = threadIdx.x;
  const int m0 = blockIdx.x * 128, n0 = blockIdx.y * 128;
  const int tx = tid & 15, ty = tid >> 4;
  const int srow = tid >> 1, skof = (tid & 1) << 3;
  float acc[8][8] = {};
  for (int k0 = 0; k0 < K; k0 += 16) {
    float a_[8], w_[8];
    const int gm = m0 + srow, gn = n0 + srow;
#pragma unroll
    for (int j = 0; j < 8; j++) {
      const int kk = k0 + skof + j;
      a_[j] = (gm < M && kk < K) ? A[(size_t)gm*K + kk] : 0.f;
      w_[j] = (kk < K) ? W[(size_t)gn*K + kk] : 0.f;
    }
    __syncthreads();
#pragma unroll
    for (int j = 0; j < 8; j++) { As[skof+j][srow] = a_[j]; Ws[skof+j][srow] = w_[j]; }
    __syncthreads();
#pragma unroll
    for (int k = 0; k < 16; k++) {
      const float4 a0 = *(const float4*)&As[k][ty << 3];
      const float4 a1 = *(const float4*)&As[k][(ty << 3) + 4];
      const float4 b0 = *(const float4*)&Ws[k][tx << 3];
      const float4 b1 = *(const float4*)&Ws[k][(tx << 3) + 4];
      const float av[8] = {a0.x,a0.y,a0.z,a0.w,a1.x,a1.y,a1.z,a1.w};
      const float bv[8] = {b0.x,b0.y,b0.z,b0.w,b1.x,b1.y,b1.z,b1.w};
#pragma unroll
      for (int i = 0; i < 8; i++)
#pragma unroll
        for (int j = 0; j < 8; j++) acc[i][j] += av[i]*bv[j];
    }
  }
  float bvv[8] = {0,0,0,0,0,0,0,0};
  if (BIAS) {
#pragma unroll
    for (int j = 0; j < 8; j++) bvv[j] = bias[n0 + (tx<<3) + j];
  }
#pragma unroll
  for (int i = 0; i < 8; i++) {
    const int gm = m0 + (ty<<3) + i;
    if (gm >= M) continue;
    float4 o0 = make_float4(acc[i][0]+bvv[0], acc[i][1]+bvv[1], acc[i][2]+bvv[2], acc[i][3]+bvv[3]);
    float4 o1 = make_float4(acc[i][4]+bvv[4], acc[i][5]+bvv[5], acc[i][6]+bvv[6], acc[i][7]+bvv[7]);
    *(float4*)&C[(size_t)gm*Nn + n0 + (tx<<3)]     = o0;
    *(float4*)&C[(size_t)gm*Nn + n0 + (tx<<3) + 4] = o1;
  }
}

// ------- Whh transpose + f16 pack: wt[k8][g][0..7] = half(W[g][8k8+j]) ------
__global__ __launch_bounds__(256) void transpose_w_kernel(
    const float* __restrict__ whhf, const float* __restrict__ whhb,
    _Float16* __restrict__ wtf, _Float16* __restrict__ wtb)
{
  int it = blockIdx.x*256 + threadIdx.x;  // dir(1) | k8(5) | g(10)
  if (it >= 2*32*1024) return;
  int dir = it >> 15, rem = it & 32767;
  int k8 = rem >> 10, g = rem & 1023;
  const float* w = dir ? whhb : whhf;
  _Float16*   wt = dir ? wtb  : wtf;
  f16x8 pk;
#pragma unroll
  for (int j = 0; j < 8; j++) pk[j] = (_Float16)w[(size_t)g*HID + (k8<<3) + j];
  *(f16x8*)&wt[(((size_t)k8<<10) + g) << 3] = pk;
}

// ---------------- batch-split bidirectional LSTM (no inter-block sync) ------
// 64 blocks x 512 threads; dir = ((blk&7)>>2) XCD-grouped; 2 batch rows/block.
// Thread t owns gate rows t and t+512. f16 weights (b128 loads), f16 h in LDS,
// dot2 f32-accumulate. 2 barriers/step.
__global__ __launch_bounds__(512, 1) void lstm_kernel(
    const float* __restrict__ xgf, const float* __restrict__ xgb,
    const _Float16* __restrict__ wtf, const _Float16* __restrict__ wtb,
    const int* __restrict__ lengths,
    float* __restrict__ hsf, float* __restrict__ hsb)
{
  const int b8  = blockIdx.x & 7;
  const int dir = b8 >> 2;
  const int p   = (blockIdx.x >> 3) * 4 + (b8 & 3);   // 0..31
  const int r0 = 2*p, r1 = r0 + 1;
  const float* __restrict__ xg = dir ? xgb : xgf;
  const _Float16* __restrict__ wt = dir ? wtb : wtf;
  float* __restrict__ hs = dir ? hsb : hsf;
  const int t = threadIdx.x;
  const int u = t & 255;

  __shared__ _Float16 hb[2][256];
  __shared__ float exf[2][256];
  __shared__ float exo[2][256];
  if (t < 256) { hb[0][t] = (_Float16)0.f; hb[1][t] = (_Float16)0.f; }
  __syncthreads();

  const int len0 = lengths[r0], len1 = lengths[r1];   // len0 >= len1
  float c0 = 0.f, c1 = 0.f;
  for (int s = 0; s < len0; s++) {
    const bool a1 = s < len1;
    const int t0 = dir ? (len0 - 1 - s) : s;
    const int t1 = dir ? (len1 - 1 - s) : s;
    const float* xr0 = xg + ((size_t)r0*TT + t0)*GG4;
    const float xa0 = xr0[t], xb0 = xr0[t + 512];
    float xa1 = 0.f, xb1 = 0.f;
    if (a1) {
      const float* xr1 = xg + ((size_t)r1*TT + t1)*GG4;
      xa1 = xr1[t]; xb1 = xr1[t + 512];
    }
    float aa0 = 0.f, aa1 = 0.f, ab0 = 0.f, ab1 = 0.f;
#pragma unroll 8
    for (int k8 = 0; k8 < 32; k8++) {
      f16x8u w0, w1, h0, h1;
      w0.v = *(const f16x8*)&wt[(((size_t)k8<<10) + t) << 3];
      w1.v = *(const f16x8*)&wt[(((size_t)k8<<10) + t + 512) << 3];
      h0.v = *(const f16x8*)&hb[0][k8 << 3];
      h1.v = *(const f16x8*)&hb[1][k8 << 3];
#pragma unroll
      for (int j = 0; j < 4; j++) {
        aa0 = dot2(w0.p[j], h0.p[j], aa0);
        aa1 = dot2(w0.p[j], h1.p[j], aa1);
        ab0 = dot2(w1.p[j], h0.p[j], ab0);
        ab1 = dot2(w1.p[j], h1.p[j], ab1);
      }
    }
    if (t >= 256) {            // publish f,o pre-activations (rows 256..511, 768..1023)
      exf[0][u] = aa0 + xa0;  exf[1][u] = aa1 + xa1;
      exo[0][u] = ab0 + xb0;  exo[1][u] = ab1 + xb1;
    }
    __syncthreads();           // all hb reads done + ex visible
    if (t < 256) {
      {
        const float ig = sigf(aa0 + xa0);          // i gate (row t)
        const float gg = tanh_(ab0 + xb0);         // g gate (row t+512)
        const float fg = sigf(exf[0][u]);
        const float og = sigf(exo[0][u]);
        c0 = fg*c0 + ig*gg;
        const float h = og*tanh_(c0);
        hb[0][u] = (_Float16)h;
        hs[((size_t)r0*TT + t0)*HID + u] = h;
      }
      if (a1) {
        const float ig = sigf(aa1 + xa1);
        const float gg = tanh_(ab1 + xb1);
        const float fg = sigf(exf[1][u]);
        const float og = sigf(exo[1][u]);
        c1 = fg*c1 + ig*gg;
        const float h = og*tanh_(c1);
        hb[1][u] = (_Float16)h;
        hs[((size_t)r1*TT + t1)*HID + u] = h;
      }
    }
    __syncthreads();           // new h visible
  }
}

// ---------------- hx = concat(h_f[tok], h_b[tok]) ---------------------------
__global__ __launch_bounds__(256) void gather_hx_kernel(
    const int* __restrict__ tok, const float* __restrict__ hsf,
    const float* __restrict__ hsb, float* __restrict__ hx, int Nn)
{
  int it = blockIdx.x*256 + threadIdx.x;     // item = n*128 + q
  if (it >= Nn*128) return;
  int n = it >> 7, q = it & 127;
  int tk = tok[n];
  int b = tk >> 7, t = tk & 127;
  float4 v;
  if (q < 64) v = *(const float4*)&hsf[((size_t)b*TT + t)*HID + (q<<2)];
  else        v = *(const float4*)&hsb[((size_t)b*TT + t)*HID + ((q-64)<<2)];
  *(float4*)&hx[(size_t)n*512 + (q<<2)] = v;
}

// ---------------- UT[k][r] = (r<768 ? Uiou[r][k] : Uf[r-768][k]) ------------
__global__ __launch_bounds__(256) void ut_kernel(
    const float* __restrict__ Uiou, const float* __restrict__ Uf,
    float* __restrict__ UT)
{
  int idx = blockIdx.x*256 + threadIdx.x;
  if (idx >= 256*1024) return;
  int k = idx >> 10, r = idx & 1023;
  UT[idx] = (r < 768) ? Uiou[(size_t)r*HID + k] : Uf[(size_t)(r-768)*HID + k];
}

// ---------------- node sort by level + children CSR by parent ---------------
__global__ __launch_bounds__(1024) void sort_kernel(
    const int* __restrict__ child_idx, const int* __restrict__ parent_idx,
    const int* __restrict__ node_level,
    int* __restrict__ nlist, int* __restrict__ nlvloff,
    int* __restrict__ choff, int* __restrict__ chlist,
    int* __restrict__ deg /* zeroed; reused as cursor */, int E, int Nn)
{
  __shared__ int nhist[MAXLV], ncur[MAXLV];
  __shared__ int part[1024];
  const int tid = threadIdx.x;
  if (tid < MAXLV) nhist[tid] = 0;
  __syncthreads();
  for (int n = tid; n < Nn; n += 1024) {
    int lv = node_level[n]; lv = lv < MAXLV-1 ? lv : MAXLV-1;
    atomicAdd(&nhist[lv], 1);
  }
  for (int e = tid; e < E; e += 1024) atomicAdd(&deg[parent_idx[e]], 1);
  __syncthreads();
  if (tid == 0) {
    int t = 0;
    for (int l = 0; l < MAXLV; l++) { ncur[l] = t; nlvloff[l] = t; t += nhist[l]; }
    nlvloff[MAXLV] = t;
  }
  __syncthreads();
  for (int n = tid; n < Nn; n += 1024) {
    int lv = node_level[n]; lv = lv < MAXLV-1 ? lv : MAXLV-1;
    nlist[atomicAdd(&ncur[lv], 1)] = n;
  }
  __syncthreads();
  // exclusive scan of deg -> choff (chunked Hillis-Steele)
  int loc[8]; int s = 0;
#pragma unroll
  for (int m = 0; m < 8; m++) {
    const int i = tid*8 + m;
    loc[m] = s;
    s += (i < Nn) ? deg[i] : 0;
  }
  part[tid] = s;
  __syncthreads();
  for (int off = 1; off < 1024; off <<= 1) {
    int v = (tid >= off) ? part[tid - off] : 0;
    __syncthreads();
    part[tid] += v;
    __syncthreads();
  }
  const int pre = (tid > 0) ? part[tid-1] : 0;
#pragma unroll
  for (int m = 0; m < 8; m++) {
    const int i = tid*8 + m;
    if (i < Nn) { choff[i] = pre + loc[m]; }
  }
  if (tid == 1023) choff[Nn] = part[1023];
  __syncthreads();
#pragma unroll
  for (int m = 0; m < 8; m++) {           // cursor = choff copy (deg reused)
    const int i = tid*8 + m;
    if (i < Nn) deg[i] = pre + loc[m];
  }
  __syncthreads();
  for (int e = tid; e < E; e += 1024) {
    int pos = atomicAdd(&deg[parent_idx[e]], 1);
    chlist[pos] = child_idx[e];
  }
}

// ---------------- tree: gather-based level loop (NO atomics) ----------------
__device__ __forceinline__ void tree_barrier(int* flags, int epoch){
  __syncthreads();
  if (threadIdx.x == 0)
    __hip_atomic_store(&flags[blockIdx.x << 5], epoch, __ATOMIC_RELEASE,
                       __HIP_MEMORY_SCOPE_AGENT);
  if (threadIdx.x < 64) {
    long guard = 0;
    for (;;) {
      int mn = 0x7fffffff;
#pragma unroll
      for (int i = 0; i < 4; i++) {
        int v = __hip_atomic_load(&flags[(threadIdx.x + (i << 6)) << 5],
                                  __ATOMIC_RELAXED, __HIP_MEMORY_SCOPE_AGENT);
        mn = mn < v ? mn : v;
      }
      if (__all(mn >= epoch)) break;
      __builtin_amdgcn_s_sleep(1);
      if (++guard > 30000000L) break;
    }
    __builtin_amdgcn_fence(__ATOMIC_ACQUIRE, "agent");
  }
  __syncthreads();
}

__global__ __launch_bounds__(256) void tree_kernel(
    const int* __restrict__ nlv_ptr,
    const int* __restrict__ nlist, const int* __restrict__ nlvloff,
    const int* __restrict__ choff, const int* __restrict__ chlist,
    const float* __restrict__ UT,
    const float* __restrict__ biou, const float* __restrict__ buf_,
    const float* __restrict__ iou,
    float* __restrict__ um, float* __restrict__ fm,
    float* __restrict__ cnode, float* __restrict__ hout,
    int* __restrict__ flags)
{
  int n_lv = nlv_ptr[0];
  if (n_lv > MAXLV) n_lv = MAXLV;
  const int tid = threadIdx.x;
  __shared__ float tlds[16*1040];          // A: acc[16][1040] ; B: hl[16][260]
  __shared__ int nids[16];
  int ep = 1;
  for (int l = 0; l < n_lv; l++) {
    const int na = nlvloff[l];
    const int nL = nlvloff[l+1] - na;
    const int ngs = (nL + 15) >> 4;
    // ---------------- Phase A: gather + apply ----------------
    for (int ng = blockIdx.x; ng < ngs; ng += gridDim.x) {
      __syncthreads();
      const int j = tid >> 4, q = tid & 15;
      const int jn = (ng << 4) + j;
      const int n = (jn < nL) ? nlist[na + jn] : -1;
      float* accj = tlds + j*1040;
      if (n >= 0) {
#pragma unroll
        for (int it = 0; it < 12; ++it) {
          const int d = it*64 + (q << 2);
          *(float4*)&accj[d] = *(const float4*)&iou[(size_t)n*GG3 + d];
        }
#pragma unroll
        for (int it = 0; it < 4; ++it) {
          const int d = 768 + it*64 + (q << 2);
          *(float4*)&accj[d] = make_float4(0.f,0.f,0.f,0.f);
        }
        const int e0 = choff[n], e1 = choff[n+1];
        for (int e = e0; e < e1; ++e) {
          const int ch = chlist[e];
          const float* umc = um + (size_t)ch*GG3;
          const float* fmc = fm + (size_t)ch*HID;
#pragma unroll
          for (int it = 0; it < 12; ++it) {
            const int d = it*64 + (q << 2);
            const float4 v = *(const float4*)&umc[d];
            float4 a = *(float4*)&accj[d];
            a.x += v.x; a.y += v.y; a.z += v.z; a.w += v.w;
            *(float4*)&accj[d] = a;
          }
#pragma unroll
          for (int it = 0; it < 4; ++it) {
            const int d = it*64 + (q << 2);
            const float4 v = *(const float4*)&fmc[d];
            float4 a = *(float4*)&accj[768 + d];
            a.x += v.x; a.y += v.y; a.z += v.z; a.w += v.w;
            *(float4*)&accj[768 + d] = a;
          }
        }
      }
      __syncthreads();
      if (n >= 0) {
#pragma unroll
        for (int k = 0; k < 16; ++k) {
          const int u = q + (k << 4);
          const float i_ = accj[u]       + biou[u];
          const float o_ = accj[256 + u] + biou[256 + u];
          const float uu = accj[512 + u] + biou[512 + u];
          const float cr = accj[768 + u];
          const float cv = sigf(i_)*tanh_(uu) + cr;
          const float hv = sigf(o_)*tanh_(cv);
          cnode[(size_t)n*HID + u] = cv;
          hout [(size_t)n*HID + u] = hv;
        }
      }
    }
    tree_barrier(flags, ep++);
    // ---------------- Phase B: emit messages (tiled GEMM) ----------------
    float* hl = tlds;                       // [16][260]
    const int tiles = ngs << 2;
    for (int tl = blockIdx.x; tl < tiles; tl += gridDim.x) {
      const int ng = tl >> 2, rg = tl & 3;
      __syncthreads();
      if (tid < 16) {
        const int jn = (ng << 4) + tid;
        nids[tid] = (jn < nL) ? nlist[na + jn] : -1;
      }
      __syncthreads();
#pragma unroll
      for (int it = 0; it < 4; ++it) {
        const int idx = it*256 + tid;
        const int jj = idx >> 6, d = (idx & 63) << 2;
        const int n2 = nids[jj];
        float4 v = make_float4(0.f,0.f,0.f,0.f);
        if (n2 >= 0) v = *(const float4*)&hout[(size_t)n2*HID + d];
        *(float4*)&hl[jj*260 + d] = v;
      }
      __syncthreads();
      const int lane = tid & 63, j0 = (tid >> 6) << 2;
      float acc[4][4] = {};
      for (int k4 = 0; k4 < 64; ++k4) {
        const int kb = k4 << 2;
        const float4 hv0 = *(const float4*)&hl[(j0+0)*260 + kb];
        const float4 hv1 = *(const float4*)&hl[(j0+1)*260 + kb];
        const float4 hv2 = *(const float4*)&hl[(j0+2)*260 + kb];
        const float4 hv3 = *(const float4*)&hl[(j0+3)*260 + kb];
#pragma unroll
        for (int i = 0; i < 4; ++i) {
          const float* ur = UT + ((size_t)kb << 10) + (rg << 8) + lane + (i << 6);
          const float w0 = ur[0], w1 = ur[1024], w2 = ur[2048], w3 = ur[3072];
          acc[i][0] += w0*hv0.x + w1*hv0.y + w2*hv0.z + w3*hv0.w;
          acc[i][1] += w0*hv1.x + w1*hv1.y + w2*hv1.z + w3*hv1.w;
          acc[i][2] += w0*hv2.x + w1*hv2.y + w2*hv2.z + w3*hv2.w;
          acc[i][3] += w0*hv3.x + w1*hv3.y + w2*hv3.z + w3*hv3.w;
        }
      }
      if (rg < 3) {
#pragma unroll
        for (int i = 0; i < 4; ++i) {
          const int row = (rg << 8) + lane + (i << 6);
#pragma unroll
          for (int jj = 0; jj < 4; ++jj) {
            const int n2 = nids[j0 + jj];
            if (n2 >= 0) um[(size_t)n2*GG3 + row] = acc[i][jj];
          }
        }
      } else {
#pragma unroll
        for (int i = 0; i < 4; ++i) {
          const int fr = lane + (i << 6);
          const float b = buf_[fr];
#pragma unroll
          for (int jj = 0; jj < 4; ++jj) {
            const int n2 = nids[j0 + jj];
            if (n2 >= 0)
              fm[(size_t)n2*HID + fr] =
                sigf(acc[i][jj] + b) * cnode[(size_t)n2*HID + fr];
          }
        }
      }
    }
    tree_barrier(flags, ep++);
  }
}

// ---------------- launch ------------------------------------------------------
extern "C" void kernel_launch(void* const* d_in, const int* in_sizes, int n_in,
                              void* d_out, int out_size, void* d_ws, size_t ws_size,
                              hipStream_t stream)
{
  const int*   embed_ids = (const int*)d_in[0];
  const int*   lengths   = (const int*)d_in[1];
  const int*   child_idx = (const int*)d_in[2];
  const int*   parent_idx= (const int*)d_in[3];
  const int*   tok_idx   = (const int*)d_in[4];
  const int*   node_level= (const int*)d_in[5];
  const int*   nlv       = (const int*)d_in[6];
  const float* emb  = (const float*)d_in[7];
  const float* wihf = (const float*)d_in[8];
  const float* whhf = (const float*)d_in[9];
  const float* bf   = (const float*)d_in[10];
  const float* wihb = (const float*)d_in[11];
  const float* whhb = (const float*)d_in[12];
  const float* bb   = (const float*)d_in[13];
  const float* Wiou = (const float*)d_in[14];
  const float* Uiou = (const float*)d_in[15];
  const float* biou = (const float*)d_in[16];
  const float* Uf   = (const float*)d_in[17];
  const float* buf_ = (const float*)d_in[18];
  const int E  = in_sizes[2];
  const int Nn = in_sizes[4];
  float* hout = (float*)d_out;

  char* w = (char*)d_ws;
  size_t off = 0;
  auto take = [&](size_t bytes) -> char* {
    char* p = w + off;
    off += (bytes + 255) & ~(size_t)255;
    return p;
  };
  int*      flags = (int*)     take(32768);                // zeroed: tree barrier
  int*      deg   = (int*)     take((size_t)(Nn+1)*4);     // zeroed: CSR degree/cursor
  size_t zero_end = off;
  float*    x     = (float*)   take((size_t)8192*300*4);
  float*    xgf   = (float*)   take((size_t)8192*1024*4);
  float*    xgb   = (float*)   take((size_t)8192*1024*4);
  _Float16* wtf   = (_Float16*)take((size_t)32*1024*8*2);  // f16 [k8][g][8]
  _Float16* wtb   = (_Float16*)take((size_t)32*1024*8*2);
  float*    hsf   = (float*)   take((size_t)64*128*256*4);
  float*    hsb   = (float*)   take((size_t)64*128*256*4);
  float*    hx    = (float*)   take((size_t)Nn*512*4);
  float*    iou   = (float*)   take((size_t)Nn*GG3*4);
  float*    um    = (float*)   take((size_t)Nn*GG3*4);
  float*    fm    = (float*)   take((size_t)Nn*HID*4);
  float*    cnode = (float*)   take((size_t)Nn*HID*4);
  float*    UT    = (float*)   take((size_t)256*1024*4);
  int*      nlist = (int*)     take((size_t)Nn*4);
  int*      nlvloff=(int*)     take((size_t)(MAXLV+1)*4);
  int*      choff = (int*)     take((size_t)(Nn+1)*4);
  int*      chlist= (int*)     take((size_t)(E>0?E:1)*4);
  (void)ws_size; (void)n_in; (void)out_size; (void)node_level;

  hipMemsetAsync(d_ws, 0, zero_end, stream);
  gather_x_kernel<<<(8192*75 + 255)/256, 256, 0, stream>>>(embed_ids, emb, x);
  gemm_kernel<true><<<dim3(8192/128, 1024/128), 256, 0, stream>>>(x, wihf, bf, xgf, 8192, 1024, 300);
  gemm_kernel<true><<<dim3(8192/128, 1024/128), 256, 0, stream>>>(x, wihb, bb, xgb, 8192, 1024, 300);
  transpose_w_kernel<<<(2*32*1024 + 255)/256, 256, 0, stream>>>(whhf, whhb, wtf, wtb);
  lstm_kernel<<<64, 512, 0, stream>>>(xgf, xgb, wtf, wtb, lengths, hsf, hsb);
  gather_hx_kernel<<<(Nn*128 + 255)/256, 256, 0, stream>>>(tok_idx, hsf, hsb, hx, Nn);
  gemm_kernel<false><<<dim3((Nn+127)/128, GG3/128), 256, 0, stream>>>(hx, Wiou, nullptr, iou, Nn, GG3, 512);
  ut_kernel<<<(256*1024 + 255)/256, 256, 0, stream>>>(Uiou, Uf, UT);
  sort_kernel<<<1, 1024, 0, stream>>>(child_idx, parent_idx, node_level,
                                      nlist, nlvloff, choff, chlist, deg, E, Nn);
  tree_kernel<<<256, 256, 0, stream>>>(nlv, nlist, nlvloff, choff, chlist, UT,
                                       biou, buf_, iou, um, fm, cnode, hout, flags);
}

// Round 12
// 1615.172 us; speedup vs baseline: 2.5678x; 1.0784x over previous
//
#include <hip/hip_runtime.h>
#include <hip/hip_fp16.h>
#include <cstdint>
#include <cstddef>

#define TT 128
#define HID 256
#define GG4 1024
#define GG3 768

typedef _Float16 f16x2 __attribute__((ext_vector_type(2)));
typedef _Float16 f16x8 __attribute__((ext_vector_type(8)));

union f16x8u { f16x8 v; f16x2 p[4]; };

__device__ __forceinline__ float sigf(float x){ return 1.f/(1.f+__expf(-x)); }
__device__ __forceinline__ float tanh_(float x){
  float cx = fminf(fmaxf(x,-15.f),15.f);
  float e = __expf(2.f*cx);
  return (e-1.f)/(e+1.f);
}

__device__ __forceinline__ float dot2(f16x2 a, f16x2 b, float c){
#if __has_builtin(__builtin_amdgcn_fdot2)
  return __builtin_amdgcn_fdot2(a, b, c, false);
#else
  return c + (float)a[0]*(float)b[0] + (float)a[1]*(float)b[1];
#endif
}

// ---------------- embedding gather: x[m][e] = emb[ids[m]][e] ----------------
__global__ __launch_bounds__(256) void gather_x_kernel(
    const int* __restrict__ ids, const float* __restrict__ emb, float* __restrict__ x)
{
  int it = blockIdx.x*256 + threadIdx.x;        // item = m*75 + q  (300 = 75 float4)
  if (it >= 8192*75) return;
  int m = it / 75, q = (it % 75) * 4;
  int id = ids[m];
  *(float4*)&x[(size_t)m*300 + q] = *(const float4*)&emb[(size_t)id*300 + q];
}

// ---------------- tiled GEMM 128x128, 8x8/thread: C[m][n] = A[m]·W[n] (+bias)
template<bool BIAS>
__global__ __launch_bounds__(256) void gemm_kernel(
    const float* __restrict__ A, const float* __restrict__ W,
    const float* __restrict__ bias, float* __restrict__ C,
    int M, int Nn, int K)
{
  __shared__ float As[16][132];
  __shared__ float Ws[16][132];
  const int tid = threadIdx.x;
  const int m0 = blockIdx.x * 128, n0 = blockIdx.y * 128;
  const int tx = tid & 15, ty = tid >> 4;
  const int srow = tid >> 1, skof = (tid & 1) << 3;
  float acc[8][8] = {};
  for (int k0 = 0; k0 < K; k0 += 16) {
    float a_[8], w_[8];
    const int gm = m0 + srow, gn = n0 + srow;
#pragma unroll
    for (int j = 0; j < 8; j++) {
      const int kk = k0 + skof + j;
      a_[j] = (gm < M && kk < K) ? A[(size_t)gm*K + kk] : 0.f;
      w_[j] = (kk < K) ? W[(size_t)gn*K + kk] : 0.f;
    }
    __syncthreads();
#pragma unroll
    for (int j = 0; j < 8; j++) { As[skof+j][srow] = a_[j]; Ws[skof+j][srow] = w_[j]; }
    __syncthreads();
#pragma unroll
    for (int k = 0; k < 16; k++) {
      const float4 a0 = *(const float4*)&As[k][ty << 3];
      const float4 a1 = *(const float4*)&As[k][(ty << 3) + 4];
      const float4 b0 = *(const float4*)&Ws[k][tx << 3];
      const float4 b1 = *(const float4*)&Ws[k][(tx << 3) + 4];
      const float av[8] = {a0.x,a0.y,a0.z,a0.w,a1.x,a1.y,a1.z,a1.w};
      const float bv[8] = {b0.x,b0.y,b0.z,b0.w,b1.x,b1.y,b1.z,b1.w};
#pragma unroll
      for (int i = 0; i < 8; i++)
#pragma unroll
        for (int j = 0; j < 8; j++) acc[i][j] += av[i]*bv[j];
    }
  }
  float bvv[8] = {0,0,0,0,0,0,0,0};
  if (BIAS) {
#pragma unroll
    for (int j = 0; j < 8; j++) bvv[j] = bias[n0 + (tx<<3) + j];
  }
#pragma unroll
  for (int i = 0; i < 8; i++) {
    const int gm = m0 + (ty<<3) + i;
    if (gm >= M) continue;
    float4 o0 = make_float4(acc[i][0]+bvv[0], acc[i][1]+bvv[1], acc[i][2]+bvv[2], acc[i][3]+bvv[3]);
    float4 o1 = make_float4(acc[i][4]+bvv[4], acc[i][5]+bvv[5], acc[i][6]+bvv[6], acc[i][7]+bvv[7]);
    *(float4*)&C[(size_t)gm*Nn + n0 + (tx<<3)]     = o0;
    *(float4*)&C[(size_t)gm*Nn + n0 + (tx<<3) + 4] = o1;
  }
}

// ------- Whh transpose + f16 pack: wt[k8][g][0..7] = half(W[g][8k8+j]) ------
__global__ __launch_bounds__(256) void transpose_w_kernel(
    const float* __restrict__ whhf, const float* __restrict__ whhb,
    _Float16* __restrict__ wtf, _Float16* __restrict__ wtb)
{
  int it = blockIdx.x*256 + threadIdx.x;  // dir(1) | k8(5) | g(10)
  if (it >= 2*32*1024) return;
  int dir = it >> 15, rem = it & 32767;
  int k8 = rem >> 10, g = rem & 1023;
  const float* w = dir ? whhb : whhf;
  _Float16*   wt = dir ? wtb  : wtf;
  f16x8 pk;
#pragma unroll
  for (int j = 0; j < 8; j++) pk[j] = (_Float16)w[(size_t)g*HID + (k8<<3) + j];
  *(f16x8*)&wt[(((size_t)k8<<10) + g) << 3] = pk;
}

// ---------------- batch-split bidirectional LSTM (no inter-block sync) ------
__global__ __launch_bounds__(512, 1) void lstm_kernel(
    const float* __restrict__ xgf, const float* __restrict__ xgb,
    const _Float16* __restrict__ wtf, const _Float16* __restrict__ wtb,
    const int* __restrict__ lengths,
    float* __restrict__ hsf, float* __restrict__ hsb)
{
  const int b8  = blockIdx.x & 7;
  const int dir = b8 >> 2;
  const int p   = (blockIdx.x >> 3) * 4 + (b8 & 3);   // 0..31
  const int r0 = 2*p, r1 = r0 + 1;
  const float* __restrict__ xg = dir ? xgb : xgf;
  const _Float16* __restrict__ wt = dir ? wtb : wtf;
  float* __restrict__ hs = dir ? hsb : hsf;
  const int t = threadIdx.x;
  const int u = t & 255;

  __shared__ _Float16 hb[2][256];
  __shared__ float exf[2][256];
  __shared__ float exo[2][256];
  if (t < 256) { hb[0][t] = (_Float16)0.f; hb[1][t] = (_Float16)0.f; }
  __syncthreads();

  const int len0 = lengths[r0], len1 = lengths[r1];   // len0 >= len1
  float c0 = 0.f, c1 = 0.f;
  for (int s = 0; s < len0; s++) {
    const bool a1 = s < len1;
    const int t0 = dir ? (len0 - 1 - s) : s;
    const int t1 = dir ? (len1 - 1 - s) : s;
    const float* xr0 = xg + ((size_t)r0*TT + t0)*GG4;
    const float xa0 = xr0[t], xb0 = xr0[t + 512];
    float xa1 = 0.f, xb1 = 0.f;
    if (a1) {
      const float* xr1 = xg + ((size_t)r1*TT + t1)*GG4;
      xa1 = xr1[t]; xb1 = xr1[t + 512];
    }
    float aa0 = 0.f, aa1 = 0.f, ab0 = 0.f, ab1 = 0.f;
#pragma unroll 8
    for (int k8 = 0; k8 < 32; k8++) {
      f16x8u w0, w1, h0, h1;
      w0.v = *(const f16x8*)&wt[(((size_t)k8<<10) + t) << 3];
      w1.v = *(const f16x8*)&wt[(((size_t)k8<<10) + t + 512) << 3];
      h0.v = *(const f16x8*)&hb[0][k8 << 3];
      h1.v = *(const f16x8*)&hb[1][k8 << 3];
#pragma unroll
      for (int j = 0; j < 4; j++) {
        aa0 = dot2(w0.p[j], h0.p[j], aa0);
        aa1 = dot2(w0.p[j], h1.p[j], aa1);
        ab0 = dot2(w1.p[j], h0.p[j], ab0);
        ab1 = dot2(w1.p[j], h1.p[j], ab1);
      }
    }
    if (t >= 256) {            // publish f,o pre-activations
      exf[0][u] = aa0 + xa0;  exf[1][u] = aa1 + xa1;
      exo[0][u] = ab0 + xb0;  exo[1][u] = ab1 + xb1;
    }
    __syncthreads();
    if (t < 256) {
      {
        const float ig = sigf(aa0 + xa0);
        const float gg = tanh_(ab0 + xb0);
        const float fg = sigf(exf[0][u]);
        const float og = sigf(exo[0][u]);
        c0 = fg*c0 + ig*gg;
        const float h = og*tanh_(c0);
        hb[0][u] = (_Float16)h;
        hs[((size_t)r0*TT + t0)*HID + u] = h;
      }
      if (a1) {
        const float ig = sigf(aa1 + xa1);
        const float gg = tanh_(ab1 + xb1);
        const float fg = sigf(exf[1][u]);
        const float og = sigf(exo[1][u]);
        c1 = fg*c1 + ig*gg;
        const float h = og*tanh_(c1);
        hb[1][u] = (_Float16)h;
        hs[((size_t)r1*TT + t1)*HID + u] = h;
      }
    }
    __syncthreads();
  }
}

// ---------------- hx = concat(h_f[tok], h_b[tok]) ---------------------------
__global__ __launch_bounds__(256) void gather_hx_kernel(
    const int* __restrict__ tok, const float* __restrict__ hsf,
    const float* __restrict__ hsb, float* __restrict__ hx, int Nn)
{
  int it = blockIdx.x*256 + threadIdx.x;     // item = n*128 + q
  if (it >= Nn*128) return;
  int n = it >> 7, q = it & 127;
  int tk = tok[n];
  int b = tk >> 7, t = tk & 127;
  float4 v;
  if (q < 64) v = *(const float4*)&hsf[((size_t)b*TT + t)*HID + (q<<2)];
  else        v = *(const float4*)&hsb[((size_t)b*TT + t)*HID + ((q-64)<<2)];
  *(float4*)&hx[(size_t)n*512 + (q<<2)] = v;
}

// ---------------- UT[k][r] = (r<768 ? Uiou[r][k] : Uf[r-768][k]) ------------
__global__ __launch_bounds__(256) void ut_kernel(
    const float* __restrict__ Uiou, const float* __restrict__ Uf,
    float* __restrict__ UT)
{
  int idx = blockIdx.x*256 + threadIdx.x;
  if (idx >= 256*1024) return;
  int k = idx >> 10, r = idx & 1023;
  UT[idx] = (r < 768) ? Uiou[(size_t)r*HID + k] : Uf[(size_t)(r-768)*HID + k];
}

// ---------------- children CSR by parent ------------------------------------
__global__ __launch_bounds__(1024) void csr_kernel(
    const int* __restrict__ child_idx, const int* __restrict__ parent_idx,
    int* __restrict__ choff, int* __restrict__ chlist,
    int* __restrict__ deg /* zeroed; reused as cursor */, int E, int Nn)
{
  __shared__ int part[1024];
  const int tid = threadIdx.x;
  for (int e = tid; e < E; e += 1024) atomicAdd(&deg[parent_idx[e]], 1);
  __syncthreads();
  int loc[8]; int s = 0;
#pragma unroll
  for (int m = 0; m < 8; m++) {
    const int i = tid*8 + m;
    loc[m] = s;
    s += (i < Nn) ? deg[i] : 0;
  }
  part[tid] = s;
  __syncthreads();
  for (int off = 1; off < 1024; off <<= 1) {
    int v = (tid >= off) ? part[tid - off] : 0;
    __syncthreads();
    part[tid] += v;
    __syncthreads();
  }
  const int pre = (tid > 0) ? part[tid-1] : 0;
#pragma unroll
  for (int m = 0; m < 8; m++) {
    const int i = tid*8 + m;
    if (i < Nn) choff[i] = pre + loc[m];
  }
  if (tid == 1023) choff[Nn] = part[1023];
  __syncthreads();
#pragma unroll
  for (int m = 0; m < 8; m++) {
    const int i = tid*8 + m;
    if (i < Nn) deg[i] = pre + loc[m];
  }
  __syncthreads();
  for (int e = tid; e < E; e += 1024) {
    int pos = atomicAdd(&deg[parent_idx[e]], 1);
    chlist[pos] = child_idx[e];
  }
}

// ---------------- per-tree level sort ---------------------------------------
// 64 blocks (1/tree) x 128 threads. tnlist[b][i]: node ids level-sorted;
// tlvloff[b][l]: level offsets; tnlv[b]: #levels.
__global__ __launch_bounds__(128) void tree_sort_kernel(
    const int* __restrict__ lengths, const int* __restrict__ node_level,
    int* __restrict__ tnlist, int* __restrict__ tlvloff, int* __restrict__ tnlv)
{
  const int b = blockIdx.x, tid = threadIdx.x;
  __shared__ int hist[130], cur[129];
  __shared__ int off_s, len_s, mx;
  if (tid == 0) {
    int o = 0;
    for (int i = 0; i < b; i++) o += lengths[i];
    off_s = o; len_s = lengths[b]; mx = 1;
  }
  for (int i = tid; i < 130; i += 128) hist[i] = 0;
  __syncthreads();
  const int off = off_s, len = len_s;
  for (int i = tid; i < len; i += 128) {
    int lv = node_level[off + i];
    atomicAdd(&hist[lv], 1);
    atomicMax(&mx, lv + 1);
  }
  __syncthreads();
  if (tid == 0) {
    int s = 0;
    for (int l = 0; l < 129; l++) { cur[l] = s; tlvloff[b*130 + l] = s; s += hist[l]; }
    tlvloff[b*130 + 129] = s;
    tnlv[b] = mx;
  }
  __syncthreads();
  for (int i = tid; i < len; i += 128) {
    int lv = node_level[off + i];
    int pos = atomicAdd(&cur[lv], 1);
    tnlist[b*128 + pos] = off + i;
  }
}

// ---------------- tree: one block per tree, NO inter-block sync -------------
// 64 blocks x 512 threads. Per level: groups of 8 nodes.
//  A: acc = iou[n] (+768-wide) ++ 0 (256-wide cred); add children um/fm (CSR);
//     apply -> c,h into LDS (cl/hl) + hout global.
//  B (skip at top level): rows r=tid, tid+512: s[r] = sum_k UT[k][r]*hl[j][k];
//     r<768 -> um[n][r] ; r>=768 -> fm[n][r-768] = sig(s+buf)*cl[j][r-768].
__global__ __launch_bounds__(512) void tree_kernel(
    const int* __restrict__ tnlist, const int* __restrict__ tlvloff,
    const int* __restrict__ tnlv,
    const int* __restrict__ choff, const int* __restrict__ chlist,
    const float* __restrict__ UT,
    const float* __restrict__ biou, const float* __restrict__ buf_,
    const float* __restrict__ iou,
    float* __restrict__ um, float* __restrict__ fm,
    float* __restrict__ hout)
{
  const int b = blockIdx.x;
  const int tid = threadIdx.x;
  const int nlv = tnlv[b];
  const int* __restrict__ nl = tnlist + b*128;
  const int* __restrict__ lo = tlvloff + b*130;
  __shared__ float acc[8][1024];
  __shared__ float hl[8][256];
  __shared__ float cl[8][256];
  const int j = tid >> 6, lane = tid & 63;
  for (int l = 0; l < nlv; l++) {
    const int na = lo[l], ne = lo[l+1];
    for (int g0 = na; g0 < ne; g0 += 8) {
      __syncthreads();                       // hl/cl free (prev group's B done)
      const int n = (g0 + j < ne) ? nl[g0 + j] : -1;
      if (n >= 0) {
        float4 a[4];
#pragma unroll
        for (int q = 0; q < 4; q++) {
          const int d = lane*16 + q*4;
          a[q] = (d < GG3) ? *(const float4*)&iou[(size_t)n*GG3 + d]
                           : make_float4(0.f,0.f,0.f,0.f);
        }
        const int e0 = choff[n], e1 = choff[n+1];
        for (int e = e0; e < e1; ++e) {
          const int ch = chlist[e];
#pragma unroll
          for (int q = 0; q < 4; q++) {
            const int d = lane*16 + q*4;
            const float4 v = (d < GG3) ? *(const float4*)&um[(size_t)ch*GG3 + d]
                                       : *(const float4*)&fm[(size_t)ch*HID + (d-GG3)];
            a[q].x += v.x; a[q].y += v.y; a[q].z += v.z; a[q].w += v.w;
          }
        }
#pragma unroll
        for (int q = 0; q < 4; q++) *(float4*)&acc[j][lane*16 + q*4] = a[q];
      }
      __syncthreads();                       // acc complete
      if (n >= 0) {
#pragma unroll
        for (int i = 0; i < 4; i++) {
          const int u = lane*4 + i;
          const float i_ = acc[j][u]       + biou[u];
          const float o_ = acc[j][256 + u] + biou[256 + u];
          const float uu = acc[j][512 + u] + biou[512 + u];
          const float cv = sigf(i_)*tanh_(uu) + acc[j][768 + u];
          const float hv = sigf(o_)*tanh_(cv);
          cl[j][u] = cv; hl[j][u] = hv;
          hout[(size_t)n*HID + u] = hv;
        }
      }
      __syncthreads();                       // hl/cl ready
      if (l == nlv - 1) continue;            // root: no messages consumed
      const int c8 = (ne - g0) < 8 ? (ne - g0) : 8;
      float s0[8] = {0,0,0,0,0,0,0,0};
      float s1[8] = {0,0,0,0,0,0,0,0};
      for (int k4 = 0; k4 < 64; ++k4) {
        const int kb = k4 << 2;
        float4 hj[8];
#pragma unroll
        for (int jj = 0; jj < 8; ++jj) hj[jj] = *(const float4*)&hl[jj][kb];
        const float w00 = UT[(size_t)(kb+0)*1024 + tid];
        const float w01 = UT[(size_t)(kb+1)*1024 + tid];
        const float w02 = UT[(size_t)(kb+2)*1024 + tid];
        const float w03 = UT[(size_t)(kb+3)*1024 + tid];
        const float w10 = UT[(size_t)(kb+0)*1024 + tid + 512];
        const float w11 = UT[(size_t)(kb+1)*1024 + tid + 512];
        const float w12 = UT[(size_t)(kb+2)*1024 + tid + 512];
        const float w13 = UT[(size_t)(kb+3)*1024 + tid + 512];
#pragma unroll
        for (int jj = 0; jj < 8; ++jj) {
          s0[jj] += w00*hj[jj].x + w01*hj[jj].y + w02*hj[jj].z + w03*hj[jj].w;
          s1[jj] += w10*hj[jj].x + w11*hj[jj].y + w12*hj[jj].z + w13*hj[jj].w;
        }
      }
      const int r1 = tid + 512;
#pragma unroll
      for (int jj = 0; jj < 8; ++jj) {
        if (jj < c8) {
          const int n2 = nl[g0 + jj];
          um[(size_t)n2*GG3 + tid] = s0[jj];
          if (r1 < GG3) {
            um[(size_t)n2*GG3 + r1] = s1[jj];
          } else {
            const int fr = r1 - GG3;
            fm[(size_t)n2*HID + fr] = sigf(s1[jj] + buf_[fr]) * cl[jj][fr];
          }
        }
      }
    }
  }
}

// ---------------- launch ------------------------------------------------------
extern "C" void kernel_launch(void* const* d_in, const int* in_sizes, int n_in,
                              void* d_out, int out_size, void* d_ws, size_t ws_size,
                              hipStream_t stream)
{
  const int*   embed_ids = (const int*)d_in[0];
  const int*   lengths   = (const int*)d_in[1];
  const int*   child_idx = (const int*)d_in[2];
  const int*   parent_idx= (const int*)d_in[3];
  const int*   tok_idx   = (const int*)d_in[4];
  const int*   node_level= (const int*)d_in[5];
  const float* emb  = (const float*)d_in[7];
  const float* wihf = (const float*)d_in[8];
  const float* whhf = (const float*)d_in[9];
  const float* bf   = (const float*)d_in[10];
  const float* wihb = (const float*)d_in[11];
  const float* whhb = (const float*)d_in[12];
  const float* bb   = (const float*)d_in[13];
  const float* Wiou = (const float*)d_in[14];
  const float* Uiou = (const float*)d_in[15];
  const float* biou = (const float*)d_in[16];
  const float* Uf   = (const float*)d_in[17];
  const float* buf_ = (const float*)d_in[18];
  const int E  = in_sizes[2];
  const int Nn = in_sizes[4];
  float* hout = (float*)d_out;

  char* w = (char*)d_ws;
  size_t off = 0;
  auto take = [&](size_t bytes) -> char* {
    char* p = w + off;
    off += (bytes + 255) & ~(size_t)255;
    return p;
  };
  int*      deg   = (int*)     take((size_t)(Nn+1)*4);     // zeroed: CSR degree/cursor
  size_t zero_end = off;
  float*    x     = (float*)   take((size_t)8192*300*4);
  float*    xgf   = (float*)   take((size_t)8192*1024*4);
  float*    xgb   = (float*)   take((size_t)8192*1024*4);
  _Float16* wtf   = (_Float16*)take((size_t)32*1024*8*2);  // f16 [k8][g][8]
  _Float16* wtb   = (_Float16*)take((size_t)32*1024*8*2);
  float*    hsf   = (float*)   take((size_t)64*128*256*4);
  float*    hsb   = (float*)   take((size_t)64*128*256*4);
  float*    hx    = (float*)   take((size_t)Nn*512*4);
  float*    iou   = (float*)   take((size_t)Nn*GG3*4);
  float*    um    = (float*)   take((size_t)Nn*GG3*4);
  float*    fm    = (float*)   take((size_t)Nn*HID*4);
  float*    UT    = (float*)   take((size_t)256*1024*4);
  int*      tnlist= (int*)     take((size_t)64*128*4);
  int*      tlvloff=(int*)     take((size_t)64*130*4);
  int*      tnlv  = (int*)     take((size_t)64*4);
  int*      choff = (int*)     take((size_t)(Nn+1)*4);
  int*      chlist= (int*)     take((size_t)(E>0?E:1)*4);
  (void)ws_size; (void)n_in; (void)out_size;

  hipMemsetAsync(d_ws, 0, zero_end, stream);
  gather_x_kernel<<<(8192*75 + 255)/256, 256, 0, stream>>>(embed_ids, emb, x);
  gemm_kernel<true><<<dim3(8192/128, 1024/128), 256, 0, stream>>>(x, wihf, bf, xgf, 8192, 1024, 300);
  gemm_kernel<true><<<dim3(8192/128, 1024/128), 256, 0, stream>>>(x, wihb, bb, xgb, 8192, 1024, 300);
  transpose_w_kernel<<<(2*32*1024 + 255)/256, 256, 0, stream>>>(whhf, whhb, wtf, wtb);
  lstm_kernel<<<64, 512, 0, stream>>>(xgf, xgb, wtf, wtb, lengths, hsf, hsb);
  gather_hx_kernel<<<(Nn*128 + 255)/256, 256, 0, stream>>>(tok_idx, hsf, hsb, hx, Nn);
  gemm_kernel<false><<<dim3((Nn+127)/128, GG3/128), 256, 0, stream>>>(hx, Wiou, nullptr, iou, Nn, GG3, 512);
  ut_kernel<<<(256*1024 + 255)/256, 256, 0, stream>>>(Uiou, Uf, UT);
  csr_kernel<<<1, 1024, 0, stream>>>(child_idx, parent_idx, choff, chlist, deg, E, Nn);
  tree_sort_kernel<<<64, 128, 0, stream>>>(lengths, node_level, tnlist, tlvloff, tnlv);
  tree_kernel<<<64, 512, 0, stream>>>(tnlist, tlvloff, tnlv, choff, chlist, UT,
                                      biou, buf_, iou, um, fm, hout);
}

// Round 13
// 1345.728 us; speedup vs baseline: 3.0819x; 1.2002x over previous
//
#include <hip/hip_runtime.h>
#include <hip/hip_fp16.h>
#include <cstdint>
#include <cstddef>

#define TT 128
#define HID 256
#define GG4 1024
#define GG3 768

typedef _Float16 f16x2 __attribute__((ext_vector_type(2)));
typedef _Float16 f16x8 __attribute__((ext_vector_type(8)));
typedef short    bf16x8 __attribute__((ext_vector_type(8)));
typedef float    f32x4 __attribute__((ext_vector_type(4)));

union f16x8u { f16x8 v; f16x2 p[4]; };

__device__ __forceinline__ float sigf(float x){ return 1.f/(1.f+__expf(-x)); }
__device__ __forceinline__ float tanh_(float x){
  float cx = fminf(fmaxf(x,-15.f),15.f);
  float e = __expf(2.f*cx);
  return (e-1.f)/(e+1.f);
}

__device__ __forceinline__ float dot2(f16x2 a, f16x2 b, float c){
#if __has_builtin(__builtin_amdgcn_fdot2)
  return __builtin_amdgcn_fdot2(a, b, c, false);
#else
  return c + (float)a[0]*(float)b[0] + (float)a[1]*(float)b[1];
#endif
}

__device__ __forceinline__ ushort f2bf(float x){
  union { float f; uint32_t u; } v; v.f = x;
  uint32_t r = v.u + 0x7FFF + ((v.u >> 16) & 1);
  return (ushort)(r >> 16);
}

// ---------- embedding gather -> bf16, K padded 300->320 ---------------------
__global__ __launch_bounds__(256) void gather_x_kernel(
    const int* __restrict__ ids, const float* __restrict__ emb, ushort* __restrict__ xh)
{
  int it = blockIdx.x*256 + threadIdx.x;        // item = m*40 + q  (320/8 chunks)
  if (it >= 8192*40) return;
  int m = it / 40, q = it - m*40;
  int k0 = q << 3;
  int id = ids[m];
  ushort o[8];
#pragma unroll
  for (int j = 0; j < 8; j++) {
    int k = k0 + j;
    o[j] = (k < 300) ? f2bf(emb[(size_t)id*300 + k]) : (ushort)0;
  }
  *(uint4*)&xh[(size_t)m*320 + k0] = *(uint4*)o;
}

// ---------- f32 -> bf16 with K padding --------------------------------------
__global__ __launch_bounds__(256) void cvt_pad_kernel(
    const float* __restrict__ src, ushort* __restrict__ dst, int K, int Kp, int nitem)
{
  int it = blockIdx.x*256 + threadIdx.x;
  if (it >= nitem) return;
  int chunks = Kp >> 3;
  int r = it / chunks, q = it - r*chunks;
  int k0 = q << 3;
  ushort o[8];
#pragma unroll
  for (int j = 0; j < 8; j++) {
    int k = k0 + j;
    o[j] = (k < K) ? f2bf(src[(size_t)r*K + k]) : (ushort)0;
  }
  *(uint4*)&dst[(size_t)r*Kp + k0] = *(uint4*)o;
}

// ---------- MFMA bf16 GEMM: C[m][n] = A[m][:]·Bt[n][:] (+bias) --------------
// A:[M][Kp] bf16, Bt:[N][Kp] bf16 (N%128==0), C:[M][N] f32. 256 thr = 4 waves,
// tile 128x128, wave 64x64 = 4x4 frags of 16x16x32.
template<bool BIAS>
__global__ __launch_bounds__(256) void mfma_gemm_kernel(
    const ushort* __restrict__ A, const ushort* __restrict__ Bt,
    const float* __restrict__ bias, float* __restrict__ C,
    int M, int N, int ksteps)
{
  constexpr int LDS_ROW = 40;                   // padded (bank-stride 20 -> 2-way)
  __shared__ ushort As[128*LDS_ROW];
  __shared__ ushort Bs[128*LDS_ROW];
  const int tid = threadIdx.x;
  const int m0 = blockIdx.x * 128, n0 = blockIdx.y * 128;
  const int wave = tid >> 6, lane = tid & 63;
  const int wm = (wave >> 1) * 64, wn = (wave & 1) * 64;
  const int fr = lane & 15;                     // frag row (A/Bt)
  const int fk = (lane >> 4) << 3;              // k offset within 32
  const size_t Kp = (size_t)ksteps << 5;
  const int r0_ = tid >> 2,        k0_ = (tid & 3) << 3;          // stage chunk 0
  const int r1_ = (tid + 256) >> 2, k1_ = ((tid + 256) & 3) << 3; // stage chunk 1
  f32x4 acc[4][4] = {};
  for (int ks = 0; ks < ksteps; ks++) {
    const int kb = ks << 5;
    uint4 av0 = make_uint4(0,0,0,0), av1 = make_uint4(0,0,0,0);
    if (m0 + r0_ < M) av0 = *(const uint4*)&A[(size_t)(m0+r0_)*Kp + kb + k0_];
    if (m0 + r1_ < M) av1 = *(const uint4*)&A[(size_t)(m0+r1_)*Kp + kb + k1_];
    const uint4 bv0 = *(const uint4*)&Bt[(size_t)(n0+r0_)*Kp + kb + k0_];
    const uint4 bv1 = *(const uint4*)&Bt[(size_t)(n0+r1_)*Kp + kb + k1_];
    __syncthreads();
    *(uint4*)&As[r0_*LDS_ROW + k0_] = av0;
    *(uint4*)&As[r1_*LDS_ROW + k1_] = av1;
    *(uint4*)&Bs[r0_*LDS_ROW + k0_] = bv0;
    *(uint4*)&Bs[r1_*LDS_ROW + k1_] = bv1;
    __syncthreads();
    bf16x8 af[4], bfr[4];
#pragma unroll
    for (int i = 0; i < 4; i++) {
      af[i]  = *(const bf16x8*)&As[(wm + i*16 + fr)*LDS_ROW + fk];
      bfr[i] = *(const bf16x8*)&Bs[(wn + i*16 + fr)*LDS_ROW + fk];
    }
#pragma unroll
    for (int mi = 0; mi < 4; mi++)
#pragma unroll
      for (int ni = 0; ni < 4; ni++)
        acc[mi][ni] = __builtin_amdgcn_mfma_f32_16x16x32_bf16(af[mi], bfr[ni], acc[mi][ni], 0, 0, 0);
  }
  const int drow = (lane >> 4) << 2, dcol = lane & 15;
#pragma unroll
  for (int mi = 0; mi < 4; mi++) {
#pragma unroll
    for (int ni = 0; ni < 4; ni++) {
      const int col = n0 + wn + ni*16 + dcol;
      const float bv = BIAS ? bias[col] : 0.f;
#pragma unroll
      for (int r = 0; r < 4; r++) {
        const int row = m0 + wm + mi*16 + drow + r;
        if (row < M) C[(size_t)row*N + col] = acc[mi][ni][r] + bv;
      }
    }
  }
}

// ------- Whh transpose + f16 pack: wt[k8][g][0..7] = half(W[g][8k8+j]) ------
__global__ __launch_bounds__(256) void transpose_w_kernel(
    const float* __restrict__ whhf, const float* __restrict__ whhb,
    _Float16* __restrict__ wtf, _Float16* __restrict__ wtb)
{
  int it = blockIdx.x*256 + threadIdx.x;  // dir(1) | k8(5) | g(10)
  if (it >= 2*32*1024) return;
  int dir = it >> 15, rem = it & 32767;
  int k8 = rem >> 10, g = rem & 1023;
  const float* w = dir ? whhb : whhf;
  _Float16*   wt = dir ? wtb  : wtf;
  f16x8 pk;
#pragma unroll
  for (int j = 0; j < 8; j++) pk[j] = (_Float16)w[(size_t)g*HID + (k8<<3) + j];
  *(f16x8*)&wt[(((size_t)k8<<10) + g) << 3] = pk;
}

// ---------------- batch-split bidirectional LSTM (no inter-block sync) ------
__global__ __launch_bounds__(512, 1) void lstm_kernel(
    const float* __restrict__ xgf, const float* __restrict__ xgb,
    const _Float16* __restrict__ wtf, const _Float16* __restrict__ wtb,
    const int* __restrict__ lengths,
    float* __restrict__ hsf, float* __restrict__ hsb)
{
  const int b8  = blockIdx.x & 7;
  const int dir = b8 >> 2;
  const int p   = (blockIdx.x >> 3) * 4 + (b8 & 3);   // 0..31
  const int r0 = 2*p, r1 = r0 + 1;
  const float* __restrict__ xg = dir ? xgb : xgf;
  const _Float16* __restrict__ wt = dir ? wtb : wtf;
  float* __restrict__ hs = dir ? hsb : hsf;
  const int t = threadIdx.x;
  const int u = t & 255;

  __shared__ _Float16 hb[2][256];
  __shared__ float exf[2][256];
  __shared__ float exo[2][256];
  if (t < 256) { hb[0][t] = (_Float16)0.f; hb[1][t] = (_Float16)0.f; }
  __syncthreads();

  const int len0 = lengths[r0], len1 = lengths[r1];   // len0 >= len1
  float c0 = 0.f, c1 = 0.f;
  for (int s = 0; s < len0; s++) {
    const bool a1 = s < len1;
    const int t0 = dir ? (len0 - 1 - s) : s;
    const int t1 = dir ? (len1 - 1 - s) : s;
    const float* xr0 = xg + ((size_t)r0*TT + t0)*GG4;
    const float xa0 = xr0[t], xb0 = xr0[t + 512];
    float xa1 = 0.f, xb1 = 0.f;
    if (a1) {
      const float* xr1 = xg + ((size_t)r1*TT + t1)*GG4;
      xa1 = xr1[t]; xb1 = xr1[t + 512];
    }
    float aa0 = 0.f, aa1 = 0.f, ab0 = 0.f, ab1 = 0.f;
#pragma unroll 8
    for (int k8 = 0; k8 < 32; k8++) {
      f16x8u w0, w1, h0, h1;
      w0.v = *(const f16x8*)&wt[(((size_t)k8<<10) + t) << 3];
      w1.v = *(const f16x8*)&wt[(((size_t)k8<<10) + t + 512) << 3];
      h0.v = *(const f16x8*)&hb[0][k8 << 3];
      h1.v = *(const f16x8*)&hb[1][k8 << 3];
#pragma unroll
      for (int j = 0; j < 4; j++) {
        aa0 = dot2(w0.p[j], h0.p[j], aa0);
        aa1 = dot2(w0.p[j], h1.p[j], aa1);
        ab0 = dot2(w1.p[j], h0.p[j], ab0);
        ab1 = dot2(w1.p[j], h1.p[j], ab1);
      }
    }
    if (t >= 256) {            // publish f,o pre-activations
      exf[0][u] = aa0 + xa0;  exf[1][u] = aa1 + xa1;
      exo[0][u] = ab0 + xb0;  exo[1][u] = ab1 + xb1;
    }
    __syncthreads();
    if (t < 256) {
      {
        const float ig = sigf(aa0 + xa0);
        const float gg = tanh_(ab0 + xb0);
        const float fg = sigf(exf[0][u]);
        const float og = sigf(exo[0][u]);
        c0 = fg*c0 + ig*gg;
        const float h = og*tanh_(c0);
        hb[0][u] = (_Float16)h;
        hs[((size_t)r0*TT + t0)*HID + u] = h;
      }
      if (a1) {
        const float ig = sigf(aa1 + xa1);
        const float gg = tanh_(ab1 + xb1);
        const float fg = sigf(exf[1][u]);
        const float og = sigf(exo[1][u]);
        c1 = fg*c1 + ig*gg;
        const float h = og*tanh_(c1);
        hb[1][u] = (_Float16)h;
        hs[((size_t)r1*TT + t1)*HID + u] = h;
      }
    }
    __syncthreads();
  }
}

// ---------------- hxh = bf16 concat(h_f[tok], h_b[tok]) ---------------------
__global__ __launch_bounds__(256) void gather_hx_kernel(
    const int* __restrict__ tok, const float* __restrict__ hsf,
    const float* __restrict__ hsb, ushort* __restrict__ hxh, int Nn)
{
  int it = blockIdx.x*256 + threadIdx.x;     // item = n*64 + q (512/8 chunks)
  if (it >= Nn*64) return;
  int n = it >> 6, q = it & 63;
  int k0 = q << 3;
  int tk = tok[n];
  int b = tk >> 7, t = tk & 127;
  const float* src = (k0 < 256) ? &hsf[((size_t)b*TT + t)*HID + k0]
                                : &hsb[((size_t)b*TT + t)*HID + (k0 - 256)];
  ushort o[8];
#pragma unroll
  for (int j = 0; j < 8; j++) o[j] = f2bf(src[j]);
  *(uint4*)&hxh[(size_t)n*512 + k0] = *(uint4*)o;
}

// ---------------- UT[k][r] = (r<768 ? Uiou[r][k] : Uf[r-768][k]) ------------
__global__ __launch_bounds__(256) void ut_kernel(
    const float* __restrict__ Uiou, const float* __restrict__ Uf,
    float* __restrict__ UT)
{
  int idx = blockIdx.x*256 + threadIdx.x;
  if (idx >= 256*1024) return;
  int k = idx >> 10, r = idx & 1023;
  UT[idx] = (r < 768) ? Uiou[(size_t)r*HID + k] : Uf[(size_t)(r-768)*HID + k];
}

// ---------------- children CSR by parent ------------------------------------
__global__ __launch_bounds__(1024) void csr_kernel(
    const int* __restrict__ child_idx, const int* __restrict__ parent_idx,
    int* __restrict__ choff, int* __restrict__ chlist,
    int* __restrict__ deg /* zeroed; reused as cursor */, int E, int Nn)
{
  __shared__ int part[1024];
  const int tid = threadIdx.x;
  for (int e = tid; e < E; e += 1024) atomicAdd(&deg[parent_idx[e]], 1);
  __syncthreads();
  int loc[8]; int s = 0;
#pragma unroll
  for (int m = 0; m < 8; m++) {
    const int i = tid*8 + m;
    loc[m] = s;
    s += (i < Nn) ? deg[i] : 0;
  }
  part[tid] = s;
  __syncthreads();
  for (int off = 1; off < 1024; off <<= 1) {
    int v = (tid >= off) ? part[tid - off] : 0;
    __syncthreads();
    part[tid] += v;
    __syncthreads();
  }
  const int pre = (tid > 0) ? part[tid-1] : 0;
#pragma unroll
  for (int m = 0; m < 8; m++) {
    const int i = tid*8 + m;
    if (i < Nn) choff[i] = pre + loc[m];
  }
  if (tid == 1023) choff[Nn] = part[1023];
  __syncthreads();
#pragma unroll
  for (int m = 0; m < 8; m++) {
    const int i = tid*8 + m;
    if (i < Nn) deg[i] = pre + loc[m];
  }
  __syncthreads();
  for (int e = tid; e < E; e += 1024) {
    int pos = atomicAdd(&deg[parent_idx[e]], 1);
    chlist[pos] = child_idx[e];
  }
}

// ---------------- per-tree level sort ---------------------------------------
__global__ __launch_bounds__(128) void tree_sort_kernel(
    const int* __restrict__ lengths, const int* __restrict__ node_level,
    int* __restrict__ tnlist, int* __restrict__ tlvloff, int* __restrict__ tnlv)
{
  const int b = blockIdx.x, tid = threadIdx.x;
  __shared__ int hist[130], cur[129];
  __shared__ int off_s, len_s, mx;
  if (tid == 0) {
    int o = 0;
    for (int i = 0; i < b; i++) o += lengths[i];
    off_s = o; len_s = lengths[b]; mx = 1;
  }
  for (int i = tid; i < 130; i += 128) hist[i] = 0;
  __syncthreads();
  const int off = off_s, len = len_s;
  for (int i = tid; i < len; i += 128) {
    int lv = node_level[off + i];
    atomicAdd(&hist[lv], 1);
    atomicMax(&mx, lv + 1);
  }
  __syncthreads();
  if (tid == 0) {
    int s = 0;
    for (int l = 0; l < 129; l++) { cur[l] = s; tlvloff[b*130 + l] = s; s += hist[l]; }
    tlvloff[b*130 + 129] = s;
    tnlv[b] = mx;
  }
  __syncthreads();
  for (int i = tid; i < len; i += 128) {
    int lv = node_level[off + i];
    int pos = atomicAdd(&cur[lv], 1);
    tnlist[b*128 + pos] = off + i;
  }
}

// ---------------- tree: one block per tree, NO inter-block sync -------------
__global__ __launch_bounds__(512) void tree_kernel(
    const int* __restrict__ tnlist, const int* __restrict__ tlvloff,
    const int* __restrict__ tnlv,
    const int* __restrict__ choff, const int* __restrict__ chlist,
    const float* __restrict__ UT,
    const float* __restrict__ biou, const float* __restrict__ buf_,
    const float* __restrict__ iou,
    float* __restrict__ um, float* __restrict__ fm,
    float* __restrict__ hout)
{
  const int b = blockIdx.x;
  const int tid = threadIdx.x;
  const int nlv = tnlv[b];
  const int* __restrict__ nl = tnlist + b*128;
  const int* __restrict__ lo = tlvloff + b*130;
  __shared__ float acc[8][1024];
  __shared__ float hl[8][256];
  __shared__ float cl[8][256];
  const int j = tid >> 6, lane = tid & 63;
  for (int l = 0; l < nlv; l++) {
    const int na = lo[l], ne = lo[l+1];
    for (int g0 = na; g0 < ne; g0 += 8) {
      __syncthreads();
      const int n = (g0 + j < ne) ? nl[g0 + j] : -1;
      if (n >= 0) {
        float4 a[4];
#pragma unroll
        for (int q = 0; q < 4; q++) {
          const int d = lane*16 + q*4;
          a[q] = (d < GG3) ? *(const float4*)&iou[(size_t)n*GG3 + d]
                           : make_float4(0.f,0.f,0.f,0.f);
        }
        const int e0 = choff[n], e1 = choff[n+1];
        for (int e = e0; e < e1; ++e) {
          const int ch = chlist[e];
#pragma unroll
          for (int q = 0; q < 4; q++) {
            const int d = lane*16 + q*4;
            const float4 v = (d < GG3) ? *(const float4*)&um[(size_t)ch*GG3 + d]
                                       : *(const float4*)&fm[(size_t)ch*HID + (d-GG3)];
            a[q].x += v.x; a[q].y += v.y; a[q].z += v.z; a[q].w += v.w;
          }
        }
#pragma unroll
        for (int q = 0; q < 4; q++) *(float4*)&acc[j][lane*16 + q*4] = a[q];
      }
      __syncthreads();
      if (n >= 0) {
#pragma unroll
        for (int i = 0; i < 4; i++) {
          const int u = lane*4 + i;
          const float i_ = acc[j][u]       + biou[u];
          const float o_ = acc[j][256 + u] + biou[256 + u];
          const float uu = acc[j][512 + u] + biou[512 + u];
          const float cv = sigf(i_)*tanh_(uu) + acc[j][768 + u];
          const float hv = sigf(o_)*tanh_(cv);
          cl[j][u] = cv; hl[j][u] = hv;
          hout[(size_t)n*HID + u] = hv;
        }
      }
      __syncthreads();
      if (l == nlv - 1) continue;
      const int c8 = (ne - g0) < 8 ? (ne - g0) : 8;
      float s0[8] = {0,0,0,0,0,0,0,0};
      float s1[8] = {0,0,0,0,0,0,0,0};
      for (int k4 = 0; k4 < 64; ++k4) {
        const int kb = k4 << 2;
        float4 hj[8];
#pragma unroll
        for (int jj = 0; jj < 8; ++jj) hj[jj] = *(const float4*)&hl[jj][kb];
        const float w00 = UT[(size_t)(kb+0)*1024 + tid];
        const float w01 = UT[(size_t)(kb+1)*1024 + tid];
        const float w02 = UT[(size_t)(kb+2)*1024 + tid];
        const float w03 = UT[(size_t)(kb+3)*1024 + tid];
        const float w10 = UT[(size_t)(kb+0)*1024 + tid + 512];
        const float w11 = UT[(size_t)(kb+1)*1024 + tid + 512];
        const float w12 = UT[(size_t)(kb+2)*1024 + tid + 512];
        const float w13 = UT[(size_t)(kb+3)*1024 + tid + 512];
#pragma unroll
        for (int jj = 0; jj < 8; ++jj) {
          s0[jj] += w00*hj[jj].x + w01*hj[jj].y + w02*hj[jj].z + w03*hj[jj].w;
          s1[jj] += w10*hj[jj].x + w11*hj[jj].y + w12*hj[jj].z + w13*hj[jj].w;
        }
      }
      const int r1 = tid + 512;
#pragma unroll
      for (int jj = 0; jj < 8; ++jj) {
        if (jj < c8) {
          const int n2 = nl[g0 + jj];
          um[(size_t)n2*GG3 + tid] = s0[jj];
          if (r1 < GG3) {
            um[(size_t)n2*GG3 + r1] = s1[jj];
          } else {
            const int fr = r1 - GG3;
            fm[(size_t)n2*HID + fr] = sigf(s1[jj] + buf_[fr]) * cl[jj][fr];
          }
        }
      }
    }
  }
}

// ---------------- launch ------------------------------------------------------
extern "C" void kernel_launch(void* const* d_in, const int* in_sizes, int n_in,
                              void* d_out, int out_size, void* d_ws, size_t ws_size,
                              hipStream_t stream)
{
  const int*   embed_ids = (const int*)d_in[0];
  const int*   lengths   = (const int*)d_in[1];
  const int*   child_idx = (const int*)d_in[2];
  const int*   parent_idx= (const int*)d_in[3];
  const int*   tok_idx   = (const int*)d_in[4];
  const int*   node_level= (const int*)d_in[5];
  const float* emb  = (const float*)d_in[7];
  const float* wihf = (const float*)d_in[8];
  const float* whhf = (const float*)d_in[9];
  const float* bf   = (const float*)d_in[10];
  const float* wihb = (const float*)d_in[11];
  const float* whhb = (const float*)d_in[12];
  const float* bb   = (const float*)d_in[13];
  const float* Wiou = (const float*)d_in[14];
  const float* Uiou = (const float*)d_in[15];
  const float* biou = (const float*)d_in[16];
  const float* Uf   = (const float*)d_in[17];
  const float* buf_ = (const float*)d_in[18];
  const int E  = in_sizes[2];
  const int Nn = in_sizes[4];
  float* hout = (float*)d_out;

  char* w = (char*)d_ws;
  size_t off = 0;
  auto take = [&](size_t bytes) -> char* {
    char* p = w + off;
    off += (bytes + 255) & ~(size_t)255;
    return p;
  };
  int*      deg   = (int*)     take((size_t)(Nn+1)*4);     // zeroed: CSR degree/cursor
  size_t zero_end = off;
  ushort*   xh    = (ushort*)  take((size_t)8192*320*2);   // bf16, K padded
  ushort*   wtihf = (ushort*)  take((size_t)1024*320*2);
  ushort*   wtihb = (ushort*)  take((size_t)1024*320*2);
  ushort*   wiouh = (ushort*)  take((size_t)768*512*2);
  float*    xgf   = (float*)   take((size_t)8192*1024*4);
  float*    xgb   = (float*)   take((size_t)8192*1024*4);
  _Float16* wtf   = (_Float16*)take((size_t)32*1024*8*2);  // f16 [k8][g][8]
  _Float16* wtb   = (_Float16*)take((size_t)32*1024*8*2);
  float*    hsf   = (float*)   take((size_t)64*128*256*4);
  float*    hsb   = (float*)   take((size_t)64*128*256*4);
  ushort*   hxh   = (ushort*)  take((size_t)Nn*512*2);
  float*    iou   = (float*)   take((size_t)Nn*GG3*4);
  float*    um    = (float*)   take((size_t)Nn*GG3*4);
  float*    fm    = (float*)   take((size_t)Nn*HID*4);
  float*    UT    = (float*)   take((size_t)256*1024*4);
  int*      tnlist= (int*)     take((size_t)64*128*4);
  int*      tlvloff=(int*)     take((size_t)64*130*4);
  int*      tnlv  = (int*)     take((size_t)64*4);
  int*      choff = (int*)     take((size_t)(Nn+1)*4);
  int*      chlist= (int*)     take((size_t)(E>0?E:1)*4);
  (void)ws_size; (void)n_in; (void)out_size;

  hipMemsetAsync(d_ws, 0, zero_end, stream);
  gather_x_kernel<<<(8192*40 + 255)/256, 256, 0, stream>>>(embed_ids, emb, xh);
  cvt_pad_kernel<<<(1024*40 + 255)/256, 256, 0, stream>>>(wihf, wtihf, 300, 320, 1024*40);
  cvt_pad_kernel<<<(1024*40 + 255)/256, 256, 0, stream>>>(wihb, wtihb, 300, 320, 1024*40);
  cvt_pad_kernel<<<(768*64 + 255)/256, 256, 0, stream>>>(Wiou, wiouh, 512, 512, 768*64);
  mfma_gemm_kernel<true><<<dim3(64, 8), 256, 0, stream>>>(xh, wtihf, bf, xgf, 8192, 1024, 10);
  mfma_gemm_kernel<true><<<dim3(64, 8), 256, 0, stream>>>(xh, wtihb, bb, xgb, 8192, 1024, 10);
  transpose_w_kernel<<<(2*32*1024 + 255)/256, 256, 0, stream>>>(whhf, whhb, wtf, wtb);
  lstm_kernel<<<64, 512, 0, stream>>>(xgf, xgb, wtf, wtb, lengths, hsf, hsb);
  gather_hx_kernel<<<(Nn*64 + 255)/256, 256, 0, stream>>>(tok_idx, hsf, hsb, hxh, Nn);
  mfma_gemm_kernel<false><<<dim3((Nn + 127)/128, 6), 256, 0, stream>>>(hxh, wiouh, nullptr, iou, Nn, GG3, 16);
  ut_kernel<<<(256*1024 + 255)/256, 256, 0, stream>>>(Uiou, Uf, UT);
  csr_kernel<<<1, 1024, 0, stream>>>(child_idx, parent_idx, choff, chlist, deg, E, Nn);
  tree_sort_kernel<<<64, 128, 0, stream>>>(lengths, node_level, tnlist, tlvloff, tnlv);
  tree_kernel<<<64, 512, 0, stream>>>(tnlist, tlvloff, tnlv, choff, chlist, UT,
                                      biou, buf_, iou, um, fm, hout);
}

// Round 14
// 1284.329 us; speedup vs baseline: 3.2293x; 1.0478x over previous
//
#include <hip/hip_runtime.h>
#include <hip/hip_fp16.h>
#include <cstdint>
#include <cstddef>

#define TT 128
#define HID 256
#define GG4 1024
#define GG3 768

typedef _Float16 f16x2 __attribute__((ext_vector_type(2)));
typedef _Float16 f16x8 __attribute__((ext_vector_type(8)));
typedef short    bf16x8 __attribute__((ext_vector_type(8)));
typedef float    f32x4 __attribute__((ext_vector_type(4)));

union f16x8u { f16x8 v; f16x2 p[4]; };
union u2f { uint32_t u; f16x2 h; };

__device__ __forceinline__ float sigf(float x){ return 1.f/(1.f+__expf(-x)); }
__device__ __forceinline__ float tanh_(float x){
  float cx = fminf(fmaxf(x,-15.f),15.f);
  float e = __expf(2.f*cx);
  return (e-1.f)/(e+1.f);
}

__device__ __forceinline__ float dot2(f16x2 a, f16x2 b, float c){
#if __has_builtin(__builtin_amdgcn_fdot2)
  return __builtin_amdgcn_fdot2(a, b, c, false);
#else
  return c + (float)a[0]*(float)b[0] + (float)a[1]*(float)b[1];
#endif
}

__device__ __forceinline__ ushort f2bf(float x){
  union { float f; uint32_t u; } v; v.f = x;
  uint32_t r = v.u + 0x7FFF + ((v.u >> 16) & 1);
  return (ushort)(r >> 16);
}

// ---------- embedding gather -> bf16, K padded 300->320 ---------------------
__global__ __launch_bounds__(256) void gather_x_kernel(
    const int* __restrict__ ids, const float* __restrict__ emb, ushort* __restrict__ xh)
{
  int it = blockIdx.x*256 + threadIdx.x;        // item = m*40 + q  (320/8 chunks)
  if (it >= 8192*40) return;
  int m = it / 40, q = it - m*40;
  int k0 = q << 3;
  int id = ids[m];
  ushort o[8];
#pragma unroll
  for (int j = 0; j < 8; j++) {
    int k = k0 + j;
    o[j] = (k < 300) ? f2bf(emb[(size_t)id*300 + k]) : (ushort)0;
  }
  *(uint4*)&xh[(size_t)m*320 + k0] = *(uint4*)o;
}

// ---------- f32 -> bf16 with K padding --------------------------------------
__global__ __launch_bounds__(256) void cvt_pad_kernel(
    const float* __restrict__ src, ushort* __restrict__ dst, int K, int Kp, int nitem)
{
  int it = blockIdx.x*256 + threadIdx.x;
  if (it >= nitem) return;
  int chunks = Kp >> 3;
  int r = it / chunks, q = it - r*chunks;
  int k0 = q << 3;
  ushort o[8];
#pragma unroll
  for (int j = 0; j < 8; j++) {
    int k = k0 + j;
    o[j] = (k < K) ? f2bf(src[(size_t)r*K + k]) : (ushort)0;
  }
  *(uint4*)&dst[(size_t)r*Kp + k0] = *(uint4*)o;
}

// ---------- MFMA bf16 GEMM: C[m][n] = A[m][:]·Bt[n][:] (+bias) --------------
template<bool BIAS>
__global__ __launch_bounds__(256) void mfma_gemm_kernel(
    const ushort* __restrict__ A, const ushort* __restrict__ Bt,
    const float* __restrict__ bias, float* __restrict__ C,
    int M, int N, int ksteps)
{
  constexpr int LDS_ROW = 40;
  __shared__ ushort As[128*LDS_ROW];
  __shared__ ushort Bs[128*LDS_ROW];
  const int tid = threadIdx.x;
  const int m0 = blockIdx.x * 128, n0 = blockIdx.y * 128;
  const int wave = tid >> 6, lane = tid & 63;
  const int wm = (wave >> 1) * 64, wn = (wave & 1) * 64;
  const int fr = lane & 15;
  const int fk = (lane >> 4) << 3;
  const size_t Kp = (size_t)ksteps << 5;
  const int r0_ = tid >> 2,        k0_ = (tid & 3) << 3;
  const int r1_ = (tid + 256) >> 2, k1_ = ((tid + 256) & 3) << 3;
  f32x4 acc[4][4] = {};
  for (int ks = 0; ks < ksteps; ks++) {
    const int kb = ks << 5;
    uint4 av0 = make_uint4(0,0,0,0), av1 = make_uint4(0,0,0,0);
    if (m0 + r0_ < M) av0 = *(const uint4*)&A[(size_t)(m0+r0_)*Kp + kb + k0_];
    if (m0 + r1_ < M) av1 = *(const uint4*)&A[(size_t)(m0+r1_)*Kp + kb + k1_];
    const uint4 bv0 = *(const uint4*)&Bt[(size_t)(n0+r0_)*Kp + kb + k0_];
    const uint4 bv1 = *(const uint4*)&Bt[(size_t)(n0+r1_)*Kp + kb + k1_];
    __syncthreads();
    *(uint4*)&As[r0_*LDS_ROW + k0_] = av0;
    *(uint4*)&As[r1_*LDS_ROW + k1_] = av1;
    *(uint4*)&Bs[r0_*LDS_ROW + k0_] = bv0;
    *(uint4*)&Bs[r1_*LDS_ROW + k1_] = bv1;
    __syncthreads();
    bf16x8 af[4], bfr[4];
#pragma unroll
    for (int i = 0; i < 4; i++) {
      af[i]  = *(const bf16x8*)&As[(wm + i*16 + fr)*LDS_ROW + fk];
      bfr[i] = *(const bf16x8*)&Bs[(wn + i*16 + fr)*LDS_ROW + fk];
    }
#pragma unroll
    for (int mi = 0; mi < 4; mi++)
#pragma unroll
      for (int ni = 0; ni < 4; ni++)
        acc[mi][ni] = __builtin_amdgcn_mfma_f32_16x16x32_bf16(af[mi], bfr[ni], acc[mi][ni], 0, 0, 0);
  }
  const int drow = (lane >> 4) << 2, dcol = lane & 15;
#pragma unroll
  for (int mi = 0; mi < 4; mi++) {
#pragma unroll
    for (int ni = 0; ni < 4; ni++) {
      const int col = n0 + wn + ni*16 + dcol;
      const float bv = BIAS ? bias[col] : 0.f;
#pragma unroll
      for (int r = 0; r < 4; r++) {
        const int row = m0 + wm + mi*16 + drow + r;
        if (row < M) C[(size_t)row*N + col] = acc[mi][ni][r] + bv;
      }
    }
  }
}

// ------- Whh transpose + f16 pack: wt[k8][g][0..7] = half(W[g][8k8+j]) ------
__global__ __launch_bounds__(256) void transpose_w_kernel(
    const float* __restrict__ whhf, const float* __restrict__ whhb,
    _Float16* __restrict__ wtf, _Float16* __restrict__ wtb)
{
  int it = blockIdx.x*256 + threadIdx.x;  // dir(1) | k8(5) | g(10)
  if (it >= 2*32*1024) return;
  int dir = it >> 15, rem = it & 32767;
  int k8 = rem >> 10, g = rem & 1023;
  const float* w = dir ? whhb : whhf;
  _Float16*   wt = dir ? wtb  : wtf;
  f16x8 pk;
#pragma unroll
  for (int j = 0; j < 8; j++) pk[j] = (_Float16)w[(size_t)g*HID + (k8<<3) + j];
  *(f16x8*)&wt[(((size_t)k8<<10) + g) << 3] = pk;
}

// ---------------- batch-split bidirectional LSTM (no inter-block sync) ------
// 64 blocks x 1024 threads (16 waves/CU); dir = ((blk&7)>>2) XCD-grouped.
// Thread t owns ONE gate row t for 2 batch rows (1 b128 weight load per k8,
// reused for both). Gate-0 threads hold c and do the cell update. 2 barriers.
__global__ __launch_bounds__(1024, 1) void lstm_kernel(
    const float* __restrict__ xgf, const float* __restrict__ xgb,
    const _Float16* __restrict__ wtf, const _Float16* __restrict__ wtb,
    const int* __restrict__ lengths,
    float* __restrict__ hsf, float* __restrict__ hsb)
{
  const int b8  = blockIdx.x & 7;
  const int dir = b8 >> 2;
  const int p   = (blockIdx.x >> 3) * 4 + (b8 & 3);   // 0..31
  const int r0 = 2*p, r1 = r0 + 1;
  const float* __restrict__ xg = dir ? xgb : xgf;
  const _Float16* __restrict__ wt = dir ? wtb : wtf;
  float* __restrict__ hs = dir ? hsb : hsf;
  const int t = threadIdx.x;
  const int u = t & 255, gate = t >> 8;

  __shared__ _Float16 hb[2][256];
  __shared__ float ex[4][2][256];
  if (t < 256) { hb[0][t] = (_Float16)0.f; hb[1][t] = (_Float16)0.f; }
  __syncthreads();

  const int len0 = lengths[r0], len1 = lengths[r1];   // len0 >= len1
  float c0 = 0.f, c1 = 0.f;
  for (int s = 0; s < len0; s++) {
    const bool a1 = s < len1;
    const int t0 = dir ? (len0 - 1 - s) : s;
    const int t1 = dir ? (len1 - 1 - s) : s;
    const float xa0 = xg[((size_t)r0*TT + t0)*GG4 + t];
    const float xa1 = a1 ? xg[((size_t)r1*TT + t1)*GG4 + t] : 0.f;
    float acc0 = 0.f, acc1 = 0.f;
#pragma unroll 8
    for (int k8 = 0; k8 < 32; k8++) {
      f16x8u w, h0, h1;
      w.v  = *(const f16x8*)&wt[(((size_t)k8<<10) + t) << 3];
      h0.v = *(const f16x8*)&hb[0][k8 << 3];
      h1.v = *(const f16x8*)&hb[1][k8 << 3];
#pragma unroll
      for (int j = 0; j < 4; j++) {
        acc0 = dot2(w.p[j], h0.p[j], acc0);
        acc1 = dot2(w.p[j], h1.p[j], acc1);
      }
    }
    ex[gate][0][u] = acc0 + xa0;
    ex[gate][1][u] = acc1 + xa1;
    __syncthreads();           // hb reads done + ex published
    if (gate == 0) {
      {
        const float ig = sigf(ex[0][0][u]);
        const float fg = sigf(ex[1][0][u]);
        const float gg = tanh_(ex[2][0][u]);
        const float og = sigf(ex[3][0][u]);
        c0 = fg*c0 + ig*gg;
        const float h = og*tanh_(c0);
        hb[0][u] = (_Float16)h;
        hs[((size_t)r0*TT + t0)*HID + u] = h;
      }
      if (a1) {
        const float ig = sigf(ex[0][1][u]);
        const float fg = sigf(ex[1][1][u]);
        const float gg = tanh_(ex[2][1][u]);
        const float og = sigf(ex[3][1][u]);
        c1 = fg*c1 + ig*gg;
        const float h = og*tanh_(c1);
        hb[1][u] = (_Float16)h;
        hs[((size_t)r1*TT + t1)*HID + u] = h;
      }
    }
    __syncthreads();           // new h visible; ex free for next iter
  }
}

// ---------------- hxh = bf16 concat(h_f[tok], h_b[tok]) ---------------------
__global__ __launch_bounds__(256) void gather_hx_kernel(
    const int* __restrict__ tok, const float* __restrict__ hsf,
    const float* __restrict__ hsb, ushort* __restrict__ hxh, int Nn)
{
  int it = blockIdx.x*256 + threadIdx.x;     // item = n*64 + q (512/8 chunks)
  if (it >= Nn*64) return;
  int n = it >> 6, q = it & 63;
  int k0 = q << 3;
  int tk = tok[n];
  int b = tk >> 7, t = tk & 127;
  const float* src = (k0 < 256) ? &hsf[((size_t)b*TT + t)*HID + k0]
                                : &hsb[((size_t)b*TT + t)*HID + (k0 - 256)];
  ushort o[8];
#pragma unroll
  for (int j = 0; j < 8; j++) o[j] = f2bf(src[j]);
  *(uint4*)&hxh[(size_t)n*512 + k0] = *(uint4*)o;
}

// ------ wth[k][2r] = f16 UT row r; wth[k][2r+1] = f16 UT row r+512 ----------
// (UT[r][k] = r<768 ? Uiou[r][k] : Uf[r-768][k])
__global__ __launch_bounds__(256) void uth_kernel(
    const float* __restrict__ Uiou, const float* __restrict__ Uf,
    _Float16* __restrict__ wth)
{
  int idx = blockIdx.x*256 + threadIdx.x;
  if (idx >= 256*512) return;
  int k = idx >> 9, rr = idx & 511;
  const float v0 = Uiou[(size_t)rr*HID + k];            // rr < 512 < 768
  const int r2 = rr + 512;
  const float v1 = (r2 < GG3) ? Uiou[(size_t)r2*HID + k]
                              : Uf[(size_t)(r2-GG3)*HID + k];
  wth[(size_t)k*1024 + (rr<<1)]     = (_Float16)v0;
  wth[(size_t)k*1024 + (rr<<1) + 1] = (_Float16)v1;
}

// ---------------- children CSR by parent ------------------------------------
__global__ __launch_bounds__(1024) void csr_kernel(
    const int* __restrict__ child_idx, const int* __restrict__ parent_idx,
    int* __restrict__ choff, int* __restrict__ chlist,
    int* __restrict__ deg /* zeroed; reused as cursor */, int E, int Nn)
{
  __shared__ int part[1024];
  const int tid = threadIdx.x;
  for (int e = tid; e < E; e += 1024) atomicAdd(&deg[parent_idx[e]], 1);
  __syncthreads();
  int loc[8]; int s = 0;
#pragma unroll
  for (int m = 0; m < 8; m++) {
    const int i = tid*8 + m;
    loc[m] = s;
    s += (i < Nn) ? deg[i] : 0;
  }
  part[tid] = s;
  __syncthreads();
  for (int off = 1; off < 1024; off <<= 1) {
    int v = (tid >= off) ? part[tid - off] : 0;
    __syncthreads();
    part[tid] += v;
    __syncthreads();
  }
  const int pre = (tid > 0) ? part[tid-1] : 0;
#pragma unroll
  for (int m = 0; m < 8; m++) {
    const int i = tid*8 + m;
    if (i < Nn) choff[i] = pre + loc[m];
  }
  if (tid == 1023) choff[Nn] = part[1023];
  __syncthreads();
#pragma unroll
  for (int m = 0; m < 8; m++) {
    const int i = tid*8 + m;
    if (i < Nn) deg[i] = pre + loc[m];
  }
  __syncthreads();
  for (int e = tid; e < E; e += 1024) {
    int pos = atomicAdd(&deg[parent_idx[e]], 1);
    chlist[pos] = child_idx[e];
  }
}

// ---------------- per-tree level sort ---------------------------------------
__global__ __launch_bounds__(128) void tree_sort_kernel(
    const int* __restrict__ lengths, const int* __restrict__ node_level,
    int* __restrict__ tnlist, int* __restrict__ tlvloff, int* __restrict__ tnlv)
{
  const int b = blockIdx.x, tid = threadIdx.x;
  __shared__ int hist[130], cur[129];
  __shared__ int off_s, len_s, mx;
  if (tid == 0) {
    int o = 0;
    for (int i = 0; i < b; i++) o += lengths[i];
    off_s = o; len_s = lengths[b]; mx = 1;
  }
  for (int i = tid; i < 130; i += 128) hist[i] = 0;
  __syncthreads();
  const int off = off_s, len = len_s;
  for (int i = tid; i < len; i += 128) {
    int lv = node_level[off + i];
    atomicAdd(&hist[lv], 1);
    atomicMax(&mx, lv + 1);
  }
  __syncthreads();
  if (tid == 0) {
    int s = 0;
    for (int l = 0; l < 129; l++) { cur[l] = s; tlvloff[b*130 + l] = s; s += hist[l]; }
    tlvloff[b*130 + 129] = s;
    tnlv[b] = mx;
  }
  __syncthreads();
  for (int i = tid; i < len; i += 128) {
    int lv = node_level[off + i];
    int pos = atomicAdd(&cur[lv], 1);
    tnlist[b*128 + pos] = off + i;
  }
}

// ---------------- tree: one block per tree, NO inter-block sync -------------
__global__ __launch_bounds__(512) void tree_kernel(
    const int* __restrict__ tnlist, const int* __restrict__ tlvloff,
    const int* __restrict__ tnlv,
    const int* __restrict__ choff, const int* __restrict__ chlist,
    const _Float16* __restrict__ wth,
    const float* __restrict__ biou, const float* __restrict__ buf_,
    const float* __restrict__ iou,
    float* __restrict__ um, float* __restrict__ fm,
    float* __restrict__ hout)
{
  const int b = blockIdx.x;
  const int tid = threadIdx.x;
  const int nlv = tnlv[b];
  const int* __restrict__ nl = tnlist + b*128;
  const int* __restrict__ lo = tlvloff + b*130;
  __shared__ float acc[8][1024];
  __shared__ float hl[8][256];
  __shared__ float cl[8][256];
  const int j = tid >> 6, lane = tid & 63;
  for (int l = 0; l < nlv; l++) {
    const int na = lo[l], ne = lo[l+1];
    for (int g0 = na; g0 < ne; g0 += 8) {
      __syncthreads();
      const int n = (g0 + j < ne) ? nl[g0 + j] : -1;
      if (n >= 0) {
        float4 a[4];
#pragma unroll
        for (int q = 0; q < 4; q++) {
          const int d = lane*16 + q*4;
          a[q] = (d < GG3) ? *(const float4*)&iou[(size_t)n*GG3 + d]
                           : make_float4(0.f,0.f,0.f,0.f);
        }
        const int e0 = choff[n], e1 = choff[n+1];
        for (int e = e0; e < e1; ++e) {
          const int ch = chlist[e];
#pragma unroll
          for (int q = 0; q < 4; q++) {
            const int d = lane*16 + q*4;
            const float4 v = (d < GG3) ? *(const float4*)&um[(size_t)ch*GG3 + d]
                                       : *(const float4*)&fm[(size_t)ch*HID + (d-GG3)];
            a[q].x += v.x; a[q].y += v.y; a[q].z += v.z; a[q].w += v.w;
          }
        }
#pragma unroll
        for (int q = 0; q < 4; q++) *(float4*)&acc[j][lane*16 + q*4] = a[q];
      }
      __syncthreads();
      if (n >= 0) {
#pragma unroll
        for (int i = 0; i < 4; i++) {
          const int u = lane*4 + i;
          const float i_ = acc[j][u]       + biou[u];
          const float o_ = acc[j][256 + u] + biou[256 + u];
          const float uu = acc[j][512 + u] + biou[512 + u];
          const float cv = sigf(i_)*tanh_(uu) + acc[j][768 + u];
          const float hv = sigf(o_)*tanh_(cv);
          cl[j][u] = cv; hl[j][u] = hv;
          hout[(size_t)n*HID + u] = hv;
        }
      }
      __syncthreads();
      if (l == nlv - 1) continue;
      const int c8 = (ne - g0) < 8 ? (ne - g0) : 8;
      float s0[8] = {0,0,0,0,0,0,0,0};
      float s1[8] = {0,0,0,0,0,0,0,0};
      for (int k4 = 0; k4 < 64; ++k4) {
        const int kb = k4 << 2;
        float4 hj[8];
#pragma unroll
        for (int jj = 0; jj < 8; ++jj) hj[jj] = *(const float4*)&hl[jj][kb];
        u2f q0, q1, q2, q3;
        q0.u = *(const uint32_t*)&wth[(size_t)(kb+0)*1024 + (tid<<1)];
        q1.u = *(const uint32_t*)&wth[(size_t)(kb+1)*1024 + (tid<<1)];
        q2.u = *(const uint32_t*)&wth[(size_t)(kb+2)*1024 + (tid<<1)];
        q3.u = *(const uint32_t*)&wth[(size_t)(kb+3)*1024 + (tid<<1)];
        const float w00 = (float)q0.h[0], w10 = (float)q0.h[1];
        const float w01 = (float)q1.h[0], w11 = (float)q1.h[1];
        const float w02 = (float)q2.h[0], w12 = (float)q2.h[1];
        const float w03 = (float)q3.h[0], w13 = (float)q3.h[1];
#pragma unroll
        for (int jj = 0; jj < 8; ++jj) {
          s0[jj] += w00*hj[jj].x + w01*hj[jj].y + w02*hj[jj].z + w03*hj[jj].w;
          s1[jj] += w10*hj[jj].x + w11*hj[jj].y + w12*hj[jj].z + w13*hj[jj].w;
        }
      }
      const int r1 = tid + 512;
#pragma unroll
      for (int jj = 0; jj < 8; ++jj) {
        if (jj < c8) {
          const int n2 = nl[g0 + jj];
          um[(size_t)n2*GG3 + tid] = s0[jj];
          if (r1 < GG3) {
            um[(size_t)n2*GG3 + r1] = s1[jj];
          } else {
            const int fr = r1 - GG3;
            fm[(size_t)n2*HID + fr] = sigf(s1[jj] + buf_[fr]) * cl[jj][fr];
          }
        }
      }
    }
  }
}

// ---------------- launch ------------------------------------------------------
extern "C" void kernel_launch(void* const* d_in, const int* in_sizes, int n_in,
                              void* d_out, int out_size, void* d_ws, size_t ws_size,
                              hipStream_t stream)
{
  const int*   embed_ids = (const int*)d_in[0];
  const int*   lengths   = (const int*)d_in[1];
  const int*   child_idx = (const int*)d_in[2];
  const int*   parent_idx= (const int*)d_in[3];
  const int*   tok_idx   = (const int*)d_in[4];
  const int*   node_level= (const int*)d_in[5];
  const float* emb  = (const float*)d_in[7];
  const float* wihf = (const float*)d_in[8];
  const float* whhf = (const float*)d_in[9];
  const float* bf   = (const float*)d_in[10];
  const float* wihb = (const float*)d_in[11];
  const float* whhb = (const float*)d_in[12];
  const float* bb   = (const float*)d_in[13];
  const float* Wiou = (const float*)d_in[14];
  const float* Uiou = (const float*)d_in[15];
  const float* biou = (const float*)d_in[16];
  const float* Uf   = (const float*)d_in[17];
  const float* buf_ = (const float*)d_in[18];
  const int E  = in_sizes[2];
  const int Nn = in_sizes[4];
  float* hout = (float*)d_out;

  char* w = (char*)d_ws;
  size_t off = 0;
  auto take = [&](size_t bytes) -> char* {
    char* p = w + off;
    off += (bytes + 255) & ~(size_t)255;
    return p;
  };
  int*      deg   = (int*)     take((size_t)(Nn+1)*4);     // zeroed: CSR degree/cursor
  size_t zero_end = off;
  ushort*   xh    = (ushort*)  take((size_t)8192*320*2);   // bf16, K padded
  ushort*   wtihf = (ushort*)  take((size_t)1024*320*2);
  ushort*   wtihb = (ushort*)  take((size_t)1024*320*2);
  ushort*   wiouh = (ushort*)  take((size_t)768*512*2);
  float*    xgf   = (float*)   take((size_t)8192*1024*4);
  float*    xgb   = (float*)   take((size_t)8192*1024*4);
  _Float16* wtf   = (_Float16*)take((size_t)32*1024*8*2);  // f16 [k8][g][8]
  _Float16* wtb   = (_Float16*)take((size_t)32*1024*8*2);
  float*    hsf   = (float*)   take((size_t)64*128*256*4);
  float*    hsb   = (float*)   take((size_t)64*128*256*4);
  ushort*   hxh   = (ushort*)  take((size_t)Nn*512*2);
  float*    iou   = (float*)   take((size_t)Nn*GG3*4);
  float*    um    = (float*)   take((size_t)Nn*GG3*4);
  float*    fm    = (float*)   take((size_t)Nn*HID*4);
  _Float16* wth   = (_Float16*)take((size_t)256*1024*2);   // f16 pair-packed UT
  int*      tnlist= (int*)     take((size_t)64*128*4);
  int*      tlvloff=(int*)     take((size_t)64*130*4);
  int*      tnlv  = (int*)     take((size_t)64*4);
  int*      choff = (int*)     take((size_t)(Nn+1)*4);
  int*      chlist= (int*)     take((size_t)(E>0?E:1)*4);
  (void)ws_size; (void)n_in; (void)out_size;

  hipMemsetAsync(d_ws, 0, zero_end, stream);
  gather_x_kernel<<<(8192*40 + 255)/256, 256, 0, stream>>>(embed_ids, emb, xh);
  cvt_pad_kernel<<<(1024*40 + 255)/256, 256, 0, stream>>>(wihf, wtihf, 300, 320, 1024*40);
  cvt_pad_kernel<<<(1024*40 + 255)/256, 256, 0, stream>>>(wihb, wtihb, 300, 320, 1024*40);
  cvt_pad_kernel<<<(768*64 + 255)/256, 256, 0, stream>>>(Wiou, wiouh, 512, 512, 768*64);
  mfma_gemm_kernel<true><<<dim3(64, 8), 256, 0, stream>>>(xh, wtihf, bf, xgf, 8192, 1024, 10);
  mfma_gemm_kernel<true><<<dim3(64, 8), 256, 0, stream>>>(xh, wtihb, bb, xgb, 8192, 1024, 10);
  transpose_w_kernel<<<(2*32*1024 + 255)/256, 256, 0, stream>>>(whhf, whhb, wtf, wtb);
  lstm_kernel<<<64, 1024, 0, stream>>>(xgf, xgb, wtf, wtb, lengths, hsf, hsb);
  gather_hx_kernel<<<(Nn*64 + 255)/256, 256, 0, stream>>>(tok_idx, hsf, hsb, hxh, Nn);
  mfma_gemm_kernel<false><<<dim3((Nn + 127)/128, 6), 256, 0, stream>>>(hxh, wiouh, nullptr, iou, Nn, GG3, 16);
  uth_kernel<<<(256*512 + 255)/256, 256, 0, stream>>>(Uiou, Uf, wth);
  csr_kernel<<<1, 1024, 0, stream>>>(child_idx, parent_idx, choff, chlist, deg, E, Nn);
  tree_sort_kernel<<<64, 128, 0, stream>>>(lengths, node_level, tnlist, tlvloff, tnlv);
  tree_kernel<<<64, 512, 0, stream>>>(tnlist, tlvloff, tnlv, choff, chlist, wth,
                                      biou, buf_, iou, um, fm, hout);
}

// Round 15
// 1018.594 us; speedup vs baseline: 4.0718x; 1.2609x over previous
//
#include <hip/hip_runtime.h>
#include <hip/hip_fp16.h>
#include <cstdint>
#include <cstddef>

#define TT 128
#define HID 256
#define GG4 1024
#define GG3 768

typedef _Float16 f16x2 __attribute__((ext_vector_type(2)));
typedef _Float16 f16x8 __attribute__((ext_vector_type(8)));
typedef short    bf16x8 __attribute__((ext_vector_type(8)));
typedef float    f32x4 __attribute__((ext_vector_type(4)));

union f16x8u { f16x8 v; f16x2 p[4]; };

__device__ __forceinline__ float sigf(float x){ return 1.f/(1.f+__expf(-x)); }
__device__ __forceinline__ float tanh_(float x){
  float cx = fminf(fmaxf(x,-15.f),15.f);
  float e = __expf(2.f*cx);
  return (e-1.f)/(e+1.f);
}

__device__ __forceinline__ float dot2(f16x2 a, f16x2 b, float c){
#if __has_builtin(__builtin_amdgcn_fdot2)
  return __builtin_amdgcn_fdot2(a, b, c, false);
#else
  return c + (float)a[0]*(float)b[0] + (float)a[1]*(float)b[1];
#endif
}

__device__ __forceinline__ ushort f2bf(float x){
  union { float f; uint32_t u; } v; v.f = x;
  uint32_t r = v.u + 0x7FFF + ((v.u >> 16) & 1);
  return (ushort)(r >> 16);
}

// ---------- embedding gather -> bf16, K padded 300->320 ---------------------
__global__ __launch_bounds__(256) void gather_x_kernel(
    const int* __restrict__ ids, const float* __restrict__ emb, ushort* __restrict__ xh)
{
  int it = blockIdx.x*256 + threadIdx.x;        // item = m*40 + q  (320/8 chunks)
  if (it >= 8192*40) return;
  int m = it / 40, q = it - m*40;
  int k0 = q << 3;
  int id = ids[m];
  ushort o[8];
#pragma unroll
  for (int j = 0; j < 8; j++) {
    int k = k0 + j;
    o[j] = (k < 300) ? f2bf(emb[(size_t)id*300 + k]) : (ushort)0;
  }
  *(uint4*)&xh[(size_t)m*320 + k0] = *(uint4*)o;
}

// ---------- f32 -> bf16 with K padding --------------------------------------
__global__ __launch_bounds__(256) void cvt_pad_kernel(
    const float* __restrict__ src, ushort* __restrict__ dst, int K, int Kp, int nitem)
{
  int it = blockIdx.x*256 + threadIdx.x;
  if (it >= nitem) return;
  int chunks = Kp >> 3;
  int r = it / chunks, q = it - r*chunks;
  int k0 = q << 3;
  ushort o[8];
#pragma unroll
  for (int j = 0; j < 8; j++) {
    int k = k0 + j;
    o[j] = (k < K) ? f2bf(src[(size_t)r*K + k]) : (ushort)0;
  }
  *(uint4*)&dst[(size_t)r*Kp + k0] = *(uint4*)o;
}

// ---------- MFMA bf16 GEMM: C[m][n] = A[m][:]·Bt[n][:] (+bias) --------------
template<bool BIAS>
__global__ __launch_bounds__(256) void mfma_gemm_kernel(
    const ushort* __restrict__ A, const ushort* __restrict__ Bt,
    const float* __restrict__ bias, float* __restrict__ C,
    int M, int N, int ksteps)
{
  constexpr int LDS_ROW = 40;
  __shared__ ushort As[128*LDS_ROW];
  __shared__ ushort Bs[128*LDS_ROW];
  const int tid = threadIdx.x;
  const int m0 = blockIdx.x * 128, n0 = blockIdx.y * 128;
  const int wave = tid >> 6, lane = tid & 63;
  const int wm = (wave >> 1) * 64, wn = (wave & 1) * 64;
  const int fr = lane & 15;
  const int fk = (lane >> 4) << 3;
  const size_t Kp = (size_t)ksteps << 5;
  const int r0_ = tid >> 2,        k0_ = (tid & 3) << 3;
  const int r1_ = (tid + 256) >> 2, k1_ = ((tid + 256) & 3) << 3;
  f32x4 acc[4][4] = {};
  for (int ks = 0; ks < ksteps; ks++) {
    const int kb = ks << 5;
    uint4 av0 = make_uint4(0,0,0,0), av1 = make_uint4(0,0,0,0);
    if (m0 + r0_ < M) av0 = *(const uint4*)&A[(size_t)(m0+r0_)*Kp + kb + k0_];
    if (m0 + r1_ < M) av1 = *(const uint4*)&A[(size_t)(m0+r1_)*Kp + kb + k1_];
    const uint4 bv0 = *(const uint4*)&Bt[(size_t)(n0+r0_)*Kp + kb + k0_];
    const uint4 bv1 = *(const uint4*)&Bt[(size_t)(n0+r1_)*Kp + kb + k1_];
    __syncthreads();
    *(uint4*)&As[r0_*LDS_ROW + k0_] = av0;
    *(uint4*)&As[r1_*LDS_ROW + k1_] = av1;
    *(uint4*)&Bs[r0_*LDS_ROW + k0_] = bv0;
    *(uint4*)&Bs[r1_*LDS_ROW + k1_] = bv1;
    __syncthreads();
    bf16x8 af[4], bfr[4];
#pragma unroll
    for (int i = 0; i < 4; i++) {
      af[i]  = *(const bf16x8*)&As[(wm + i*16 + fr)*LDS_ROW + fk];
      bfr[i] = *(const bf16x8*)&Bs[(wn + i*16 + fr)*LDS_ROW + fk];
    }
#pragma unroll
    for (int mi = 0; mi < 4; mi++)
#pragma unroll
      for (int ni = 0; ni < 4; ni++)
        acc[mi][ni] = __builtin_amdgcn_mfma_f32_16x16x32_bf16(af[mi], bfr[ni], acc[mi][ni], 0, 0, 0);
  }
  const int drow = (lane >> 4) << 2, dcol = lane & 15;
#pragma unroll
  for (int mi = 0; mi < 4; mi++) {
#pragma unroll
    for (int ni = 0; ni < 4; ni++) {
      const int col = n0 + wn + ni*16 + dcol;
      const float bv = BIAS ? bias[col] : 0.f;
#pragma unroll
      for (int r = 0; r < 4; r++) {
        const int row = m0 + wm + mi*16 + drow + r;
        if (row < M) C[(size_t)row*N + col] = acc[mi][ni][r] + bv;
      }
    }
  }
}

// ------- Whh transpose + f16 pack: wt[k8][g][0..7] = half(W[g][8k8+j]) ------
__global__ __launch_bounds__(256) void transpose_w_kernel(
    const float* __restrict__ whhf, const float* __restrict__ whhb,
    _Float16* __restrict__ wtf, _Float16* __restrict__ wtb)
{
  int it = blockIdx.x*256 + threadIdx.x;  // dir(1) | k8(5) | g(10)
  if (it >= 2*32*1024) return;
  int dir = it >> 15, rem = it & 32767;
  int k8 = rem >> 10, g = rem & 1023;
  const float* w = dir ? whhb : whhf;
  _Float16*   wt = dir ? wtb  : wtf;
  f16x8 pk;
#pragma unroll
  for (int j = 0; j < 8; j++) pk[j] = (_Float16)w[(size_t)g*HID + (k8<<3) + j];
  *(f16x8*)&wt[(((size_t)k8<<10) + g) << 3] = pk;
}

// ---------------- batch-split bidirectional LSTM (no inter-block sync) ------
__global__ __launch_bounds__(1024, 1) void lstm_kernel(
    const float* __restrict__ xgf, const float* __restrict__ xgb,
    const _Float16* __restrict__ wtf, const _Float16* __restrict__ wtb,
    const int* __restrict__ lengths,
    float* __restrict__ hsf, float* __restrict__ hsb)
{
  const int b8  = blockIdx.x & 7;
  const int dir = b8 >> 2;
  const int p   = (blockIdx.x >> 3) * 4 + (b8 & 3);   // 0..31
  const int r0 = 2*p, r1 = r0 + 1;
  const float* __restrict__ xg = dir ? xgb : xgf;
  const _Float16* __restrict__ wt = dir ? wtb : wtf;
  float* __restrict__ hs = dir ? hsb : hsf;
  const int t = threadIdx.x;
  const int u = t & 255, gate = t >> 8;

  __shared__ _Float16 hb[2][256];
  __shared__ float ex[4][2][256];
  if (t < 256) { hb[0][t] = (_Float16)0.f; hb[1][t] = (_Float16)0.f; }
  __syncthreads();

  const int len0 = lengths[r0], len1 = lengths[r1];   // len0 >= len1
  float c0 = 0.f, c1 = 0.f;
  for (int s = 0; s < len0; s++) {
    const bool a1 = s < len1;
    const int t0 = dir ? (len0 - 1 - s) : s;
    const int t1 = dir ? (len1 - 1 - s) : s;
    const float xa0 = xg[((size_t)r0*TT + t0)*GG4 + t];
    const float xa1 = a1 ? xg[((size_t)r1*TT + t1)*GG4 + t] : 0.f;
    float acc0 = 0.f, acc1 = 0.f;
#pragma unroll 8
    for (int k8 = 0; k8 < 32; k8++) {
      f16x8u w, h0, h1;
      w.v  = *(const f16x8*)&wt[(((size_t)k8<<10) + t) << 3];
      h0.v = *(const f16x8*)&hb[0][k8 << 3];
      h1.v = *(const f16x8*)&hb[1][k8 << 3];
#pragma unroll
      for (int j = 0; j < 4; j++) {
        acc0 = dot2(w.p[j], h0.p[j], acc0);
        acc1 = dot2(w.p[j], h1.p[j], acc1);
      }
    }
    ex[gate][0][u] = acc0 + xa0;
    ex[gate][1][u] = acc1 + xa1;
    __syncthreads();
    if (gate == 0) {
      {
        const float ig = sigf(ex[0][0][u]);
        const float fg = sigf(ex[1][0][u]);
        const float gg = tanh_(ex[2][0][u]);
        const float og = sigf(ex[3][0][u]);
        c0 = fg*c0 + ig*gg;
        const float h = og*tanh_(c0);
        hb[0][u] = (_Float16)h;
        hs[((size_t)r0*TT + t0)*HID + u] = h;
      }
      if (a1) {
        const float ig = sigf(ex[0][1][u]);
        const float fg = sigf(ex[1][1][u]);
        const float gg = tanh_(ex[2][1][u]);
        const float og = sigf(ex[3][1][u]);
        c1 = fg*c1 + ig*gg;
        const float h = og*tanh_(c1);
        hb[1][u] = (_Float16)h;
        hs[((size_t)r1*TT + t1)*HID + u] = h;
      }
    }
    __syncthreads();
  }
}

// ---------------- hxh = bf16 concat(h_f[tok], h_b[tok]) ---------------------
__global__ __launch_bounds__(256) void gather_hx_kernel(
    const int* __restrict__ tok, const float* __restrict__ hsf,
    const float* __restrict__ hsb, ushort* __restrict__ hxh, int Nn)
{
  int it = blockIdx.x*256 + threadIdx.x;     // item = n*64 + q (512/8 chunks)
  if (it >= Nn*64) return;
  int n = it >> 6, q = it & 63;
  int k0 = q << 3;
  int tk = tok[n];
  int b = tk >> 7, t = tk & 127;
  const float* src = (k0 < 256) ? &hsf[((size_t)b*TT + t)*HID + k0]
                                : &hsb[((size_t)b*TT + t)*HID + (k0 - 256)];
  ushort o[8];
#pragma unroll
  for (int j = 0; j < 8; j++) o[j] = f2bf(src[j]);
  *(uint4*)&hxh[(size_t)n*512 + k0] = *(uint4*)o;
}

// ------ UTbf[r][k] bf16 row-major; row r = (r<768 ? Uiou[r] : Uf[r-768]) ----
__global__ __launch_bounds__(256) void utbf_kernel(
    const float* __restrict__ Uiou, const float* __restrict__ Uf,
    ushort* __restrict__ UTbf)
{
  int idx = blockIdx.x*256 + threadIdx.x;       // r(10) | chunk(5)
  if (idx >= 1024*32) return;
  int r = idx >> 5, c = (idx & 31) << 3;
  const float* src = (r < GG3) ? &Uiou[(size_t)r*HID + c] : &Uf[(size_t)(r-GG3)*HID + c];
  ushort o[8];
#pragma unroll
  for (int j = 0; j < 8; j++) o[j] = f2bf(src[j]);
  *(uint4*)&UTbf[(size_t)r*HID + c] = *(uint4*)o;
}

// ---------------- children CSR by parent ------------------------------------
__global__ __launch_bounds__(1024) void csr_kernel(
    const int* __restrict__ child_idx, const int* __restrict__ parent_idx,
    int* __restrict__ choff, int* __restrict__ chlist,
    int* __restrict__ deg /* zeroed; reused as cursor */, int E, int Nn)
{
  __shared__ int part[1024];
  const int tid = threadIdx.x;
  for (int e = tid; e < E; e += 1024) atomicAdd(&deg[parent_idx[e]], 1);
  __syncthreads();
  int loc[8]; int s = 0;
#pragma unroll
  for (int m = 0; m < 8; m++) {
    const int i = tid*8 + m;
    loc[m] = s;
    s += (i < Nn) ? deg[i] : 0;
  }
  part[tid] = s;
  __syncthreads();
  for (int off = 1; off < 1024; off <<= 1) {
    int v = (tid >= off) ? part[tid - off] : 0;
    __syncthreads();
    part[tid] += v;
    __syncthreads();
  }
  const int pre = (tid > 0) ? part[tid-1] : 0;
#pragma unroll
  for (int m = 0; m < 8; m++) {
    const int i = tid*8 + m;
    if (i < Nn) choff[i] = pre + loc[m];
  }
  if (tid == 1023) choff[Nn] = part[1023];
  __syncthreads();
#pragma unroll
  for (int m = 0; m < 8; m++) {
    const int i = tid*8 + m;
    if (i < Nn) deg[i] = pre + loc[m];
  }
  __syncthreads();
  for (int e = tid; e < E; e += 1024) {
    int pos = atomicAdd(&deg[parent_idx[e]], 1);
    chlist[pos] = child_idx[e];
  }
}

// ---------------- per-tree level sort ---------------------------------------
__global__ __launch_bounds__(128) void tree_sort_kernel(
    const int* __restrict__ lengths, const int* __restrict__ node_level,
    int* __restrict__ tnlist, int* __restrict__ tlvloff, int* __restrict__ tnlv)
{
  const int b = blockIdx.x, tid = threadIdx.x;
  __shared__ int hist[130], cur[129];
  __shared__ int off_s, len_s, mx;
  if (tid == 0) {
    int o = 0;
    for (int i = 0; i < b; i++) o += lengths[i];
    off_s = o; len_s = lengths[b]; mx = 1;
  }
  for (int i = tid; i < 130; i += 128) hist[i] = 0;
  __syncthreads();
  const int off = off_s, len = len_s;
  for (int i = tid; i < len; i += 128) {
    int lv = node_level[off + i];
    atomicAdd(&hist[lv], 1);
    atomicMax(&mx, lv + 1);
  }
  __syncthreads();
  if (tid == 0) {
    int s = 0;
    for (int l = 0; l < 129; l++) { cur[l] = s; tlvloff[b*130 + l] = s; s += hist[l]; }
    tlvloff[b*130 + 129] = s;
    tnlv[b] = mx;
  }
  __syncthreads();
  for (int i = tid; i < len; i += 128) {
    int lv = node_level[off + i];
    int pos = atomicAdd(&cur[lv], 1);
    tnlist[b*128 + pos] = off + i;
  }
}

// ---------------- tree: one block/tree, 16-node groups, MFMA phase B --------
// Phase A: acc[j][0..767]=iou + children um ; acc[j][768..1023]= children fm.
// Apply -> cl (f32), hl (bf16), hout. Phase B: D[16 nodes][1024 rows] =
// hl(16x256) @ UTbf^T via mfma 16x16x32; rows<768 -> um, rows>=768 -> fm.
__global__ __launch_bounds__(512) void tree_kernel(
    const int* __restrict__ tnlist, const int* __restrict__ tlvloff,
    const int* __restrict__ tnlv,
    const int* __restrict__ choff, const int* __restrict__ chlist,
    const ushort* __restrict__ UTbf,
    const float* __restrict__ biou, const float* __restrict__ buf_,
    const float* __restrict__ iou,
    float* __restrict__ um, float* __restrict__ fm,
    float* __restrict__ hout)
{
  const int b = blockIdx.x;
  const int tid = threadIdx.x;
  const int nlv = tnlv[b];
  const int* __restrict__ nl = tnlist + b*128;
  const int* __restrict__ lo = tlvloff + b*130;
  __shared__ float  acc[16][1024];     // 64 KB
  __shared__ ushort hl[16][264];       // bf16 h, padded
  __shared__ float  cl[16][260];       // f32 c, padded
  __shared__ int    nid[16];
  const int j5 = tid >> 5, lane5 = tid & 31;   // phase A: 32 thr/node
  const int wave = tid >> 6, lane = tid & 63;  // phase B
  const int fr16 = lane & 15, khalf = lane >> 4;
  for (int l = 0; l < nlv; l++) {
    const int na = lo[l], ne = lo[l+1];
    for (int g0 = na; g0 < ne; g0 += 16) {
      __syncthreads();                 // prev group done; acc/hl/cl free
      const int n = (g0 + j5 < ne) ? nl[g0 + j5] : -1;
      if (lane5 == 0) nid[j5] = n;
      if (n >= 0) {
#pragma unroll
        for (int q = 0; q < 8; q++) {
          const int d = (q*32 + lane5) << 2;
          float4 a = (d < GG3) ? *(const float4*)&iou[(size_t)n*GG3 + d]
                               : make_float4(0.f,0.f,0.f,0.f);
          *(float4*)&acc[j5][d] = a;
        }
        const int e0 = choff[n], e1 = choff[n+1];
        for (int e = e0; e < e1; ++e) {
          const int ch = chlist[e];
#pragma unroll
          for (int q = 0; q < 8; q++) {
            const int d = (q*32 + lane5) << 2;
            const float4 v = (d < GG3) ? *(const float4*)&um[(size_t)ch*GG3 + d]
                                       : *(const float4*)&fm[(size_t)ch*HID + (d-GG3)];
            float4 a = *(float4*)&acc[j5][d];
            a.x += v.x; a.y += v.y; a.z += v.z; a.w += v.w;
            *(float4*)&acc[j5][d] = a;
          }
        }
      }
      __syncthreads();                 // acc ready
      if (n >= 0) {
#pragma unroll
        for (int i = 0; i < 8; i++) {
          const int u = (lane5 << 3) + i;
          const float i_ = acc[j5][u]       + biou[u];
          const float o_ = acc[j5][256 + u] + biou[256 + u];
          const float uu = acc[j5][512 + u] + biou[512 + u];
          const float cv = sigf(i_)*tanh_(uu) + acc[j5][768 + u];
          const float hv = sigf(o_)*tanh_(cv);
          cl[j5][u] = cv;
          hl[j5][u] = f2bf(hv);
          hout[(size_t)n*HID + u] = hv;
        }
      } else {
#pragma unroll
        for (int i = 0; i < 8; i++) hl[j5][(lane5 << 3) + i] = 0;
      }
      __syncthreads();                 // hl/cl/nid ready
      if (l == nlv - 1) continue;      // root level: nothing consumes messages
      // ---- Phase B: MFMA. A-frag: node=fr16 rows of hl; per-wave 8 n-tiles.
      bf16x8 af[8];
#pragma unroll
      for (int ks = 0; ks < 8; ks++)
        af[ks] = *(const bf16x8*)&hl[fr16][ks*32 + (khalf << 3)];
      for (int nt = wave; nt < 64; nt += 8) {
        f32x4 dacc = {0.f, 0.f, 0.f, 0.f};
#pragma unroll
        for (int ks = 0; ks < 8; ks++) {
          const bf16x8 bfr = *(const bf16x8*)&UTbf[(size_t)(nt*16 + fr16)*HID + ks*32 + (khalf << 3)];
          dacc = __builtin_amdgcn_mfma_f32_16x16x32_bf16(af[ks], bfr, dacc, 0, 0, 0);
        }
        const int r = nt*16 + fr16;    // D: col=fr16 -> output row r; regs -> nodes
        if (r < GG3) {
#pragma unroll
          for (int g = 0; g < 4; g++) {
            const int n2 = nid[(khalf << 2) + g];
            if (n2 >= 0) um[(size_t)n2*GG3 + r] = dacc[g];
          }
        } else {
          const int fr = r - GG3;
          const float bv = buf_[fr];
#pragma unroll
          for (int g = 0; g < 4; g++) {
            const int jj = (khalf << 2) + g;
            const int n2 = nid[jj];
            if (n2 >= 0) fm[(size_t)n2*HID + fr] = sigf(dacc[g] + bv) * cl[jj][fr];
          }
        }
      }
    }
  }
}

// ---------------- launch ------------------------------------------------------
extern "C" void kernel_launch(void* const* d_in, const int* in_sizes, int n_in,
                              void* d_out, int out_size, void* d_ws, size_t ws_size,
                              hipStream_t stream)
{
  const int*   embed_ids = (const int*)d_in[0];
  const int*   lengths   = (const int*)d_in[1];
  const int*   child_idx = (const int*)d_in[2];
  const int*   parent_idx= (const int*)d_in[3];
  const int*   tok_idx   = (const int*)d_in[4];
  const int*   node_level= (const int*)d_in[5];
  const float* emb  = (const float*)d_in[7];
  const float* wihf = (const float*)d_in[8];
  const float* whhf = (const float*)d_in[9];
  const float* bf   = (const float*)d_in[10];
  const float* wihb = (const float*)d_in[11];
  const float* whhb = (const float*)d_in[12];
  const float* bb   = (const float*)d_in[13];
  const float* Wiou = (const float*)d_in[14];
  const float* Uiou = (const float*)d_in[15];
  const float* biou = (const float*)d_in[16];
  const float* Uf   = (const float*)d_in[17];
  const float* buf_ = (const float*)d_in[18];
  const int E  = in_sizes[2];
  const int Nn = in_sizes[4];
  float* hout = (float*)d_out;

  char* w = (char*)d_ws;
  size_t off = 0;
  auto take = [&](size_t bytes) -> char* {
    char* p = w + off;
    off += (bytes + 255) & ~(size_t)255;
    return p;
  };
  int*      deg   = (int*)     take((size_t)(Nn+1)*4);     // zeroed: CSR degree/cursor
  size_t zero_end = off;
  ushort*   xh    = (ushort*)  take((size_t)8192*320*2);   // bf16, K padded
  ushort*   wtihf = (ushort*)  take((size_t)1024*320*2);
  ushort*   wtihb = (ushort*)  take((size_t)1024*320*2);
  ushort*   wiouh = (ushort*)  take((size_t)768*512*2);
  float*    xgf   = (float*)   take((size_t)8192*1024*4);
  float*    xgb   = (float*)   take((size_t)8192*1024*4);
  _Float16* wtf   = (_Float16*)take((size_t)32*1024*8*2);  // f16 [k8][g][8]
  _Float16* wtb   = (_Float16*)take((size_t)32*1024*8*2);
  float*    hsf   = (float*)   take((size_t)64*128*256*4);
  float*    hsb   = (float*)   take((size_t)64*128*256*4);
  ushort*   hxh   = (ushort*)  take((size_t)Nn*512*2);
  float*    iou   = (float*)   take((size_t)Nn*GG3*4);
  float*    um    = (float*)   take((size_t)Nn*GG3*4);
  float*    fm    = (float*)   take((size_t)Nn*HID*4);
  ushort*   UTbf  = (ushort*)  take((size_t)1024*256*2);   // bf16 row-major
  int*      tnlist= (int*)     take((size_t)64*128*4);
  int*      tlvloff=(int*)     take((size_t)64*130*4);
  int*      tnlv  = (int*)     take((size_t)64*4);
  int*      choff = (int*)     take((size_t)(Nn+1)*4);
  int*      chlist= (int*)     take((size_t)(E>0?E:1)*4);
  (void)ws_size; (void)n_in; (void)out_size;

  hipMemsetAsync(d_ws, 0, zero_end, stream);
  gather_x_kernel<<<(8192*40 + 255)/256, 256, 0, stream>>>(embed_ids, emb, xh);
  cvt_pad_kernel<<<(1024*40 + 255)/256, 256, 0, stream>>>(wihf, wtihf, 300, 320, 1024*40);
  cvt_pad_kernel<<<(1024*40 + 255)/256, 256, 0, stream>>>(wihb, wtihb, 300, 320, 1024*40);
  cvt_pad_kernel<<<(768*64 + 255)/256, 256, 0, stream>>>(Wiou, wiouh, 512, 512, 768*64);
  mfma_gemm_kernel<true><<<dim3(64, 8), 256, 0, stream>>>(xh, wtihf, bf, xgf, 8192, 1024, 10);
  mfma_gemm_kernel<true><<<dim3(64, 8), 256, 0, stream>>>(xh, wtihb, bb, xgb, 8192, 1024, 10);
  transpose_w_kernel<<<(2*32*1024 + 255)/256, 256, 0, stream>>>(whhf, whhb, wtf, wtb);
  lstm_kernel<<<64, 1024, 0, stream>>>(xgf, xgb, wtf, wtb, lengths, hsf, hsb);
  gather_hx_kernel<<<(Nn*64 + 255)/256, 256, 0, stream>>>(tok_idx, hsf, hsb, hxh, Nn);
  mfma_gemm_kernel<false><<<dim3((Nn + 127)/128, 6), 256, 0, stream>>>(hxh, wiouh, nullptr, iou, Nn, GG3, 16);
  utbf_kernel<<<(1024*32 + 255)/256, 256, 0, stream>>>(Uiou, Uf, UTbf);
  csr_kernel<<<1, 1024, 0, stream>>>(child_idx, parent_idx, choff, chlist, deg, E, Nn);
  tree_sort_kernel<<<64, 128, 0, stream>>>(lengths, node_level, tnlist, tlvloff, tnlv);
  tree_kernel<<<64, 512, 0, stream>>>(tnlist, tlvloff, tnlv, choff, chlist, UTbf,
                                      biou, buf_, iou, um, fm, hout);
}

// Round 16
// 1010.756 us; speedup vs baseline: 4.1033x; 1.0078x over previous
//
#include <hip/hip_runtime.h>
#include <hip/hip_fp16.h>
#include <cstdint>
#include <cstddef>

#define TT 128
#define HID 256
#define GG4 1024
#define GG3 768

typedef _Float16 f16x2 __attribute__((ext_vector_type(2)));
typedef _Float16 f16x8 __attribute__((ext_vector_type(8)));
typedef short    bf16x8 __attribute__((ext_vector_type(8)));
typedef float    f32x4 __attribute__((ext_vector_type(4)));

union f16x8u { f16x8 v; f16x2 p[4]; };

__device__ __forceinline__ float sigf(float x){ return 1.f/(1.f+__expf(-x)); }
__device__ __forceinline__ float tanh_(float x){
  float cx = fminf(fmaxf(x,-15.f),15.f);
  float e = __expf(2.f*cx);
  return (e-1.f)/(e+1.f);
}

__device__ __forceinline__ float dot2(f16x2 a, f16x2 b, float c){
#if __has_builtin(__builtin_amdgcn_fdot2)
  return __builtin_amdgcn_fdot2(a, b, c, false);
#else
  return c + (float)a[0]*(float)b[0] + (float)a[1]*(float)b[1];
#endif
}

__device__ __forceinline__ ushort f2bf(float x){
  union { float f; uint32_t u; } v; v.f = x;
  uint32_t r = v.u + 0x7FFF + ((v.u >> 16) & 1);
  return (ushort)(r >> 16);
}

// ---------------- fused elementwise prep (6 segments, grid-stride) ----------
// seg0 [0,327680): gather_x -> xh bf16 [8192][320]
// seg1 [327680,368640): wihf -> wtihf bf16 [1024][320]
// seg2 [368640,409600): wihb -> wtihb
// seg3 [409600,458752): Wiou -> wiouh bf16 [768][512]
// seg4 [458752,524288): whh f16 transpose wt[k8][g][8]
// seg5 [524288,557056): UTbf bf16 [1024][256]
__global__ __launch_bounds__(256) void prep_kernel(
    const int* __restrict__ ids, const float* __restrict__ emb, ushort* __restrict__ xh,
    const float* __restrict__ wihf, ushort* __restrict__ wtihf,
    const float* __restrict__ wihb, ushort* __restrict__ wtihb,
    const float* __restrict__ Wiou, ushort* __restrict__ wiouh,
    const float* __restrict__ whhf, const float* __restrict__ whhb,
    _Float16* __restrict__ wtf, _Float16* __restrict__ wtb,
    const float* __restrict__ Uiou, const float* __restrict__ Uf,
    ushort* __restrict__ UTbf)
{
  for (int it = blockIdx.x*256 + threadIdx.x; it < 557056; it += gridDim.x*256) {
    if (it < 327680) {
      int m = it / 40, q = it - m*40;
      int k0 = q << 3;
      int id = ids[m];
      ushort o[8];
#pragma unroll
      for (int j = 0; j < 8; j++) {
        int k = k0 + j;
        o[j] = (k < 300) ? f2bf(emb[(size_t)id*300 + k]) : (ushort)0;
      }
      *(uint4*)&xh[(size_t)m*320 + k0] = *(uint4*)o;
    } else if (it < 409600) {
      int i2 = it - 327680;
      const float* src = wihf; ushort* dst = wtihf;
      if (i2 >= 40960) { i2 -= 40960; src = wihb; dst = wtihb; }
      int r = i2 / 40, q = i2 - r*40;
      int k0 = q << 3;
      ushort o[8];
#pragma unroll
      for (int j = 0; j < 8; j++) {
        int k = k0 + j;
        o[j] = (k < 300) ? f2bf(src[(size_t)r*300 + k]) : (ushort)0;
      }
      *(uint4*)&dst[(size_t)r*320 + k0] = *(uint4*)o;
    } else if (it < 458752) {
      int i2 = it - 409600;
      int r = i2 >> 6, k0 = (i2 & 63) << 3;
      ushort o[8];
#pragma unroll
      for (int j = 0; j < 8; j++) o[j] = f2bf(Wiou[(size_t)r*512 + k0 + j]);
      *(uint4*)&wiouh[(size_t)r*512 + k0] = *(uint4*)o;
    } else if (it < 524288) {
      int i2 = it - 458752;
      int dir = i2 >> 15, rem = i2 & 32767;
      int k8 = rem >> 10, g = rem & 1023;
      const float* w = dir ? whhb : whhf;
      _Float16*   wt = dir ? wtb  : wtf;
      f16x8 pk;
#pragma unroll
      for (int j = 0; j < 8; j++) pk[j] = (_Float16)w[(size_t)g*HID + (k8<<3) + j];
      *(f16x8*)&wt[(((size_t)k8<<10) + g) << 3] = pk;
    } else {
      int i2 = it - 524288;
      int r = i2 >> 5, c = (i2 & 31) << 3;
      const float* src = (r < GG3) ? &Uiou[(size_t)r*HID + c] : &Uf[(size_t)(r-GG3)*HID + c];
      ushort o[8];
#pragma unroll
      for (int j = 0; j < 8; j++) o[j] = f2bf(src[j]);
      *(uint4*)&UTbf[(size_t)r*HID + c] = *(uint4*)o;
    }
  }
}

// ---------- MFMA bf16 GEMM, double-buffered: C = A·Bt^T (+bias) -------------
template<bool BIAS>
__global__ __launch_bounds__(256) void mfma_gemm_kernel(
    const ushort* __restrict__ A, const ushort* __restrict__ Bt,
    const float* __restrict__ bias, float* __restrict__ C,
    int M, int N, int ksteps)
{
  constexpr int LDS_ROW = 40;
  __shared__ ushort As[128*LDS_ROW];
  __shared__ ushort Bs[128*LDS_ROW];
  const int tid = threadIdx.x;
  const int m0 = blockIdx.x * 128, n0 = blockIdx.y * 128;
  const int wave = tid >> 6, lane = tid & 63;
  const int wm = (wave >> 1) * 64, wn = (wave & 1) * 64;
  const int fr = lane & 15;
  const int fk = (lane >> 4) << 3;
  const size_t Kp = (size_t)ksteps << 5;
  const int r0_ = tid >> 2,        k0_ = (tid & 3) << 3;
  const int r1_ = (tid + 256) >> 2, k1_ = ((tid + 256) & 3) << 3;
  f32x4 acc[4][4] = {};
  {
    uint4 av0 = make_uint4(0,0,0,0), av1 = make_uint4(0,0,0,0);
    if (m0 + r0_ < M) av0 = *(const uint4*)&A[(size_t)(m0+r0_)*Kp + k0_];
    if (m0 + r1_ < M) av1 = *(const uint4*)&A[(size_t)(m0+r1_)*Kp + k1_];
    const uint4 bv0 = *(const uint4*)&Bt[(size_t)(n0+r0_)*Kp + k0_];
    const uint4 bv1 = *(const uint4*)&Bt[(size_t)(n0+r1_)*Kp + k1_];
    *(uint4*)&As[r0_*LDS_ROW + k0_] = av0;
    *(uint4*)&As[r1_*LDS_ROW + k1_] = av1;
    *(uint4*)&Bs[r0_*LDS_ROW + k0_] = bv0;
    *(uint4*)&Bs[r1_*LDS_ROW + k1_] = bv1;
  }
  __syncthreads();
  for (int ks = 0; ks < ksteps; ks++) {
    uint4 nav0 = make_uint4(0,0,0,0), nav1 = make_uint4(0,0,0,0);
    uint4 nbv0 = make_uint4(0,0,0,0), nbv1 = make_uint4(0,0,0,0);
    const bool more = (ks + 1 < ksteps);
    if (more) {
      const int kb = (ks + 1) << 5;
      if (m0 + r0_ < M) nav0 = *(const uint4*)&A[(size_t)(m0+r0_)*Kp + kb + k0_];
      if (m0 + r1_ < M) nav1 = *(const uint4*)&A[(size_t)(m0+r1_)*Kp + kb + k1_];
      nbv0 = *(const uint4*)&Bt[(size_t)(n0+r0_)*Kp + kb + k0_];
      nbv1 = *(const uint4*)&Bt[(size_t)(n0+r1_)*Kp + kb + k1_];
    }
    bf16x8 af[4], bfr[4];
#pragma unroll
    for (int i = 0; i < 4; i++) {
      af[i]  = *(const bf16x8*)&As[(wm + i*16 + fr)*LDS_ROW + fk];
      bfr[i] = *(const bf16x8*)&Bs[(wn + i*16 + fr)*LDS_ROW + fk];
    }
#pragma unroll
    for (int mi = 0; mi < 4; mi++)
#pragma unroll
      for (int ni = 0; ni < 4; ni++)
        acc[mi][ni] = __builtin_amdgcn_mfma_f32_16x16x32_bf16(af[mi], bfr[ni], acc[mi][ni], 0, 0, 0);
    __syncthreads();
    if (more) {
      *(uint4*)&As[r0_*LDS_ROW + k0_] = nav0;
      *(uint4*)&As[r1_*LDS_ROW + k1_] = nav1;
      *(uint4*)&Bs[r0_*LDS_ROW + k0_] = nbv0;
      *(uint4*)&Bs[r1_*LDS_ROW + k1_] = nbv1;
      __syncthreads();
    }
  }
  const int drow = (lane >> 4) << 2, dcol = lane & 15;
#pragma unroll
  for (int mi = 0; mi < 4; mi++) {
#pragma unroll
    for (int ni = 0; ni < 4; ni++) {
      const int col = n0 + wn + ni*16 + dcol;
      const float bv = BIAS ? bias[col] : 0.f;
#pragma unroll
      for (int r = 0; r < 4; r++) {
        const int row = m0 + wm + mi*16 + drow + r;
        if (row < M) C[(size_t)row*N + col] = acc[mi][ni][r] + bv;
      }
    }
  }
}

// ---------------- batch-split bidirectional LSTM (no inter-block sync) ------
__global__ __launch_bounds__(1024, 1) void lstm_kernel(
    const float* __restrict__ xgf, const float* __restrict__ xgb,
    const _Float16* __restrict__ wtf, const _Float16* __restrict__ wtb,
    const int* __restrict__ lengths,
    float* __restrict__ hsf, float* __restrict__ hsb)
{
  const int b8  = blockIdx.x & 7;
  const int dir = b8 >> 2;
  const int p   = (blockIdx.x >> 3) * 4 + (b8 & 3);   // 0..31
  const int r0 = 2*p, r1 = r0 + 1;
  const float* __restrict__ xg = dir ? xgb : xgf;
  const _Float16* __restrict__ wt = dir ? wtb : wtf;
  float* __restrict__ hs = dir ? hsb : hsf;
  const int t = threadIdx.x;
  const int u = t & 255, gate = t >> 8;

  __shared__ _Float16 hb[2][256];
  __shared__ float ex[4][2][256];
  if (t < 256) { hb[0][t] = (_Float16)0.f; hb[1][t] = (_Float16)0.f; }
  __syncthreads();

  const int len0 = lengths[r0], len1 = lengths[r1];   // len0 >= len1
  float c0 = 0.f, c1 = 0.f;
  for (int s = 0; s < len0; s++) {
    const bool a1 = s < len1;
    const int t0 = dir ? (len0 - 1 - s) : s;
    const int t1 = dir ? (len1 - 1 - s) : s;
    const float xa0 = xg[((size_t)r0*TT + t0)*GG4 + t];
    const float xa1 = a1 ? xg[((size_t)r1*TT + t1)*GG4 + t] : 0.f;
    float acc0 = 0.f, acc1 = 0.f;
#pragma unroll 8
    for (int k8 = 0; k8 < 32; k8++) {
      f16x8u w, h0, h1;
      w.v  = *(const f16x8*)&wt[(((size_t)k8<<10) + t) << 3];
      h0.v = *(const f16x8*)&hb[0][k8 << 3];
      h1.v = *(const f16x8*)&hb[1][k8 << 3];
#pragma unroll
      for (int j = 0; j < 4; j++) {
        acc0 = dot2(w.p[j], h0.p[j], acc0);
        acc1 = dot2(w.p[j], h1.p[j], acc1);
      }
    }
    ex[gate][0][u] = acc0 + xa0;
    ex[gate][1][u] = acc1 + xa1;
    __syncthreads();
    if (gate == 0) {
      {
        const float ig = sigf(ex[0][0][u]);
        const float fg = sigf(ex[1][0][u]);
        const float gg = tanh_(ex[2][0][u]);
        const float og = sigf(ex[3][0][u]);
        c0 = fg*c0 + ig*gg;
        const float h = og*tanh_(c0);
        hb[0][u] = (_Float16)h;
        hs[((size_t)r0*TT + t0)*HID + u] = h;
      }
      if (a1) {
        const float ig = sigf(ex[0][1][u]);
        const float fg = sigf(ex[1][1][u]);
        const float gg = tanh_(ex[2][1][u]);
        const float og = sigf(ex[3][1][u]);
        c1 = fg*c1 + ig*gg;
        const float h = og*tanh_(c1);
        hb[1][u] = (_Float16)h;
        hs[((size_t)r1*TT + t1)*HID + u] = h;
      }
    }
    __syncthreads();
  }
}

// ---------------- hxh = bf16 concat(h_f[tok], h_b[tok]) ---------------------
__global__ __launch_bounds__(256) void gather_hx_kernel(
    const int* __restrict__ tok, const float* __restrict__ hsf,
    const float* __restrict__ hsb, ushort* __restrict__ hxh, int Nn)
{
  int it = blockIdx.x*256 + threadIdx.x;     // item = n*64 + q (512/8 chunks)
  if (it >= Nn*64) return;
  int n = it >> 6, q = it & 63;
  int k0 = q << 3;
  int tk = tok[n];
  int b = tk >> 7, t = tk & 127;
  const float* src = (k0 < 256) ? &hsf[((size_t)b*TT + t)*HID + k0]
                                : &hsb[((size_t)b*TT + t)*HID + (k0 - 256)];
  ushort o[8];
#pragma unroll
  for (int j = 0; j < 8; j++) o[j] = f2bf(src[j]);
  *(uint4*)&hxh[(size_t)n*512 + k0] = *(uint4*)o;
}

// ---------------- children CSR by parent ------------------------------------
__global__ __launch_bounds__(1024) void csr_kernel(
    const int* __restrict__ child_idx, const int* __restrict__ parent_idx,
    int* __restrict__ choff, int* __restrict__ chlist,
    int* __restrict__ deg /* zeroed; reused as cursor */, int E, int Nn)
{
  __shared__ int part[1024];
  const int tid = threadIdx.x;
  for (int e = tid; e < E; e += 1024) atomicAdd(&deg[parent_idx[e]], 1);
  __syncthreads();
  int loc[8]; int s = 0;
#pragma unroll
  for (int m = 0; m < 8; m++) {
    const int i = tid*8 + m;
    loc[m] = s;
    s += (i < Nn) ? deg[i] : 0;
  }
  part[tid] = s;
  __syncthreads();
  for (int off = 1; off < 1024; off <<= 1) {
    int v = (tid >= off) ? part[tid - off] : 0;
    __syncthreads();
    part[tid] += v;
    __syncthreads();
  }
  const int pre = (tid > 0) ? part[tid-1] : 0;
#pragma unroll
  for (int m = 0; m < 8; m++) {
    const int i = tid*8 + m;
    if (i < Nn) choff[i] = pre + loc[m];
  }
  if (tid == 1023) choff[Nn] = part[1023];
  __syncthreads();
#pragma unroll
  for (int m = 0; m < 8; m++) {
    const int i = tid*8 + m;
    if (i < Nn) deg[i] = pre + loc[m];
  }
  __syncthreads();
  for (int e = tid; e < E; e += 1024) {
    int pos = atomicAdd(&deg[parent_idx[e]], 1);
    chlist[pos] = child_idx[e];
  }
}

// ---------------- per-tree level sort ---------------------------------------
__global__ __launch_bounds__(128) void tree_sort_kernel(
    const int* __restrict__ lengths, const int* __restrict__ node_level,
    int* __restrict__ tnlist, int* __restrict__ tlvloff, int* __restrict__ tnlv)
{
  const int b = blockIdx.x, tid = threadIdx.x;
  __shared__ int hist[130], cur[129];
  __shared__ int off_s, len_s, mx;
  if (tid == 0) {
    int o = 0;
    for (int i = 0; i < b; i++) o += lengths[i];
    off_s = o; len_s = lengths[b]; mx = 1;
  }
  for (int i = tid; i < 130; i += 128) hist[i] = 0;
  __syncthreads();
  const int off = off_s, len = len_s;
  for (int i = tid; i < len; i += 128) {
    int lv = node_level[off + i];
    atomicAdd(&hist[lv], 1);
    atomicMax(&mx, lv + 1);
  }
  __syncthreads();
  if (tid == 0) {
    int s = 0;
    for (int l = 0; l < 129; l++) { cur[l] = s; tlvloff[b*130 + l] = s; s += hist[l]; }
    tlvloff[b*130 + 129] = s;
    tnlv[b] = mx;
  }
  __syncthreads();
  for (int i = tid; i < len; i += 128) {
    int lv = node_level[off + i];
    int pos = atomicAdd(&cur[lv], 1);
    tnlist[b*128 + pos] = off + i;
  }
}

// ------- tree: one block/tree; phase A register-resident; MFMA phase B ------
__global__ __launch_bounds__(512) void tree_kernel(
    const int* __restrict__ tnlist, const int* __restrict__ tlvloff,
    const int* __restrict__ tnlv,
    const int* __restrict__ choff, const int* __restrict__ chlist,
    const ushort* __restrict__ UTbf,
    const float* __restrict__ biou, const float* __restrict__ buf_,
    const float* __restrict__ iou,
    float* __restrict__ um, float* __restrict__ fm,
    float* __restrict__ hout)
{
  const int b = blockIdx.x;
  const int tid = threadIdx.x;
  const int nlv = tnlv[b];
  const int* __restrict__ nl = tnlist + b*128;
  const int* __restrict__ lo = tlvloff + b*130;
  __shared__ ushort hl[16][264];       // bf16 h, padded
  __shared__ float  cl[16][260];       // f32 c, padded
  __shared__ int    nid[16];
  const int j5 = tid >> 5, lane5 = tid & 31;   // phase A: 32 thr/node
  const int wave = tid >> 6, lane = tid & 63;  // phase B
  const int fr16 = lane & 15, khalf = lane >> 4;
  for (int l = 0; l < nlv; l++) {
    const int na = lo[l], ne = lo[l+1];
    for (int g0 = na; g0 < ne; g0 += 16) {
      __syncthreads();                 // prev group's phase B done
      const int n = (g0 + j5 < ne) ? nl[g0 + j5] : -1;
      if (lane5 == 0) nid[j5] = n;
      if (n >= 0) {
        f32x4 a[8];
#pragma unroll
        for (int q = 0; q < 8; q++) {
          const int d = (q*32 + lane5) << 2;
          if (d < GG3) a[q] = *(const f32x4*)&iou[(size_t)n*GG3 + d];
          else         a[q] = (f32x4){0.f, 0.f, 0.f, 0.f};
        }
        const int e0 = choff[n], e1 = choff[n+1];
        for (int eb = e0; eb < e1; eb += 4) {
          int ch4[4];
#pragma unroll
          for (int i = 0; i < 4; i++) ch4[i] = (eb + i < e1) ? chlist[eb + i] : -1;
#pragma unroll
          for (int i = 0; i < 4; i++) {
            const int ch = ch4[i];
            if (ch >= 0) {
#pragma unroll
              for (int q = 0; q < 8; q++) {
                const int d = (q*32 + lane5) << 2;
                const f32x4 v = (d < GG3)
                  ? *(const f32x4*)&um[(size_t)ch*GG3 + d]
                  : *(const f32x4*)&fm[(size_t)ch*HID + (d - GG3)];
                a[q] += v;
              }
            }
          }
        }
        // apply: u = qq*128 + lane5*4 + i ; pairs (a[qq],a[qq+2],a[qq+4],a[qq+6])
#pragma unroll
        for (int qq = 0; qq < 2; qq++) {
#pragma unroll
          for (int i = 0; i < 4; i++) {
            const int u = qq*128 + (lane5 << 2) + i;
            const float i_ = a[qq][i]   + biou[u];
            const float o_ = a[qq+2][i] + biou[256 + u];
            const float uu = a[qq+4][i] + biou[512 + u];
            const float cv = sigf(i_)*tanh_(uu) + a[qq+6][i];
            const float hv = sigf(o_)*tanh_(cv);
            cl[j5][u] = cv;
            hl[j5][u] = f2bf(hv);
            hout[(size_t)n*HID + u] = hv;
          }
        }
      } else {
#pragma unroll
        for (int q = 0; q < 8; q++) hl[j5][(q << 5) + lane5] = 0;
      }
      __syncthreads();                 // hl/cl/nid ready
      if (l == nlv - 1) continue;      // root level: nothing consumes messages
      bf16x8 af[8];
#pragma unroll
      for (int ks = 0; ks < 8; ks++)
        af[ks] = *(const bf16x8*)&hl[fr16][ks*32 + (khalf << 3)];
      for (int nt = wave; nt < 64; nt += 8) {
        f32x4 dacc = {0.f, 0.f, 0.f, 0.f};
#pragma unroll
        for (int ks = 0; ks < 8; ks++) {
          const bf16x8 bfr = *(const bf16x8*)&UTbf[(size_t)(nt*16 + fr16)*HID + ks*32 + (khalf << 3)];
          dacc = __builtin_amdgcn_mfma_f32_16x16x32_bf16(af[ks], bfr, dacc, 0, 0, 0);
        }
        const int r = nt*16 + fr16;
        if (r < GG3) {
#pragma unroll
          for (int g = 0; g < 4; g++) {
            const int n2 = nid[(khalf << 2) + g];
            if (n2 >= 0) um[(size_t)n2*GG3 + r] = dacc[g];
          }
        } else {
          const int fr = r - GG3;
          const float bv = buf_[fr];
#pragma unroll
          for (int g = 0; g < 4; g++) {
            const int jj = (khalf << 2) + g;
            const int n2 = nid[jj];
            if (n2 >= 0) fm[(size_t)n2*HID + fr] = sigf(dacc[g] + bv) * cl[jj][fr];
          }
        }
      }
    }
  }
}

// ---------------- launch ------------------------------------------------------
extern "C" void kernel_launch(void* const* d_in, const int* in_sizes, int n_in,
                              void* d_out, int out_size, void* d_ws, size_t ws_size,
                              hipStream_t stream)
{
  const int*   embed_ids = (const int*)d_in[0];
  const int*   lengths   = (const int*)d_in[1];
  const int*   child_idx = (const int*)d_in[2];
  const int*   parent_idx= (const int*)d_in[3];
  const int*   tok_idx   = (const int*)d_in[4];
  const int*   node_level= (const int*)d_in[5];
  const float* emb  = (const float*)d_in[7];
  const float* wihf = (const float*)d_in[8];
  const float* whhf = (const float*)d_in[9];
  const float* bf   = (const float*)d_in[10];
  const float* wihb = (const float*)d_in[11];
  const float* whhb = (const float*)d_in[12];
  const float* bb   = (const float*)d_in[13];
  const float* Wiou = (const float*)d_in[14];
  const float* Uiou = (const float*)d_in[15];
  const float* biou = (const float*)d_in[16];
  const float* Uf   = (const float*)d_in[17];
  const float* buf_ = (const float*)d_in[18];
  const int E  = in_sizes[2];
  const int Nn = in_sizes[4];
  float* hout = (float*)d_out;

  char* w = (char*)d_ws;
  size_t off = 0;
  auto take = [&](size_t bytes) -> char* {
    char* p = w + off;
    off += (bytes + 255) & ~(size_t)255;
    return p;
  };
  int*      deg   = (int*)     take((size_t)(Nn+1)*4);     // zeroed: CSR degree/cursor
  size_t zero_end = off;
  ushort*   xh    = (ushort*)  take((size_t)8192*320*2);   // bf16, K padded
  ushort*   wtihf = (ushort*)  take((size_t)1024*320*2);
  ushort*   wtihb = (ushort*)  take((size_t)1024*320*2);
  ushort*   wiouh = (ushort*)  take((size_t)768*512*2);
  float*    xgf   = (float*)   take((size_t)8192*1024*4);
  float*    xgb   = (float*)   take((size_t)8192*1024*4);
  _Float16* wtf   = (_Float16*)take((size_t)32*1024*8*2);  // f16 [k8][g][8]
  _Float16* wtb   = (_Float16*)take((size_t)32*1024*8*2);
  float*    hsf   = (float*)   take((size_t)64*128*256*4);
  float*    hsb   = (float*)   take((size_t)64*128*256*4);
  ushort*   hxh   = (ushort*)  take((size_t)Nn*512*2);
  float*    iou   = (float*)   take((size_t)Nn*GG3*4);
  float*    um    = (float*)   take((size_t)Nn*GG3*4);
  float*    fm    = (float*)   take((size_t)Nn*HID*4);
  ushort*   UTbf  = (ushort*)  take((size_t)1024*256*2);   // bf16 row-major
  int*      tnlist= (int*)     take((size_t)64*128*4);
  int*      tlvloff=(int*)     take((size_t)64*130*4);
  int*      tnlv  = (int*)     take((size_t)64*4);
  int*      choff = (int*)     take((size_t)(Nn+1)*4);
  int*      chlist= (int*)     take((size_t)(E>0?E:1)*4);
  (void)ws_size; (void)n_in; (void)out_size;

  hipMemsetAsync(d_ws, 0, zero_end, stream);
  prep_kernel<<<1024, 256, 0, stream>>>(embed_ids, emb, xh, wihf, wtihf, wihb, wtihb,
                                        Wiou, wiouh, whhf, whhb, wtf, wtb, Uiou, Uf, UTbf);
  mfma_gemm_kernel<true><<<dim3(64, 8), 256, 0, stream>>>(xh, wtihf, bf, xgf, 8192, 1024, 10);
  mfma_gemm_kernel<true><<<dim3(64, 8), 256, 0, stream>>>(xh, wtihb, bb, xgb, 8192, 1024, 10);
  lstm_kernel<<<64, 1024, 0, stream>>>(xgf, xgb, wtf, wtb, lengths, hsf, hsb);
  gather_hx_kernel<<<(Nn*64 + 255)/256, 256, 0, stream>>>(tok_idx, hsf, hsb, hxh, Nn);
  mfma_gemm_kernel<false><<<dim3((Nn + 127)/128, 6), 256, 0, stream>>>(hxh, wiouh, nullptr, iou, Nn, GG3, 16);
  csr_kernel<<<1, 1024, 0, stream>>>(child_idx, parent_idx, choff, chlist, deg, E, Nn);
  tree_sort_kernel<<<64, 128, 0, stream>>>(lengths, node_level, tnlist, tlvloff, tnlv);
  tree_kernel<<<64, 512, 0, stream>>>(tnlist, tlvloff, tnlv, choff, chlist, UTbf,
                                      biou, buf_, iou, um, fm, hout);
}

// Round 17
// 923.383 us; speedup vs baseline: 4.4916x; 1.0946x over previous
//
#include <hip/hip_runtime.h>
#include <hip/hip_fp16.h>
#include <cstdint>
#include <cstddef>

#define TT 128
#define HID 256
#define GG4 1024
#define GG3 768

typedef _Float16 f16x2 __attribute__((ext_vector_type(2)));
typedef _Float16 f16x8 __attribute__((ext_vector_type(8)));
typedef short    bf16x8 __attribute__((ext_vector_type(8)));
typedef float    f32x4 __attribute__((ext_vector_type(4)));

union f16x8u { f16x8 v; f16x2 p[4]; };

__device__ __forceinline__ float sigf(float x){ return 1.f/(1.f+__expf(-x)); }
__device__ __forceinline__ float tanh_(float x){
  float cx = fminf(fmaxf(x,-15.f),15.f);
  float e = __expf(2.f*cx);
  return (e-1.f)/(e+1.f);
}

__device__ __forceinline__ float dot2(f16x2 a, f16x2 b, float c){
#if __has_builtin(__builtin_amdgcn_fdot2)
  return __builtin_amdgcn_fdot2(a, b, c, false);
#else
  return c + (float)a[0]*(float)b[0] + (float)a[1]*(float)b[1];
#endif
}

__device__ __forceinline__ ushort f2bf(float x){
  union { float f; uint32_t u; } v; v.f = x;
  uint32_t r = v.u + 0x7FFF + ((v.u >> 16) & 1);
  return (ushort)(r >> 16);
}

// ---------------- fused elementwise prep (6 segments, grid-stride) ----------
__global__ __launch_bounds__(256) void prep_kernel(
    const int* __restrict__ ids, const float* __restrict__ emb, ushort* __restrict__ xh,
    const float* __restrict__ wihf, ushort* __restrict__ wtihf,
    const float* __restrict__ wihb, ushort* __restrict__ wtihb,
    const float* __restrict__ Wiou, ushort* __restrict__ wiouh,
    const float* __restrict__ whhf, const float* __restrict__ whhb,
    _Float16* __restrict__ wtf, _Float16* __restrict__ wtb,
    const float* __restrict__ Uiou, const float* __restrict__ Uf,
    ushort* __restrict__ UTbf)
{
  for (int it = blockIdx.x*256 + threadIdx.x; it < 557056; it += gridDim.x*256) {
    if (it < 327680) {
      int m = it / 40, q = it - m*40;
      int k0 = q << 3;
      int id = ids[m];
      ushort o[8];
#pragma unroll
      for (int j = 0; j < 8; j++) {
        int k = k0 + j;
        o[j] = (k < 300) ? f2bf(emb[(size_t)id*300 + k]) : (ushort)0;
      }
      *(uint4*)&xh[(size_t)m*320 + k0] = *(uint4*)o;
    } else if (it < 409600) {
      int i2 = it - 327680;
      const float* src = wihf; ushort* dst = wtihf;
      if (i2 >= 40960) { i2 -= 40960; src = wihb; dst = wtihb; }
      int r = i2 / 40, q = i2 - r*40;
      int k0 = q << 3;
      ushort o[8];
#pragma unroll
      for (int j = 0; j < 8; j++) {
        int k = k0 + j;
        o[j] = (k < 300) ? f2bf(src[(size_t)r*300 + k]) : (ushort)0;
      }
      *(uint4*)&dst[(size_t)r*320 + k0] = *(uint4*)o;
    } else if (it < 458752) {
      int i2 = it - 409600;
      int r = i2 >> 6, k0 = (i2 & 63) << 3;
      ushort o[8];
#pragma unroll
      for (int j = 0; j < 8; j++) o[j] = f2bf(Wiou[(size_t)r*512 + k0 + j]);
      *(uint4*)&wiouh[(size_t)r*512 + k0] = *(uint4*)o;
    } else if (it < 524288) {
      int i2 = it - 458752;
      int dir = i2 >> 15, rem = i2 & 32767;
      int k8 = rem >> 10, g = rem & 1023;
      const float* w = dir ? whhb : whhf;
      _Float16*   wt = dir ? wtb  : wtf;
      f16x8 pk;
#pragma unroll
      for (int j = 0; j < 8; j++) pk[j] = (_Float16)w[(size_t)g*HID + (k8<<3) + j];
      *(f16x8*)&wt[(((size_t)k8<<10) + g) << 3] = pk;
    } else {
      int i2 = it - 524288;
      int r = i2 >> 5, c = (i2 & 31) << 3;
      const float* src = (r < GG3) ? &Uiou[(size_t)r*HID + c] : &Uf[(size_t)(r-GG3)*HID + c];
      ushort o[8];
#pragma unroll
      for (int j = 0; j < 8; j++) o[j] = f2bf(src[j]);
      *(uint4*)&UTbf[(size_t)r*HID + c] = *(uint4*)o;
    }
  }
}

// ---------- MFMA bf16 GEMM, double-buffered: C = A·Bt^T (+bias) -------------
template<bool BIAS>
__global__ __launch_bounds__(256) void mfma_gemm_kernel(
    const ushort* __restrict__ A, const ushort* __restrict__ Bt,
    const float* __restrict__ bias, float* __restrict__ C,
    int M, int N, int ksteps)
{
  constexpr int LDS_ROW = 40;
  __shared__ ushort As[128*LDS_ROW];
  __shared__ ushort Bs[128*LDS_ROW];
  const int tid = threadIdx.x;
  const int m0 = blockIdx.x * 128, n0 = blockIdx.y * 128;
  const int wave = tid >> 6, lane = tid & 63;
  const int wm = (wave >> 1) * 64, wn = (wave & 1) * 64;
  const int fr = lane & 15;
  const int fk = (lane >> 4) << 3;
  const size_t Kp = (size_t)ksteps << 5;
  const int r0_ = tid >> 2,        k0_ = (tid & 3) << 3;
  const int r1_ = (tid + 256) >> 2, k1_ = ((tid + 256) & 3) << 3;
  f32x4 acc[4][4] = {};
  {
    uint4 av0 = make_uint4(0,0,0,0), av1 = make_uint4(0,0,0,0);
    if (m0 + r0_ < M) av0 = *(const uint4*)&A[(size_t)(m0+r0_)*Kp + k0_];
    if (m0 + r1_ < M) av1 = *(const uint4*)&A[(size_t)(m0+r1_)*Kp + k1_];
    const uint4 bv0 = *(const uint4*)&Bt[(size_t)(n0+r0_)*Kp + k0_];
    const uint4 bv1 = *(const uint4*)&Bt[(size_t)(n0+r1_)*Kp + k1_];
    *(uint4*)&As[r0_*LDS_ROW + k0_] = av0;
    *(uint4*)&As[r1_*LDS_ROW + k1_] = av1;
    *(uint4*)&Bs[r0_*LDS_ROW + k0_] = bv0;
    *(uint4*)&Bs[r1_*LDS_ROW + k1_] = bv1;
  }
  __syncthreads();
  for (int ks = 0; ks < ksteps; ks++) {
    uint4 nav0 = make_uint4(0,0,0,0), nav1 = make_uint4(0,0,0,0);
    uint4 nbv0 = make_uint4(0,0,0,0), nbv1 = make_uint4(0,0,0,0);
    const bool more = (ks + 1 < ksteps);
    if (more) {
      const int kb = (ks + 1) << 5;
      if (m0 + r0_ < M) nav0 = *(const uint4*)&A[(size_t)(m0+r0_)*Kp + kb + k0_];
      if (m0 + r1_ < M) nav1 = *(const uint4*)&A[(size_t)(m0+r1_)*Kp + kb + k1_];
      nbv0 = *(const uint4*)&Bt[(size_t)(n0+r0_)*Kp + kb + k0_];
      nbv1 = *(const uint4*)&Bt[(size_t)(n0+r1_)*Kp + kb + k1_];
    }
    bf16x8 af[4], bfr[4];
#pragma unroll
    for (int i = 0; i < 4; i++) {
      af[i]  = *(const bf16x8*)&As[(wm + i*16 + fr)*LDS_ROW + fk];
      bfr[i] = *(const bf16x8*)&Bs[(wn + i*16 + fr)*LDS_ROW + fk];
    }
#pragma unroll
    for (int mi = 0; mi < 4; mi++)
#pragma unroll
      for (int ni = 0; ni < 4; ni++)
        acc[mi][ni] = __builtin_amdgcn_mfma_f32_16x16x32_bf16(af[mi], bfr[ni], acc[mi][ni], 0, 0, 0);
    __syncthreads();
    if (more) {
      *(uint4*)&As[r0_*LDS_ROW + k0_] = nav0;
      *(uint4*)&As[r1_*LDS_ROW + k1_] = nav1;
      *(uint4*)&Bs[r0_*LDS_ROW + k0_] = nbv0;
      *(uint4*)&Bs[r1_*LDS_ROW + k1_] = nbv1;
      __syncthreads();
    }
  }
  const int drow = (lane >> 4) << 2, dcol = lane & 15;
#pragma unroll
  for (int mi = 0; mi < 4; mi++) {
#pragma unroll
    for (int ni = 0; ni < 4; ni++) {
      const int col = n0 + wn + ni*16 + dcol;
      const float bv = BIAS ? bias[col] : 0.f;
#pragma unroll
      for (int r = 0; r < 4; r++) {
        const int row = m0 + wm + mi*16 + drow + r;
        if (row < M) C[(size_t)row*N + col] = acc[mi][ni][r] + bv;
      }
    }
  }
}

// -------- LSTM: weights resident in VGPR(24 chunks) + LDS(8 chunks) ---------
// 64 blocks x 512 threads; dir=((blk&7)>>2); 2 batch rows/block; thread t owns
// gate rows t (i/f) and t+512 (g/o). Zero global weight traffic in step loop.
#define RCH 24            // chunks 0..23 in registers; 24..31 in LDS
__global__ __launch_bounds__(512, 2) void lstm_kernel(
    const float* __restrict__ xgf, const float* __restrict__ xgb,
    const _Float16* __restrict__ wtf, const _Float16* __restrict__ wtb,
    const int* __restrict__ lengths,
    float* __restrict__ hsf, float* __restrict__ hsb)
{
  const int b8  = blockIdx.x & 7;
  const int dir = b8 >> 2;
  const int p   = (blockIdx.x >> 3) * 4 + (b8 & 3);   // 0..31
  const int r0 = 2*p, r1 = r0 + 1;
  const float* __restrict__ xg = dir ? xgb : xgf;
  const _Float16* __restrict__ wt = dir ? wtb : wtf;
  float* __restrict__ hs = dir ? hsb : hsf;
  const int t = threadIdx.x;
  const int u = t & 255;

  extern __shared__ char smem[];
  f16x8*    wl  = (f16x8*)smem;                          // [8][2][512] = 131072 B
  _Float16* hb  = (_Float16*)(smem + 131072);            // [2][256]    = 1024 B
  float*    exf = (float*)(smem + 131072 + 1024);        // [2][256]    = 2048 B
  float*    exo = exf + 512;                             // [2][256]    = 2048 B

  // ---- preload weights: 24 chunks -> regs, 8 chunks -> LDS ----
  f16x8u wr0[RCH], wr1[RCH];
#pragma unroll
  for (int c = 0; c < RCH; c++) {
    wr0[c].v = *(const f16x8*)&wt[(((size_t)c << 10) + t) << 3];
    wr1[c].v = *(const f16x8*)&wt[(((size_t)c << 10) + t + 512) << 3];
  }
#pragma unroll
  for (int c = RCH; c < 32; c++) {
    wl[((c - RCH)*2 + 0)*512 + t] = *(const f16x8*)&wt[(((size_t)c << 10) + t) << 3];
    wl[((c - RCH)*2 + 1)*512 + t] = *(const f16x8*)&wt[(((size_t)c << 10) + t + 512) << 3];
  }
  if (t < 256) { hb[t] = (_Float16)0.f; hb[256 + t] = (_Float16)0.f; }
  __syncthreads();

  const int len0 = lengths[r0], len1 = lengths[r1];   // len0 >= len1
  float c0 = 0.f, c1 = 0.f;
  for (int s = 0; s < len0; s++) {
    const bool a1 = s < len1;
    const int t0 = dir ? (len0 - 1 - s) : s;
    const int t1 = dir ? (len1 - 1 - s) : s;
    const float* xr0 = xg + ((size_t)r0*TT + t0)*GG4;
    const float xa0 = xr0[t], xb0 = xr0[t + 512];
    float xa1 = 0.f, xb1 = 0.f;
    if (a1) {
      const float* xr1 = xg + ((size_t)r1*TT + t1)*GG4;
      xa1 = xr1[t]; xb1 = xr1[t + 512];
    }
    float aa0 = 0.f, aa1 = 0.f, ab0 = 0.f, ab1 = 0.f;
#pragma unroll
    for (int k8 = 0; k8 < 32; k8++) {
      f16x8u w0, w1, h0, h1;
      if (k8 < RCH) { w0 = wr0[k8]; w1 = wr1[k8]; }
      else {
        w0.v = wl[((k8 - RCH)*2 + 0)*512 + t];
        w1.v = wl[((k8 - RCH)*2 + 1)*512 + t];
      }
      h0.v = *(const f16x8*)&hb[k8 << 3];
      h1.v = *(const f16x8*)&hb[256 + (k8 << 3)];
#pragma unroll
      for (int j = 0; j < 4; j++) {
        aa0 = dot2(w0.p[j], h0.p[j], aa0);
        aa1 = dot2(w0.p[j], h1.p[j], aa1);
        ab0 = dot2(w1.p[j], h0.p[j], ab0);
        ab1 = dot2(w1.p[j], h1.p[j], ab1);
      }
    }
    if (t >= 256) {            // publish f,o pre-activations
      exf[u]       = aa0 + xa0;  exf[256 + u] = aa1 + xa1;
      exo[u]       = ab0 + xb0;  exo[256 + u] = ab1 + xb1;
    }
    __syncthreads();           // hb reads done + ex published
    if (t < 256) {
      {
        const float ig = sigf(aa0 + xa0);          // i (row t)
        const float gg = tanh_(ab0 + xb0);         // g (row t+512)
        const float fg = sigf(exf[u]);
        const float og = sigf(exo[u]);
        c0 = fg*c0 + ig*gg;
        const float h = og*tanh_(c0);
        hb[u] = (_Float16)h;
        hs[((size_t)r0*TT + t0)*HID + u] = h;
      }
      if (a1) {
        const float ig = sigf(aa1 + xa1);
        const float gg = tanh_(ab1 + xb1);
        const float fg = sigf(exf[256 + u]);
        const float og = sigf(exo[256 + u]);
        c1 = fg*c1 + ig*gg;
        const float h = og*tanh_(c1);
        hb[256 + u] = (_Float16)h;
        hs[((size_t)r1*TT + t1)*HID + u] = h;
      }
    }
    __syncthreads();           // new h visible
  }
}

// ---------------- hxh = bf16 concat(h_f[tok], h_b[tok]) ---------------------
__global__ __launch_bounds__(256) void gather_hx_kernel(
    const int* __restrict__ tok, const float* __restrict__ hsf,
    const float* __restrict__ hsb, ushort* __restrict__ hxh, int Nn)
{
  int it = blockIdx.x*256 + threadIdx.x;     // item = n*64 + q (512/8 chunks)
  if (it >= Nn*64) return;
  int n = it >> 6, q = it & 63;
  int k0 = q << 3;
  int tk = tok[n];
  int b = tk >> 7, t = tk & 127;
  const float* src = (k0 < 256) ? &hsf[((size_t)b*TT + t)*HID + k0]
                                : &hsb[((size_t)b*TT + t)*HID + (k0 - 256)];
  ushort o[8];
#pragma unroll
  for (int j = 0; j < 8; j++) o[j] = f2bf(src[j]);
  *(uint4*)&hxh[(size_t)n*512 + k0] = *(uint4*)o;
}

// ---------------- children CSR by parent ------------------------------------
__global__ __launch_bounds__(1024) void csr_kernel(
    const int* __restrict__ child_idx, const int* __restrict__ parent_idx,
    int* __restrict__ choff, int* __restrict__ chlist,
    int* __restrict__ deg /* zeroed; reused as cursor */, int E, int Nn)
{
  __shared__ int part[1024];
  const int tid = threadIdx.x;
  for (int e = tid; e < E; e += 1024) atomicAdd(&deg[parent_idx[e]], 1);
  __syncthreads();
  int loc[8]; int s = 0;
#pragma unroll
  for (int m = 0; m < 8; m++) {
    const int i = tid*8 + m;
    loc[m] = s;
    s += (i < Nn) ? deg[i] : 0;
  }
  part[tid] = s;
  __syncthreads();
  for (int off = 1; off < 1024; off <<= 1) {
    int v = (tid >= off) ? part[tid - off] : 0;
    __syncthreads();
    part[tid] += v;
    __syncthreads();
  }
  const int pre = (tid > 0) ? part[tid-1] : 0;
#pragma unroll
  for (int m = 0; m < 8; m++) {
    const int i = tid*8 + m;
    if (i < Nn) choff[i] = pre + loc[m];
  }
  if (tid == 1023) choff[Nn] = part[1023];
  __syncthreads();
#pragma unroll
  for (int m = 0; m < 8; m++) {
    const int i = tid*8 + m;
    if (i < Nn) deg[i] = pre + loc[m];
  }
  __syncthreads();
  for (int e = tid; e < E; e += 1024) {
    int pos = atomicAdd(&deg[parent_idx[e]], 1);
    chlist[pos] = child_idx[e];
  }
}

// ---------------- per-tree level sort ---------------------------------------
__global__ __launch_bounds__(128) void tree_sort_kernel(
    const int* __restrict__ lengths, const int* __restrict__ node_level,
    int* __restrict__ tnlist, int* __restrict__ tlvloff, int* __restrict__ tnlv)
{
  const int b = blockIdx.x, tid = threadIdx.x;
  __shared__ int hist[130], cur[129];
  __shared__ int off_s, len_s, mx;
  if (tid == 0) {
    int o = 0;
    for (int i = 0; i < b; i++) o += lengths[i];
    off_s = o; len_s = lengths[b]; mx = 1;
  }
  for (int i = tid; i < 130; i += 128) hist[i] = 0;
  __syncthreads();
  const int off = off_s, len = len_s;
  for (int i = tid; i < len; i += 128) {
    int lv = node_level[off + i];
    atomicAdd(&hist[lv], 1);
    atomicMax(&mx, lv + 1);
  }
  __syncthreads();
  if (tid == 0) {
    int s = 0;
    for (int l = 0; l < 129; l++) { cur[l] = s; tlvloff[b*130 + l] = s; s += hist[l]; }
    tlvloff[b*130 + 129] = s;
    tnlv[b] = mx;
  }
  __syncthreads();
  for (int i = tid; i < len; i += 128) {
    int lv = node_level[off + i];
    int pos = atomicAdd(&cur[lv], 1);
    tnlist[b*128 + pos] = off + i;
  }
}

// ------- tree: one block/tree; phase A register-resident; MFMA phase B ------
__global__ __launch_bounds__(512) void tree_kernel(
    const int* __restrict__ tnlist, const int* __restrict__ tlvloff,
    const int* __restrict__ tnlv,
    const int* __restrict__ choff, const int* __restrict__ chlist,
    const ushort* __restrict__ UTbf,
    const float* __restrict__ biou, const float* __restrict__ buf_,
    const float* __restrict__ iou,
    float* __restrict__ um, float* __restrict__ fm,
    float* __restrict__ hout)
{
  const int b = blockIdx.x;
  const int tid = threadIdx.x;
  const int nlv = tnlv[b];
  const int* __restrict__ nl = tnlist + b*128;
  const int* __restrict__ lo = tlvloff + b*130;
  __shared__ ushort hl[16][264];
  __shared__ float  cl[16][260];
  __shared__ int    nid[16];
  const int j5 = tid >> 5, lane5 = tid & 31;
  const int wave = tid >> 6, lane = tid & 63;
  const int fr16 = lane & 15, khalf = lane >> 4;
  for (int l = 0; l < nlv; l++) {
    const int na = lo[l], ne = lo[l+1];
    for (int g0 = na; g0 < ne; g0 += 16) {
      __syncthreads();
      const int n = (g0 + j5 < ne) ? nl[g0 + j5] : -1;
      if (lane5 == 0) nid[j5] = n;
      if (n >= 0) {
        f32x4 a[8];
#pragma unroll
        for (int q = 0; q < 8; q++) {
          const int d = (q*32 + lane5) << 2;
          if (d < GG3) a[q] = *(const f32x4*)&iou[(size_t)n*GG3 + d];
          else         a[q] = (f32x4){0.f, 0.f, 0.f, 0.f};
        }
        const int e0 = choff[n], e1 = choff[n+1];
        for (int eb = e0; eb < e1; eb += 4) {
          int ch4[4];
#pragma unroll
          for (int i = 0; i < 4; i++) ch4[i] = (eb + i < e1) ? chlist[eb + i] : -1;
#pragma unroll
          for (int i = 0; i < 4; i++) {
            const int ch = ch4[i];
            if (ch >= 0) {
#pragma unroll
              for (int q = 0; q < 8; q++) {
                const int d = (q*32 + lane5) << 2;
                const f32x4 v = (d < GG3)
                  ? *(const f32x4*)&um[(size_t)ch*GG3 + d]
                  : *(const f32x4*)&fm[(size_t)ch*HID + (d - GG3)];
                a[q] += v;
              }
            }
          }
        }
#pragma unroll
        for (int qq = 0; qq < 2; qq++) {
#pragma unroll
          for (int i = 0; i < 4; i++) {
            const int u = qq*128 + (lane5 << 2) + i;
            const float i_ = a[qq][i]   + biou[u];
            const float o_ = a[qq+2][i] + biou[256 + u];
            const float uu = a[qq+4][i] + biou[512 + u];
            const float cv = sigf(i_)*tanh_(uu) + a[qq+6][i];
            const float hv = sigf(o_)*tanh_(cv);
            cl[j5][u] = cv;
            hl[j5][u] = f2bf(hv);
            hout[(size_t)n*HID + u] = hv;
          }
        }
      } else {
#pragma unroll
        for (int q = 0; q < 8; q++) hl[j5][(q << 5) + lane5] = 0;
      }
      __syncthreads();
      if (l == nlv - 1) continue;
      bf16x8 af[8];
#pragma unroll
      for (int ks = 0; ks < 8; ks++)
        af[ks] = *(const bf16x8*)&hl[fr16][ks*32 + (khalf << 3)];
      for (int nt = wave; nt < 64; nt += 8) {
        f32x4 dacc = {0.f, 0.f, 0.f, 0.f};
#pragma unroll
        for (int ks = 0; ks < 8; ks++) {
          const bf16x8 bfr = *(const bf16x8*)&UTbf[(size_t)(nt*16 + fr16)*HID + ks*32 + (khalf << 3)];
          dacc = __builtin_amdgcn_mfma_f32_16x16x32_bf16(af[ks], bfr, dacc, 0, 0, 0);
        }
        const int r = nt*16 + fr16;
        if (r < GG3) {
#pragma unroll
          for (int g = 0; g < 4; g++) {
            const int n2 = nid[(khalf << 2) + g];
            if (n2 >= 0) um[(size_t)n2*GG3 + r] = dacc[g];
          }
        } else {
          const int fr = r - GG3;
          const float bv = buf_[fr];
#pragma unroll
          for (int g = 0; g < 4; g++) {
            const int jj = (khalf << 2) + g;
            const int n2 = nid[jj];
            if (n2 >= 0) fm[(size_t)n2*HID + fr] = sigf(dacc[g] + bv) * cl[jj][fr];
          }
        }
      }
    }
  }
}

// ---------------- launch ------------------------------------------------------
extern "C" void kernel_launch(void* const* d_in, const int* in_sizes, int n_in,
                              void* d_out, int out_size, void* d_ws, size_t ws_size,
                              hipStream_t stream)
{
  const int*   embed_ids = (const int*)d_in[0];
  const int*   lengths   = (const int*)d_in[1];
  const int*   child_idx = (const int*)d_in[2];
  const int*   parent_idx= (const int*)d_in[3];
  const int*   tok_idx   = (const int*)d_in[4];
  const int*   node_level= (const int*)d_in[5];
  const float* emb  = (const float*)d_in[7];
  const float* wihf = (const float*)d_in[8];
  const float* whhf = (const float*)d_in[9];
  const float* bf   = (const float*)d_in[10];
  const float* wihb = (const float*)d_in[11];
  const float* whhb = (const float*)d_in[12];
  const float* bb   = (const float*)d_in[13];
  const float* Wiou = (const float*)d_in[14];
  const float* Uiou = (const float*)d_in[15];
  const float* biou = (const float*)d_in[16];
  const float* Uf   = (const float*)d_in[17];
  const float* buf_ = (const float*)d_in[18];
  const int E  = in_sizes[2];
  const int Nn = in_sizes[4];
  float* hout = (float*)d_out;

  char* w = (char*)d_ws;
  size_t off = 0;
  auto take = [&](size_t bytes) -> char* {
    char* p = w + off;
    off += (bytes + 255) & ~(size_t)255;
    return p;
  };
  int*      deg   = (int*)     take((size_t)(Nn+1)*4);     // zeroed: CSR degree/cursor
  size_t zero_end = off;
  ushort*   xh    = (ushort*)  take((size_t)8192*320*2);   // bf16, K padded
  ushort*   wtihf = (ushort*)  take((size_t)1024*320*2);
  ushort*   wtihb = (ushort*)  take((size_t)1024*320*2);
  ushort*   wiouh = (ushort*)  take((size_t)768*512*2);
  float*    xgf   = (float*)   take((size_t)8192*1024*4);
  float*    xgb   = (float*)   take((size_t)8192*1024*4);
  _Float16* wtf   = (_Float16*)take((size_t)32*1024*8*2);  // f16 [k8][g][8]
  _Float16* wtb   = (_Float16*)take((size_t)32*1024*8*2);
  float*    hsf   = (float*)   take((size_t)64*128*256*4);
  float*    hsb   = (float*)   take((size_t)64*128*256*4);
  ushort*   hxh   = (ushort*)  take((size_t)Nn*512*2);
  float*    iou   = (float*)   take((size_t)Nn*GG3*4);
  float*    um    = (float*)   take((size_t)Nn*GG3*4);
  float*    fm    = (float*)   take((size_t)Nn*HID*4);
  ushort*   UTbf  = (ushort*)  take((size_t)1024*256*2);   // bf16 row-major
  int*      tnlist= (int*)     take((size_t)64*128*4);
  int*      tlvloff=(int*)     take((size_t)64*130*4);
  int*      tnlv  = (int*)     take((size_t)64*4);
  int*      choff = (int*)     take((size_t)(Nn+1)*4);
  int*      chlist= (int*)     take((size_t)(E>0?E:1)*4);
  (void)ws_size; (void)n_in; (void)out_size;

  hipMemsetAsync(d_ws, 0, zero_end, stream);
  prep_kernel<<<1024, 256, 0, stream>>>(embed_ids, emb, xh, wihf, wtihf, wihb, wtihb,
                                        Wiou, wiouh, whhf, whhb, wtf, wtb, Uiou, Uf, UTbf);
  mfma_gemm_kernel<true><<<dim3(64, 8), 256, 0, stream>>>(xh, wtihf, bf, xgf, 8192, 1024, 10);
  mfma_gemm_kernel<true><<<dim3(64, 8), 256, 0, stream>>>(xh, wtihb, bb, xgb, 8192, 1024, 10);
  lstm_kernel<<<64, 512, 136192, stream>>>(xgf, xgb, wtf, wtb, lengths, hsf, hsb);
  gather_hx_kernel<<<(Nn*64 + 255)/256, 256, 0, stream>>>(tok_idx, hsf, hsb, hxh, Nn);
  mfma_gemm_kernel<false><<<dim3((Nn + 127)/128, 6), 256, 0, stream>>>(hxh, wiouh, nullptr, iou, Nn, GG3, 16);
  csr_kernel<<<1, 1024, 0, stream>>>(child_idx, parent_idx, choff, chlist, deg, E, Nn);
  tree_sort_kernel<<<64, 128, 0, stream>>>(lengths, node_level, tnlist, tlvloff, tnlv);
  tree_kernel<<<64, 512, 0, stream>>>(tnlist, tlvloff, tnlv, choff, chlist, UTbf,
                                      biou, buf_, iou, um, fm, hout);
}

// Round 18
// 908.099 us; speedup vs baseline: 4.5672x; 1.0168x over previous
//
#include <hip/hip_runtime.h>
#include <hip/hip_fp16.h>
#include <cstdint>
#include <cstddef>

#define TT 128
#define HID 256
#define GG4 1024
#define GG3 768

typedef _Float16 f16x2 __attribute__((ext_vector_type(2)));
typedef _Float16 f16x8 __attribute__((ext_vector_type(8)));
typedef short    bf16x8 __attribute__((ext_vector_type(8)));
typedef float    f32x4 __attribute__((ext_vector_type(4)));

union f16x8u { f16x8 v; f16x2 p[4]; uint4 q; };

__device__ __forceinline__ float sigf(float x){ return 1.f/(1.f+__expf(-x)); }
__device__ __forceinline__ float tanh_(float x){
  float cx = fminf(fmaxf(x,-15.f),15.f);
  float e = __expf(2.f*cx);
  return (e-1.f)/(e+1.f);
}

__device__ __forceinline__ float dot2(f16x2 a, f16x2 b, float c){
#if __has_builtin(__builtin_amdgcn_fdot2)
  return __builtin_amdgcn_fdot2(a, b, c, false);
#else
  return c + (float)a[0]*(float)b[0] + (float)a[1]*(float)b[1];
#endif
}

__device__ __forceinline__ ushort f2bf(float x){
  union { float f; uint32_t u; } v; v.f = x;
  uint32_t r = v.u + 0x7FFF + ((v.u >> 16) & 1);
  return (ushort)(r >> 16);
}

// ---------------- fused elementwise prep (6 segments, grid-stride) ----------
__global__ __launch_bounds__(256) void prep_kernel(
    const int* __restrict__ ids, const float* __restrict__ emb, ushort* __restrict__ xh,
    const float* __restrict__ wihf, ushort* __restrict__ wtihf,
    const float* __restrict__ wihb, ushort* __restrict__ wtihb,
    const float* __restrict__ Wiou, ushort* __restrict__ wiouh,
    const float* __restrict__ whhf, const float* __restrict__ whhb,
    _Float16* __restrict__ wtf, _Float16* __restrict__ wtb,
    const float* __restrict__ Uiou, const float* __restrict__ Uf,
    ushort* __restrict__ UTbf)
{
  for (int it = blockIdx.x*256 + threadIdx.x; it < 557056; it += gridDim.x*256) {
    if (it < 327680) {
      int m = it / 40, q = it - m*40;
      int k0 = q << 3;
      int id = ids[m];
      ushort o[8];
#pragma unroll
      for (int j = 0; j < 8; j++) {
        int k = k0 + j;
        o[j] = (k < 300) ? f2bf(emb[(size_t)id*300 + k]) : (ushort)0;
      }
      *(uint4*)&xh[(size_t)m*320 + k0] = *(uint4*)o;
    } else if (it < 409600) {
      int i2 = it - 327680;
      const float* src = wihf; ushort* dst = wtihf;
      if (i2 >= 40960) { i2 -= 40960; src = wihb; dst = wtihb; }
      int r = i2 / 40, q = i2 - r*40;
      int k0 = q << 3;
      ushort o[8];
#pragma unroll
      for (int j = 0; j < 8; j++) {
        int k = k0 + j;
        o[j] = (k < 300) ? f2bf(src[(size_t)r*300 + k]) : (ushort)0;
      }
      *(uint4*)&dst[(size_t)r*320 + k0] = *(uint4*)o;
    } else if (it < 458752) {
      int i2 = it - 409600;
      int r = i2 >> 6, k0 = (i2 & 63) << 3;
      ushort o[8];
#pragma unroll
      for (int j = 0; j < 8; j++) o[j] = f2bf(Wiou[(size_t)r*512 + k0 + j]);
      *(uint4*)&wiouh[(size_t)r*512 + k0] = *(uint4*)o;
    } else if (it < 524288) {
      int i2 = it - 458752;
      int dir = i2 >> 15, rem = i2 & 32767;
      int k8 = rem >> 10, g = rem & 1023;
      const float* w = dir ? whhb : whhf;
      _Float16*   wt = dir ? wtb  : wtf;
      f16x8 pk;
#pragma unroll
      for (int j = 0; j < 8; j++) pk[j] = (_Float16)w[(size_t)g*HID + (k8<<3) + j];
      *(f16x8*)&wt[(((size_t)k8<<10) + g) << 3] = pk;
    } else {
      int i2 = it - 524288;
      int r = i2 >> 5, c = (i2 & 31) << 3;
      const float* src = (r < GG3) ? &Uiou[(size_t)r*HID + c] : &Uf[(size_t)(r-GG3)*HID + c];
      ushort o[8];
#pragma unroll
      for (int j = 0; j < 8; j++) o[j] = f2bf(src[j]);
      *(uint4*)&UTbf[(size_t)r*HID + c] = *(uint4*)o;
    }
  }
}

// ---------- MFMA bf16 GEMM, double-buffered: C = A·Bt^T (+bias) -------------
template<bool BIAS>
__global__ __launch_bounds__(256) void mfma_gemm_kernel(
    const ushort* __restrict__ A, const ushort* __restrict__ Bt,
    const float* __restrict__ bias, float* __restrict__ C,
    int M, int N, int ksteps)
{
  constexpr int LDS_ROW = 40;
  __shared__ ushort As[128*LDS_ROW];
  __shared__ ushort Bs[128*LDS_ROW];
  const int tid = threadIdx.x;
  const int m0 = blockIdx.x * 128, n0 = blockIdx.y * 128;
  const int wave = tid >> 6, lane = tid & 63;
  const int wm = (wave >> 1) * 64, wn = (wave & 1) * 64;
  const int fr = lane & 15;
  const int fk = (lane >> 4) << 3;
  const size_t Kp = (size_t)ksteps << 5;
  const int r0_ = tid >> 2,        k0_ = (tid & 3) << 3;
  const int r1_ = (tid + 256) >> 2, k1_ = ((tid + 256) & 3) << 3;
  f32x4 acc[4][4] = {};
  {
    uint4 av0 = make_uint4(0,0,0,0), av1 = make_uint4(0,0,0,0);
    if (m0 + r0_ < M) av0 = *(const uint4*)&A[(size_t)(m0+r0_)*Kp + k0_];
    if (m0 + r1_ < M) av1 = *(const uint4*)&A[(size_t)(m0+r1_)*Kp + k1_];
    const uint4 bv0 = *(const uint4*)&Bt[(size_t)(n0+r0_)*Kp + k0_];
    const uint4 bv1 = *(const uint4*)&Bt[(size_t)(n0+r1_)*Kp + k1_];
    *(uint4*)&As[r0_*LDS_ROW + k0_] = av0;
    *(uint4*)&As[r1_*LDS_ROW + k1_] = av1;
    *(uint4*)&Bs[r0_*LDS_ROW + k0_] = bv0;
    *(uint4*)&Bs[r1_*LDS_ROW + k1_] = bv1;
  }
  __syncthreads();
  for (int ks = 0; ks < ksteps; ks++) {
    uint4 nav0 = make_uint4(0,0,0,0), nav1 = make_uint4(0,0,0,0);
    uint4 nbv0 = make_uint4(0,0,0,0), nbv1 = make_uint4(0,0,0,0);
    const bool more = (ks + 1 < ksteps);
    if (more) {
      const int kb = (ks + 1) << 5;
      if (m0 + r0_ < M) nav0 = *(const uint4*)&A[(size_t)(m0+r0_)*Kp + kb + k0_];
      if (m0 + r1_ < M) nav1 = *(const uint4*)&A[(size_t)(m0+r1_)*Kp + kb + k1_];
      nbv0 = *(const uint4*)&Bt[(size_t)(n0+r0_)*Kp + kb + k0_];
      nbv1 = *(const uint4*)&Bt[(size_t)(n0+r1_)*Kp + kb + k1_];
    }
    bf16x8 af[4], bfr[4];
#pragma unroll
    for (int i = 0; i < 4; i++) {
      af[i]  = *(const bf16x8*)&As[(wm + i*16 + fr)*LDS_ROW + fk];
      bfr[i] = *(const bf16x8*)&Bs[(wn + i*16 + fr)*LDS_ROW + fk];
    }
#pragma unroll
    for (int mi = 0; mi < 4; mi++)
#pragma unroll
      for (int ni = 0; ni < 4; ni++)
        acc[mi][ni] = __builtin_amdgcn_mfma_f32_16x16x32_bf16(af[mi], bfr[ni], acc[mi][ni], 0, 0, 0);
    __syncthreads();
    if (more) {
      *(uint4*)&As[r0_*LDS_ROW + k0_] = nav0;
      *(uint4*)&As[r1_*LDS_ROW + k1_] = nav1;
      *(uint4*)&Bs[r0_*LDS_ROW + k0_] = nbv0;
      *(uint4*)&Bs[r1_*LDS_ROW + k1_] = nbv1;
      __syncthreads();
    }
  }
  const int drow = (lane >> 4) << 2, dcol = lane & 15;
#pragma unroll
  for (int mi = 0; mi < 4; mi++) {
#pragma unroll
    for (int ni = 0; ni < 4; ni++) {
      const int col = n0 + wn + ni*16 + dcol;
      const float bv = BIAS ? bias[col] : 0.f;
#pragma unroll
      for (int r = 0; r < 4; r++) {
        const int row = m0 + wm + mi*16 + drow + r;
        if (row < M) C[(size_t)row*N + col] = acc[mi][ni][r] + bv;
      }
    }
  }
}

// -------- LSTM: weights PINNED in VGPR (23 chunks) + LDS (9 chunks) ---------
// 64 blocks x 512 threads; dir=((blk&7)>>2); 2 batch rows/block; thread t owns
// gate rows t (i/f) and t+512 (g/o). asm "+v" pin prevents rematerialization.
#define RCH 23            // chunks 0..22 in registers; 23..31 in LDS
__global__ __launch_bounds__(512, 2) void lstm_kernel(
    const float* __restrict__ xgf, const float* __restrict__ xgb,
    const _Float16* __restrict__ wtf, const _Float16* __restrict__ wtb,
    const int* __restrict__ lengths,
    float* __restrict__ hsf, float* __restrict__ hsb)
{
  const int b8  = blockIdx.x & 7;
  const int dir = b8 >> 2;
  const int p   = (blockIdx.x >> 3) * 4 + (b8 & 3);   // 0..31
  const int r0 = 2*p, r1 = r0 + 1;
  const float* __restrict__ xg = dir ? xgb : xgf;
  const _Float16* __restrict__ wt = dir ? wtb : wtf;
  float* __restrict__ hs = dir ? hsb : hsf;
  const int t = threadIdx.x;
  const int u = t & 255;

  extern __shared__ char smem[];
  f16x8*    wl  = (f16x8*)smem;                          // [9][2][512] = 147456 B
  _Float16* hb  = (_Float16*)(smem + 147456);            // [2][256]    = 1024 B
  float*    exf = (float*)(smem + 147456 + 1024);        // [2][256]    = 2048 B
  float*    exo = exf + 512;                             // [2][256]    = 2048 B

  // ---- preload weights: 23 chunks -> pinned regs, 9 chunks -> LDS ----
  uint4 wr0[RCH], wr1[RCH];
#pragma unroll
  for (int c = 0; c < RCH; c++) {
    wr0[c] = *(const uint4*)&wt[(((size_t)c << 10) + t) << 3];
    wr1[c] = *(const uint4*)&wt[(((size_t)c << 10) + t + 512) << 3];
  }
#pragma unroll
  for (int c = 0; c < RCH; c++) {
    asm volatile("" : "+v"(wr0[c].x), "+v"(wr0[c].y), "+v"(wr0[c].z), "+v"(wr0[c].w));
    asm volatile("" : "+v"(wr1[c].x), "+v"(wr1[c].y), "+v"(wr1[c].z), "+v"(wr1[c].w));
  }
#pragma unroll
  for (int c = RCH; c < 32; c++) {
    wl[((c - RCH)*2 + 0)*512 + t] = *(const f16x8*)&wt[(((size_t)c << 10) + t) << 3];
    wl[((c - RCH)*2 + 1)*512 + t] = *(const f16x8*)&wt[(((size_t)c << 10) + t + 512) << 3];
  }
  if (t < 256) { hb[t] = (_Float16)0.f; hb[256 + t] = (_Float16)0.f; }
  __syncthreads();

  const int len0 = lengths[r0], len1 = lengths[r1];   // len0 >= len1
  float c0 = 0.f, c1 = 0.f;
  for (int s = 0; s < len0; s++) {
    const bool a1 = s < len1;
    const int t0 = dir ? (len0 - 1 - s) : s;
    const int t1 = dir ? (len1 - 1 - s) : s;
    const float* xr0 = xg + ((size_t)r0*TT + t0)*GG4;
    const float xa0 = xr0[t], xb0 = xr0[t + 512];
    float xa1 = 0.f, xb1 = 0.f;
    if (a1) {
      const float* xr1 = xg + ((size_t)r1*TT + t1)*GG4;
      xa1 = xr1[t]; xb1 = xr1[t + 512];
    }
    float aa0 = 0.f, aa1 = 0.f, ab0 = 0.f, ab1 = 0.f;
#pragma unroll
    for (int k8 = 0; k8 < 32; k8++) {
      f16x8u w0, w1, h0, h1;
      if (k8 < RCH) { w0.q = wr0[k8]; w1.q = wr1[k8]; }
      else {
        w0.v = wl[((k8 - RCH)*2 + 0)*512 + t];
        w1.v = wl[((k8 - RCH)*2 + 1)*512 + t];
      }
      h0.v = *(const f16x8*)&hb[k8 << 3];
      h1.v = *(const f16x8*)&hb[256 + (k8 << 3)];
#pragma unroll
      for (int j = 0; j < 4; j++) {
        aa0 = dot2(w0.p[j], h0.p[j], aa0);
        aa1 = dot2(w0.p[j], h1.p[j], aa1);
        ab0 = dot2(w1.p[j], h0.p[j], ab0);
        ab1 = dot2(w1.p[j], h1.p[j], ab1);
      }
    }
    if (t >= 256) {            // publish f,o pre-activations
      exf[u]       = aa0 + xa0;  exf[256 + u] = aa1 + xa1;
      exo[u]       = ab0 + xb0;  exo[256 + u] = ab1 + xb1;
    }
    __syncthreads();           // hb reads done + ex published
    if (t < 256) {
      {
        const float ig = sigf(aa0 + xa0);          // i (row t)
        const float gg = tanh_(ab0 + xb0);         // g (row t+512)
        const float fg = sigf(exf[u]);
        const float og = sigf(exo[u]);
        c0 = fg*c0 + ig*gg;
        const float h = og*tanh_(c0);
        hb[u] = (_Float16)h;
        hs[((size_t)r0*TT + t0)*HID + u] = h;
      }
      if (a1) {
        const float ig = sigf(aa1 + xa1);
        const float gg = tanh_(ab1 + xb1);
        const float fg = sigf(exf[256 + u]);
        const float og = sigf(exo[256 + u]);
        c1 = fg*c1 + ig*gg;
        const float h = og*tanh_(c1);
        hb[256 + u] = (_Float16)h;
        hs[((size_t)r1*TT + t1)*HID + u] = h;
      }
    }
    __syncthreads();           // new h visible
  }
}

// ---------------- hxh = bf16 concat(h_f[tok], h_b[tok]) ---------------------
__global__ __launch_bounds__(256) void gather_hx_kernel(
    const int* __restrict__ tok, const float* __restrict__ hsf,
    const float* __restrict__ hsb, ushort* __restrict__ hxh, int Nn)
{
  int it = blockIdx.x*256 + threadIdx.x;     // item = n*64 + q (512/8 chunks)
  if (it >= Nn*64) return;
  int n = it >> 6, q = it & 63;
  int k0 = q << 3;
  int tk = tok[n];
  int b = tk >> 7, t = tk & 127;
  const float* src = (k0 < 256) ? &hsf[((size_t)b*TT + t)*HID + k0]
                                : &hsb[((size_t)b*TT + t)*HID + (k0 - 256)];
  ushort o[8];
#pragma unroll
  for (int j = 0; j < 8; j++) o[j] = f2bf(src[j]);
  *(uint4*)&hxh[(size_t)n*512 + k0] = *(uint4*)o;
}

// ---------------- children CSR by parent ------------------------------------
__global__ __launch_bounds__(1024) void csr_kernel(
    const int* __restrict__ child_idx, const int* __restrict__ parent_idx,
    int* __restrict__ choff, int* __restrict__ chlist,
    int* __restrict__ deg /* zeroed; reused as cursor */, int E, int Nn)
{
  __shared__ int part[1024];
  const int tid = threadIdx.x;
  for (int e = tid; e < E; e += 1024) atomicAdd(&deg[parent_idx[e]], 1);
  __syncthreads();
  int loc[8]; int s = 0;
#pragma unroll
  for (int m = 0; m < 8; m++) {
    const int i = tid*8 + m;
    loc[m] = s;
    s += (i < Nn) ? deg[i] : 0;
  }
  part[tid] = s;
  __syncthreads();
  for (int off = 1; off < 1024; off <<= 1) {
    int v = (tid >= off) ? part[tid - off] : 0;
    __syncthreads();
    part[tid] += v;
    __syncthreads();
  }
  const int pre = (tid > 0) ? part[tid-1] : 0;
#pragma unroll
  for (int m = 0; m < 8; m++) {
    const int i = tid*8 + m;
    if (i < Nn) choff[i] = pre + loc[m];
  }
  if (tid == 1023) choff[Nn] = part[1023];
  __syncthreads();
#pragma unroll
  for (int m = 0; m < 8; m++) {
    const int i = tid*8 + m;
    if (i < Nn) deg[i] = pre + loc[m];
  }
  __syncthreads();
  for (int e = tid; e < E; e += 1024) {
    int pos = atomicAdd(&deg[parent_idx[e]], 1);
    chlist[pos] = child_idx[e];
  }
}

// ---------------- per-tree level sort ---------------------------------------
__global__ __launch_bounds__(128) void tree_sort_kernel(
    const int* __restrict__ lengths, const int* __restrict__ node_level,
    int* __restrict__ tnlist, int* __restrict__ tlvloff, int* __restrict__ tnlv)
{
  const int b = blockIdx.x, tid = threadIdx.x;
  __shared__ int hist[130], cur[129];
  __shared__ int off_s, len_s, mx;
  if (tid == 0) {
    int o = 0;
    for (int i = 0; i < b; i++) o += lengths[i];
    off_s = o; len_s = lengths[b]; mx = 1;
  }
  for (int i = tid; i < 130; i += 128) hist[i] = 0;
  __syncthreads();
  const int off = off_s, len = len_s;
  for (int i = tid; i < len; i += 128) {
    int lv = node_level[off + i];
    atomicAdd(&hist[lv], 1);
    atomicMax(&mx, lv + 1);
  }
  __syncthreads();
  if (tid == 0) {
    int s = 0;
    for (int l = 0; l < 129; l++) { cur[l] = s; tlvloff[b*130 + l] = s; s += hist[l]; }
    tlvloff[b*130 + 129] = s;
    tnlv[b] = mx;
  }
  __syncthreads();
  for (int i = tid; i < len; i += 128) {
    int lv = node_level[off + i];
    int pos = atomicAdd(&cur[lv], 1);
    tnlist[b*128 + pos] = off + i;
  }
}

// ------- tree: one block/tree; phase A register-resident; MFMA phase B ------
__global__ __launch_bounds__(512) void tree_kernel(
    const int* __restrict__ tnlist, const int* __restrict__ tlvloff,
    const int* __restrict__ tnlv,
    const int* __restrict__ choff, const int* __restrict__ chlist,
    const ushort* __restrict__ UTbf,
    const float* __restrict__ biou, const float* __restrict__ buf_,
    const float* __restrict__ iou,
    float* __restrict__ um, float* __restrict__ fm,
    float* __restrict__ hout)
{
  const int b = blockIdx.x;
  const int tid = threadIdx.x;
  const int nlv = tnlv[b];
  const int* __restrict__ nl = tnlist + b*128;
  const int* __restrict__ lo = tlvloff + b*130;
  __shared__ ushort hl[16][264];
  __shared__ float  cl[16][260];
  __shared__ int    nid[16];
  const int j5 = tid >> 5, lane5 = tid & 31;
  const int wave = tid >> 6, lane = tid & 63;
  const int fr16 = lane & 15, khalf = lane >> 4;
  for (int l = 0; l < nlv; l++) {
    const int na = lo[l], ne = lo[l+1];
    for (int g0 = na; g0 < ne; g0 += 16) {
      __syncthreads();
      const int n = (g0 + j5 < ne) ? nl[g0 + j5] : -1;
      if (lane5 == 0) nid[j5] = n;
      if (n >= 0) {
        f32x4 a[8];
#pragma unroll
        for (int q = 0; q < 8; q++) {
          const int d = (q*32 + lane5) << 2;
          if (d < GG3) a[q] = *(const f32x4*)&iou[(size_t)n*GG3 + d];
          else         a[q] = (f32x4){0.f, 0.f, 0.f, 0.f};
        }
        const int e0 = choff[n], e1 = choff[n+1];
        for (int eb = e0; eb < e1; eb += 4) {
          int ch4[4];
#pragma unroll
          for (int i = 0; i < 4; i++) ch4[i] = (eb + i < e1) ? chlist[eb + i] : -1;
#pragma unroll
          for (int i = 0; i < 4; i++) {
            const int ch = ch4[i];
            if (ch >= 0) {
#pragma unroll
              for (int q = 0; q < 8; q++) {
                const int d = (q*32 + lane5) << 2;
                const f32x4 v = (d < GG3)
                  ? *(const f32x4*)&um[(size_t)ch*GG3 + d]
                  : *(const f32x4*)&fm[(size_t)ch*HID + (d - GG3)];
                a[q] += v;
              }
            }
          }
        }
#pragma unroll
        for (int qq = 0; qq < 2; qq++) {
#pragma unroll
          for (int i = 0; i < 4; i++) {
            const int u = qq*128 + (lane5 << 2) + i;
            const float i_ = a[qq][i]   + biou[u];
            const float o_ = a[qq+2][i] + biou[256 + u];
            const float uu = a[qq+4][i] + biou[512 + u];
            const float cv = sigf(i_)*tanh_(uu) + a[qq+6][i];
            const float hv = sigf(o_)*tanh_(cv);
            cl[j5][u] = cv;
            hl[j5][u] = f2bf(hv);
            hout[(size_t)n*HID + u] = hv;
          }
        }
      } else {
#pragma unroll
        for (int q = 0; q < 8; q++) hl[j5][(q << 5) + lane5] = 0;
      }
      __syncthreads();
      if (l == nlv - 1) continue;
      bf16x8 af[8];
#pragma unroll
      for (int ks = 0; ks < 8; ks++)
        af[ks] = *(const bf16x8*)&hl[fr16][ks*32 + (khalf << 3)];
      for (int nt = wave; nt < 64; nt += 8) {
        f32x4 dacc = {0.f, 0.f, 0.f, 0.f};
#pragma unroll
        for (int ks = 0; ks < 8; ks++) {
          const bf16x8 bfr = *(const bf16x8*)&UTbf[(size_t)(nt*16 + fr16)*HID + ks*32 + (khalf << 3)];
          dacc = __builtin_amdgcn_mfma_f32_16x16x32_bf16(af[ks], bfr, dacc, 0, 0, 0);
        }
        const int r = nt*16 + fr16;
        if (r < GG3) {
#pragma unroll
          for (int g = 0; g < 4; g++) {
            const int n2 = nid[(khalf << 2) + g];
            if (n2 >= 0) um[(size_t)n2*GG3 + r] = dacc[g];
          }
        } else {
          const int fr = r - GG3;
          const float bv = buf_[fr];
#pragma unroll
          for (int g = 0; g < 4; g++) {
            const int jj = (khalf << 2) + g;
            const int n2 = nid[jj];
            if (n2 >= 0) fm[(size_t)n2*HID + fr] = sigf(dacc[g] + bv) * cl[jj][fr];
          }
        }
      }
    }
  }
}

// ---------------- launch ------------------------------------------------------
extern "C" void kernel_launch(void* const* d_in, const int* in_sizes, int n_in,
                              void* d_out, int out_size, void* d_ws, size_t ws_size,
                              hipStream_t stream)
{
  const int*   embed_ids = (const int*)d_in[0];
  const int*   lengths   = (const int*)d_in[1];
  const int*   child_idx = (const int*)d_in[2];
  const int*   parent_idx= (const int*)d_in[3];
  const int*   tok_idx   = (const int*)d_in[4];
  const int*   node_level= (const int*)d_in[5];
  const float* emb  = (const float*)d_in[7];
  const float* wihf = (const float*)d_in[8];
  const float* whhf = (const float*)d_in[9];
  const float* bf   = (const float*)d_in[10];
  const float* wihb = (const float*)d_in[11];
  const float* whhb = (const float*)d_in[12];
  const float* bb   = (const float*)d_in[13];
  const float* Wiou = (const float*)d_in[14];
  const float* Uiou = (const float*)d_in[15];
  const float* biou = (const float*)d_in[16];
  const float* Uf   = (const float*)d_in[17];
  const float* buf_ = (const float*)d_in[18];
  const int E  = in_sizes[2];
  const int Nn = in_sizes[4];
  float* hout = (float*)d_out;

  char* w = (char*)d_ws;
  size_t off = 0;
  auto take = [&](size_t bytes) -> char* {
    char* p = w + off;
    off += (bytes + 255) & ~(size_t)255;
    return p;
  };
  int*      deg   = (int*)     take((size_t)(Nn+1)*4);     // zeroed: CSR degree/cursor
  size_t zero_end = off;
  ushort*   xh    = (ushort*)  take((size_t)8192*320*2);   // bf16, K padded
  ushort*   wtihf = (ushort*)  take((size_t)1024*320*2);
  ushort*   wtihb = (ushort*)  take((size_t)1024*320*2);
  ushort*   wiouh = (ushort*)  take((size_t)768*512*2);
  float*    xgf   = (float*)   take((size_t)8192*1024*4);
  float*    xgb   = (float*)   take((size_t)8192*1024*4);
  _Float16* wtf   = (_Float16*)take((size_t)32*1024*8*2);  // f16 [k8][g][8]
  _Float16* wtb   = (_Float16*)take((size_t)32*1024*8*2);
  float*    hsf   = (float*)   take((size_t)64*128*256*4);
  float*    hsb   = (float*)   take((size_t)64*128*256*4);
  ushort*   hxh   = (ushort*)  take((size_t)Nn*512*2);
  float*    iou   = (float*)   take((size_t)Nn*GG3*4);
  float*    um    = (float*)   take((size_t)Nn*GG3*4);
  float*    fm    = (float*)   take((size_t)Nn*HID*4);
  ushort*   UTbf  = (ushort*)  take((size_t)1024*256*2);   // bf16 row-major
  int*      tnlist= (int*)     take((size_t)64*128*4);
  int*      tlvloff=(int*)     take((size_t)64*130*4);
  int*      tnlv  = (int*)     take((size_t)64*4);
  int*      choff = (int*)     take((size_t)(Nn+1)*4);
  int*      chlist= (int*)     take((size_t)(E>0?E:1)*4);
  (void)ws_size; (void)n_in; (void)out_size;

  hipMemsetAsync(d_ws, 0, zero_end, stream);
  prep_kernel<<<1024, 256, 0, stream>>>(embed_ids, emb, xh, wihf, wtihf, wihb, wtihb,
                                        Wiou, wiouh, whhf, whhb, wtf, wtb, Uiou, Uf, UTbf);
  mfma_gemm_kernel<true><<<dim3(64, 8), 256, 0, stream>>>(xh, wtihf, bf, xgf, 8192, 1024, 10);
  mfma_gemm_kernel<true><<<dim3(64, 8), 256, 0, stream>>>(xh, wtihb, bb, xgb, 8192, 1024, 10);
  lstm_kernel<<<64, 512, 152576, stream>>>(xgf, xgb, wtf, wtb, lengths, hsf, hsb);
  gather_hx_kernel<<<(Nn*64 + 255)/256, 256, 0, stream>>>(tok_idx, hsf, hsb, hxh, Nn);
  mfma_gemm_kernel<false><<<dim3((Nn + 127)/128, 6), 256, 0, stream>>>(hxh, wiouh, nullptr, iou, Nn, GG3, 16);
  csr_kernel<<<1, 1024, 0, stream>>>(child_idx, parent_idx, choff, chlist, deg, E, Nn);
  tree_sort_kernel<<<64, 128, 0, stream>>>(lengths, node_level, tnlist, tlvloff, tnlv);
  tree_kernel<<<64, 512, 0, stream>>>(tnlist, tlvloff, tnlv, choff, chlist, UTbf,
                                      biou, buf_, iou, um, fm, hout);
}

// Round 19
// 781.546 us; speedup vs baseline: 5.3067x; 1.1619x over previous
//
#include <hip/hip_runtime.h>
#include <hip/hip_fp16.h>
#include <cstdint>
#include <cstddef>

#define TT 128
#define HID 256
#define GG4 1024
#define GG3 768

typedef _Float16 f16x2 __attribute__((ext_vector_type(2)));
typedef _Float16 f16x8 __attribute__((ext_vector_type(8)));
typedef short    bf16x8 __attribute__((ext_vector_type(8)));
typedef float    f32x4 __attribute__((ext_vector_type(4)));

union f16x8u { f16x8 v; f16x2 p[4]; uint4 q; };

__device__ __forceinline__ float sigf(float x){ return 1.f/(1.f+__expf(-x)); }
__device__ __forceinline__ float tanh_(float x){
  float cx = fminf(fmaxf(x,-15.f),15.f);
  float e = __expf(2.f*cx);
  return (e-1.f)/(e+1.f);
}

__device__ __forceinline__ float dot2(f16x2 a, f16x2 b, float c){
#if __has_builtin(__builtin_amdgcn_fdot2)
  return __builtin_amdgcn_fdot2(a, b, c, false);
#else
  return c + (float)a[0]*(float)b[0] + (float)a[1]*(float)b[1];
#endif
}

__device__ __forceinline__ ushort f2bf(float x){
  union { float f; uint32_t u; } v; v.f = x;
  uint32_t r = v.u + 0x7FFF + ((v.u >> 16) & 1);
  return (ushort)(r >> 16);
}

// ---------------- fused elementwise prep (6 segments, grid-stride) ----------
__global__ __launch_bounds__(256) void prep_kernel(
    const int* __restrict__ ids, const float* __restrict__ emb, ushort* __restrict__ xh,
    const float* __restrict__ wihf, ushort* __restrict__ wtihf,
    const float* __restrict__ wihb, ushort* __restrict__ wtihb,
    const float* __restrict__ Wiou, ushort* __restrict__ wiouh,
    const float* __restrict__ whhf, const float* __restrict__ whhb,
    _Float16* __restrict__ wtf, _Float16* __restrict__ wtb,
    const float* __restrict__ Uiou, const float* __restrict__ Uf,
    ushort* __restrict__ UTbf)
{
  for (int it = blockIdx.x*256 + threadIdx.x; it < 557056; it += gridDim.x*256) {
    if (it < 327680) {
      int m = it / 40, q = it - m*40;
      int k0 = q << 3;
      int id = ids[m];
      ushort o[8];
#pragma unroll
      for (int j = 0; j < 8; j++) {
        int k = k0 + j;
        o[j] = (k < 300) ? f2bf(emb[(size_t)id*300 + k]) : (ushort)0;
      }
      *(uint4*)&xh[(size_t)m*320 + k0] = *(uint4*)o;
    } else if (it < 409600) {
      int i2 = it - 327680;
      const float* src = wihf; ushort* dst = wtihf;
      if (i2 >= 40960) { i2 -= 40960; src = wihb; dst = wtihb; }
      int r = i2 / 40, q = i2 - r*40;
      int k0 = q << 3;
      ushort o[8];
#pragma unroll
      for (int j = 0; j < 8; j++) {
        int k = k0 + j;
        o[j] = (k < 300) ? f2bf(src[(size_t)r*300 + k]) : (ushort)0;
      }
      *(uint4*)&dst[(size_t)r*320 + k0] = *(uint4*)o;
    } else if (it < 458752) {
      int i2 = it - 409600;
      int r = i2 >> 6, k0 = (i2 & 63) << 3;
      ushort o[8];
#pragma unroll
      for (int j = 0; j < 8; j++) o[j] = f2bf(Wiou[(size_t)r*512 + k0 + j]);
      *(uint4*)&wiouh[(size_t)r*512 + k0] = *(uint4*)o;
    } else if (it < 524288) {
      int i2 = it - 458752;
      int dir = i2 >> 15, rem = i2 & 32767;
      int k8 = rem >> 10, g = rem & 1023;
      const float* w = dir ? whhb : whhf;
      _Float16*   wt = dir ? wtb  : wtf;
      f16x8 pk;
#pragma unroll
      for (int j = 0; j < 8; j++) pk[j] = (_Float16)w[(size_t)g*HID + (k8<<3) + j];
      *(f16x8*)&wt[(((size_t)k8<<10) + g) << 3] = pk;
    } else {
      int i2 = it - 524288;
      int r = i2 >> 5, c = (i2 & 31) << 3;
      const float* src = (r < GG3) ? &Uiou[(size_t)r*HID + c] : &Uf[(size_t)(r-GG3)*HID + c];
      ushort o[8];
#pragma unroll
      for (int j = 0; j < 8; j++) o[j] = f2bf(src[j]);
      *(uint4*)&UTbf[(size_t)r*HID + c] = *(uint4*)o;
    }
  }
}

// ---- fused MFMA bf16 GEMM for BOTH input projections (y<8: fwd, y>=8: bwd) -
__global__ __launch_bounds__(256) void mfma_gemm2_kernel(
    const ushort* __restrict__ A,
    const ushort* __restrict__ Btf, const ushort* __restrict__ Btb,
    const float* __restrict__ bf_, const float* __restrict__ bb_,
    float* __restrict__ Cf, float* __restrict__ Cb, int M, int N, int ksteps)
{
  constexpr int LDS_ROW = 40;
  __shared__ ushort As[128*LDS_ROW];
  __shared__ ushort Bs[128*LDS_ROW];
  const int tid = threadIdx.x;
  const int dirb = blockIdx.y >> 3;
  const ushort* __restrict__ Bt = dirb ? Btb : Btf;
  const float* __restrict__ bias = dirb ? bb_ : bf_;
  float* __restrict__ C = dirb ? Cb : Cf;
  const int m0 = blockIdx.x * 128, n0 = (blockIdx.y & 7) * 128;
  const int wave = tid >> 6, lane = tid & 63;
  const int wm = (wave >> 1) * 64, wn = (wave & 1) * 64;
  const int fr = lane & 15;
  const int fk = (lane >> 4) << 3;
  const size_t Kp = (size_t)ksteps << 5;
  const int r0_ = tid >> 2,        k0_ = (tid & 3) << 3;
  const int r1_ = (tid + 256) >> 2, k1_ = ((tid + 256) & 3) << 3;
  f32x4 acc[4][4] = {};
  {
    const uint4 av0 = *(const uint4*)&A[(size_t)(m0+r0_)*Kp + k0_];
    const uint4 av1 = *(const uint4*)&A[(size_t)(m0+r1_)*Kp + k1_];
    const uint4 bv0 = *(const uint4*)&Bt[(size_t)(n0+r0_)*Kp + k0_];
    const uint4 bv1 = *(const uint4*)&Bt[(size_t)(n0+r1_)*Kp + k1_];
    *(uint4*)&As[r0_*LDS_ROW + k0_] = av0;
    *(uint4*)&As[r1_*LDS_ROW + k1_] = av1;
    *(uint4*)&Bs[r0_*LDS_ROW + k0_] = bv0;
    *(uint4*)&Bs[r1_*LDS_ROW + k1_] = bv1;
  }
  __syncthreads();
  for (int ks = 0; ks < ksteps; ks++) {
    uint4 nav0, nav1, nbv0, nbv1;
    const bool more = (ks + 1 < ksteps);
    if (more) {
      const int kb = (ks + 1) << 5;
      nav0 = *(const uint4*)&A[(size_t)(m0+r0_)*Kp + kb + k0_];
      nav1 = *(const uint4*)&A[(size_t)(m0+r1_)*Kp + kb + k1_];
      nbv0 = *(const uint4*)&Bt[(size_t)(n0+r0_)*Kp + kb + k0_];
      nbv1 = *(const uint4*)&Bt[(size_t)(n0+r1_)*Kp + kb + k1_];
    }
    bf16x8 af[4], bfr[4];
#pragma unroll
    for (int i = 0; i < 4; i++) {
      af[i]  = *(const bf16x8*)&As[(wm + i*16 + fr)*LDS_ROW + fk];
      bfr[i] = *(const bf16x8*)&Bs[(wn + i*16 + fr)*LDS_ROW + fk];
    }
#pragma unroll
    for (int mi = 0; mi < 4; mi++)
#pragma unroll
      for (int ni = 0; ni < 4; ni++)
        acc[mi][ni] = __builtin_amdgcn_mfma_f32_16x16x32_bf16(af[mi], bfr[ni], acc[mi][ni], 0, 0, 0);
    __syncthreads();
    if (more) {
      *(uint4*)&As[r0_*LDS_ROW + k0_] = nav0;
      *(uint4*)&As[r1_*LDS_ROW + k1_] = nav1;
      *(uint4*)&Bs[r0_*LDS_ROW + k0_] = nbv0;
      *(uint4*)&Bs[r1_*LDS_ROW + k1_] = nbv1;
      __syncthreads();
    }
  }
  const int drow = (lane >> 4) << 2, dcol = lane & 15;
#pragma unroll
  for (int mi = 0; mi < 4; mi++) {
#pragma unroll
    for (int ni = 0; ni < 4; ni++) {
      const int col = n0 + wn + ni*16 + dcol;
      const float bv = bias[col];
#pragma unroll
      for (int r = 0; r < 4; r++) {
        const int row = m0 + wm + mi*16 + drow + r;
        C[(size_t)row*N + col] = acc[mi][ni][r] + bv;
      }
    }
  }
}

// ---------- MFMA bf16 GEMM (iou), double-buffered ---------------------------
__global__ __launch_bounds__(256) void mfma_gemm_kernel(
    const ushort* __restrict__ A, const ushort* __restrict__ Bt,
    float* __restrict__ C, int M, int N, int ksteps)
{
  constexpr int LDS_ROW = 40;
  __shared__ ushort As[128*LDS_ROW];
  __shared__ ushort Bs[128*LDS_ROW];
  const int tid = threadIdx.x;
  const int m0 = blockIdx.x * 128, n0 = blockIdx.y * 128;
  const int wave = tid >> 6, lane = tid & 63;
  const int wm = (wave >> 1) * 64, wn = (wave & 1) * 64;
  const int fr = lane & 15;
  const int fk = (lane >> 4) << 3;
  const size_t Kp = (size_t)ksteps << 5;
  const int r0_ = tid >> 2,        k0_ = (tid & 3) << 3;
  const int r1_ = (tid + 256) >> 2, k1_ = ((tid + 256) & 3) << 3;
  f32x4 acc[4][4] = {};
  {
    uint4 av0 = make_uint4(0,0,0,0), av1 = make_uint4(0,0,0,0);
    if (m0 + r0_ < M) av0 = *(const uint4*)&A[(size_t)(m0+r0_)*Kp + k0_];
    if (m0 + r1_ < M) av1 = *(const uint4*)&A[(size_t)(m0+r1_)*Kp + k1_];
    const uint4 bv0 = *(const uint4*)&Bt[(size_t)(n0+r0_)*Kp + k0_];
    const uint4 bv1 = *(const uint4*)&Bt[(size_t)(n0+r1_)*Kp + k1_];
    *(uint4*)&As[r0_*LDS_ROW + k0_] = av0;
    *(uint4*)&As[r1_*LDS_ROW + k1_] = av1;
    *(uint4*)&Bs[r0_*LDS_ROW + k0_] = bv0;
    *(uint4*)&Bs[r1_*LDS_ROW + k1_] = bv1;
  }
  __syncthreads();
  for (int ks = 0; ks < ksteps; ks++) {
    uint4 nav0 = make_uint4(0,0,0,0), nav1 = make_uint4(0,0,0,0);
    uint4 nbv0 = make_uint4(0,0,0,0), nbv1 = make_uint4(0,0,0,0);
    const bool more = (ks + 1 < ksteps);
    if (more) {
      const int kb = (ks + 1) << 5;
      if (m0 + r0_ < M) nav0 = *(const uint4*)&A[(size_t)(m0+r0_)*Kp + kb + k0_];
      if (m0 + r1_ < M) nav1 = *(const uint4*)&A[(size_t)(m0+r1_)*Kp + kb + k1_];
      nbv0 = *(const uint4*)&Bt[(size_t)(n0+r0_)*Kp + kb + k0_];
      nbv1 = *(const uint4*)&Bt[(size_t)(n0+r1_)*Kp + kb + k1_];
    }
    bf16x8 af[4], bfr[4];
#pragma unroll
    for (int i = 0; i < 4; i++) {
      af[i]  = *(const bf16x8*)&As[(wm + i*16 + fr)*LDS_ROW + fk];
      bfr[i] = *(const bf16x8*)&Bs[(wn + i*16 + fr)*LDS_ROW + fk];
    }
#pragma unroll
    for (int mi = 0; mi < 4; mi++)
#pragma unroll
      for (int ni = 0; ni < 4; ni++)
        acc[mi][ni] = __builtin_amdgcn_mfma_f32_16x16x32_bf16(af[mi], bfr[ni], acc[mi][ni], 0, 0, 0);
    __syncthreads();
    if (more) {
      *(uint4*)&As[r0_*LDS_ROW + k0_] = nav0;
      *(uint4*)&As[r1_*LDS_ROW + k1_] = nav1;
      *(uint4*)&Bs[r0_*LDS_ROW + k0_] = nbv0;
      *(uint4*)&Bs[r1_*LDS_ROW + k1_] = nbv1;
      __syncthreads();
    }
  }
  const int drow = (lane >> 4) << 2, dcol = lane & 15;
#pragma unroll
  for (int mi = 0; mi < 4; mi++) {
#pragma unroll
    for (int ni = 0; ni < 4; ni++) {
      const int col = n0 + wn + ni*16 + dcol;
#pragma unroll
      for (int r = 0; r < 4; r++) {
        const int row = m0 + wm + mi*16 + drow + r;
        if (row < M) C[(size_t)row*N + col] = acc[mi][ni][r];
      }
    }
  }
}

// -------- LSTM: f16 weights, 9/32 chunks in LDS, rest streamed from L2 ------
#define RCH 23            // chunks 0..22 from L2; 23..31 in LDS
__global__ __launch_bounds__(512, 2) void lstm_kernel(
    const float* __restrict__ xgf, const float* __restrict__ xgb,
    const _Float16* __restrict__ wtf, const _Float16* __restrict__ wtb,
    const int* __restrict__ lengths,
    float* __restrict__ hsf, float* __restrict__ hsb)
{
  const int b8  = blockIdx.x & 7;
  const int dir = b8 >> 2;
  const int p   = (blockIdx.x >> 3) * 4 + (b8 & 3);   // 0..31
  const int r0 = 2*p, r1 = r0 + 1;
  const float* __restrict__ xg = dir ? xgb : xgf;
  const _Float16* __restrict__ wt = dir ? wtb : wtf;
  float* __restrict__ hs = dir ? hsb : hsf;
  const int t = threadIdx.x;
  const int u = t & 255;

  extern __shared__ char smem[];
  f16x8*    wl  = (f16x8*)smem;                          // [9][2][512] = 147456 B
  _Float16* hb  = (_Float16*)(smem + 147456);            // [2][256]
  float*    exf = (float*)(smem + 147456 + 1024);
  float*    exo = exf + 512;

  uint4 wr0[RCH], wr1[RCH];
#pragma unroll
  for (int c = 0; c < RCH; c++) {
    wr0[c] = *(const uint4*)&wt[(((size_t)c << 10) + t) << 3];
    wr1[c] = *(const uint4*)&wt[(((size_t)c << 10) + t + 512) << 3];
  }
#pragma unroll
  for (int c = RCH; c < 32; c++) {
    wl[((c - RCH)*2 + 0)*512 + t] = *(const f16x8*)&wt[(((size_t)c << 10) + t) << 3];
    wl[((c - RCH)*2 + 1)*512 + t] = *(const f16x8*)&wt[(((size_t)c << 10) + t + 512) << 3];
  }
  if (t < 256) { hb[t] = (_Float16)0.f; hb[256 + t] = (_Float16)0.f; }
  __syncthreads();

  const int len0 = lengths[r0], len1 = lengths[r1];   // len0 >= len1
  float c0 = 0.f, c1 = 0.f;
  for (int s = 0; s < len0; s++) {
    const bool a1 = s < len1;
    const int t0 = dir ? (len0 - 1 - s) : s;
    const int t1 = dir ? (len1 - 1 - s) : s;
    const float* xr0 = xg + ((size_t)r0*TT + t0)*GG4;
    const float xa0 = xr0[t], xb0 = xr0[t + 512];
    float xa1 = 0.f, xb1 = 0.f;
    if (a1) {
      const float* xr1 = xg + ((size_t)r1*TT + t1)*GG4;
      xa1 = xr1[t]; xb1 = xr1[t + 512];
    }
    float aa0 = 0.f, aa1 = 0.f, ab0 = 0.f, ab1 = 0.f;
#pragma unroll
    for (int k8 = 0; k8 < 32; k8++) {
      f16x8u w0, w1, h0, h1;
      if (k8 < RCH) { w0.q = wr0[k8]; w1.q = wr1[k8]; }
      else {
        w0.v = wl[((k8 - RCH)*2 + 0)*512 + t];
        w1.v = wl[((k8 - RCH)*2 + 1)*512 + t];
      }
      h0.v = *(const f16x8*)&hb[k8 << 3];
      h1.v = *(const f16x8*)&hb[256 + (k8 << 3)];
#pragma unroll
      for (int j = 0; j < 4; j++) {
        aa0 = dot2(w0.p[j], h0.p[j], aa0);
        aa1 = dot2(w0.p[j], h1.p[j], aa1);
        ab0 = dot2(w1.p[j], h0.p[j], ab0);
        ab1 = dot2(w1.p[j], h1.p[j], ab1);
      }
    }
    if (t >= 256) {
      exf[u]       = aa0 + xa0;  exf[256 + u] = aa1 + xa1;
      exo[u]       = ab0 + xb0;  exo[256 + u] = ab1 + xb1;
    }
    __syncthreads();
    if (t < 256) {
      {
        const float ig = sigf(aa0 + xa0);
        const float gg = tanh_(ab0 + xb0);
        const float fg = sigf(exf[u]);
        const float og = sigf(exo[u]);
        c0 = fg*c0 + ig*gg;
        const float h = og*tanh_(c0);
        hb[u] = (_Float16)h;
        hs[((size_t)r0*TT + t0)*HID + u] = h;
      }
      if (a1) {
        const float ig = sigf(aa1 + xa1);
        const float gg = tanh_(ab1 + xb1);
        const float fg = sigf(exf[256 + u]);
        const float og = sigf(exo[256 + u]);
        c1 = fg*c1 + ig*gg;
        const float h = og*tanh_(c1);
        hb[256 + u] = (_Float16)h;
        hs[((size_t)r1*TT + t1)*HID + u] = h;
      }
    }
    __syncthreads();
  }
}

// ---------------- hxh = bf16 concat(h_f[tok], h_b[tok]) ---------------------
__global__ __launch_bounds__(256) void gather_hx_kernel(
    const int* __restrict__ tok, const float* __restrict__ hsf,
    const float* __restrict__ hsb, ushort* __restrict__ hxh, int Nn)
{
  int it = blockIdx.x*256 + threadIdx.x;
  if (it >= Nn*64) return;
  int n = it >> 6, q = it & 63;
  int k0 = q << 3;
  int tk = tok[n];
  int b = tk >> 7, t = tk & 127;
  const float* src = (k0 < 256) ? &hsf[((size_t)b*TT + t)*HID + k0]
                                : &hsb[((size_t)b*TT + t)*HID + (k0 - 256)];
  ushort o[8];
#pragma unroll
  for (int j = 0; j < 8; j++) o[j] = f2bf(src[j]);
  *(uint4*)&hxh[(size_t)n*512 + k0] = *(uint4*)o;
}

// ------ merged graph prep: blocks 0..63 = per-tree level sort, 64 = CSR -----
__global__ __launch_bounds__(1024) void graph_kernel(
    const int* __restrict__ lengths, const int* __restrict__ node_level,
    const int* __restrict__ child_idx, const int* __restrict__ parent_idx,
    int* __restrict__ tnlist, int* __restrict__ tlvloff, int* __restrict__ tnlv,
    int* __restrict__ choff, int* __restrict__ chlist,
    int* __restrict__ deg /* zeroed; reused as cursor */, int E, int Nn)
{
  const int tid = threadIdx.x;
  if (blockIdx.x < 64) {
    const int b = blockIdx.x;
    __shared__ int hist[130], cur[129];
    __shared__ int off_s, len_s, mx;
    if (tid == 0) {
      int o = 0;
      for (int i = 0; i < b; i++) o += lengths[i];
      off_s = o; len_s = lengths[b]; mx = 1;
    }
    for (int i = tid; i < 130; i += 1024) hist[i] = 0;
    __syncthreads();
    const int off = off_s, len = len_s;
    for (int i = tid; i < len; i += 1024) {
      int lv = node_level[off + i];
      atomicAdd(&hist[lv], 1);
      atomicMax(&mx, lv + 1);
    }
    __syncthreads();
    if (tid == 0) {
      int s = 0;
      for (int l = 0; l < 129; l++) { cur[l] = s; tlvloff[b*130 + l] = s; s += hist[l]; }
      tlvloff[b*130 + 129] = s;
      tnlv[b] = mx;
    }
    __syncthreads();
    for (int i = tid; i < len; i += 1024) {
      int lv = node_level[off + i];
      int pos = atomicAdd(&cur[lv], 1);
      tnlist[b*128 + pos] = off + i;
    }
  } else {
    __shared__ int part[1024];
    for (int e = tid; e < E; e += 1024) atomicAdd(&deg[parent_idx[e]], 1);
    __syncthreads();
    int loc[8]; int s = 0;
#pragma unroll
    for (int m = 0; m < 8; m++) {
      const int i = tid*8 + m;
      loc[m] = s;
      s += (i < Nn) ? deg[i] : 0;
    }
    part[tid] = s;
    __syncthreads();
    for (int off = 1; off < 1024; off <<= 1) {
      int v = (tid >= off) ? part[tid - off] : 0;
      __syncthreads();
      part[tid] += v;
      __syncthreads();
    }
    const int pre = (tid > 0) ? part[tid-1] : 0;
#pragma unroll
    for (int m = 0; m < 8; m++) {
      const int i = tid*8 + m;
      if (i < Nn) choff[i] = pre + loc[m];
    }
    if (tid == 1023) choff[Nn] = part[1023];
    __syncthreads();
#pragma unroll
    for (int m = 0; m < 8; m++) {
      const int i = tid*8 + m;
      if (i < Nn) deg[i] = pre + loc[m];
    }
    __syncthreads();
    for (int e = tid; e < E; e += 1024) {
      int pos = atomicAdd(&deg[parent_idx[e]], 1);
      chlist[pos] = child_idx[e];
    }
  }
}

// ------- tree: one block/tree; LEVEL-batched phase B (UTbf streamed once) ---
// dynamic LDS: hl[128][264] bf16 (67584 B) + nid[128] (512 B)
__global__ __launch_bounds__(512) void tree_kernel(
    const int* __restrict__ tnlist, const int* __restrict__ tlvloff,
    const int* __restrict__ tnlv,
    const int* __restrict__ choff, const int* __restrict__ chlist,
    const ushort* __restrict__ UTbf,
    const float* __restrict__ biou, const float* __restrict__ buf_,
    const float* __restrict__ iou,
    float* __restrict__ um, float* __restrict__ fm,
    float* __restrict__ cbuf, float* __restrict__ hout)
{
  const int b = blockIdx.x;
  const int tid = threadIdx.x;
  const int nlv = tnlv[b];
  const int* __restrict__ nl = tnlist + b*128;
  const int* __restrict__ lo = tlvloff + b*130;
  extern __shared__ char tsm[];
  ushort* hl  = (ushort*)tsm;                 // [128][264]
  int*    nid = (int*)(tsm + 128*264*2);      // [128]
  const int j5 = tid >> 5, lane5 = tid & 31;  // phase A: 32 thr/node
  const int wave = tid >> 6, lane = tid & 63; // phase B
  const int fr16 = lane & 15, khalf = lane >> 4;
  for (int l = 0; l < nlv; l++) {
    const int na = lo[l], ne = lo[l+1];
    const int nL = ne - na;
    const int mT = (nL + 15) >> 4;
    // ---- Phase A: all groups of this level ----
    for (int g0 = 0; g0 < (mT << 4); g0 += 16) {
      const int jn = g0 + j5;
      const int n = (jn < nL) ? nl[na + jn] : -1;
      if (lane5 == 0) nid[jn] = n;
      if (n >= 0) {
        f32x4 a[8];
#pragma unroll
        for (int q = 0; q < 8; q++) {
          const int d = (q*32 + lane5) << 2;
          if (d < GG3) a[q] = *(const f32x4*)&iou[(size_t)n*GG3 + d];
          else         a[q] = (f32x4){0.f, 0.f, 0.f, 0.f};
        }
        const int e0 = choff[n], e1 = choff[n+1];
        for (int eb = e0; eb < e1; eb += 4) {
          int ch4[4];
#pragma unroll
          for (int i = 0; i < 4; i++) ch4[i] = (eb + i < e1) ? chlist[eb + i] : -1;
#pragma unroll
          for (int i = 0; i < 4; i++) {
            const int ch = ch4[i];
            if (ch >= 0) {
#pragma unroll
              for (int q = 0; q < 8; q++) {
                const int d = (q*32 + lane5) << 2;
                const f32x4 v = (d < GG3)
                  ? *(const f32x4*)&um[(size_t)ch*GG3 + d]
                  : *(const f32x4*)&fm[(size_t)ch*HID + (d - GG3)];
                a[q] += v;
              }
            }
          }
        }
#pragma unroll
        for (int qq = 0; qq < 2; qq++) {
#pragma unroll
          for (int i = 0; i < 4; i++) {
            const int u = qq*128 + (lane5 << 2) + i;
            const float i_ = a[qq][i]   + biou[u];
            const float o_ = a[qq+2][i] + biou[256 + u];
            const float uu = a[qq+4][i] + biou[512 + u];
            const float cv = sigf(i_)*tanh_(uu) + a[qq+6][i];
            const float hv = sigf(o_)*tanh_(cv);
            cbuf[(size_t)n*HID + u] = cv;
            hl[jn*264 + u] = f2bf(hv);
            hout[(size_t)n*HID + u] = hv;
          }
        }
      } else {
#pragma unroll
        for (int q = 0; q < 8; q++) hl[jn*264 + (q << 5) + lane5] = 0;
      }
    }
    __syncthreads();                     // hl/nid/cbuf ready
    if (l < nlv - 1) {
      // ---- Phase B: stream UTbf ONCE; MFMA vs all m-tiles ----
      for (int nt = wave; nt < 64; nt += 8) {
        bf16x8 bfr[8];
        const int r = nt*16 + fr16;
#pragma unroll
        for (int ks = 0; ks < 8; ks++)
          bfr[ks] = *(const bf16x8*)&UTbf[(size_t)r*HID + ks*32 + (khalf << 3)];
        for (int mt = 0; mt < mT; mt++) {
          f32x4 dacc = {0.f, 0.f, 0.f, 0.f};
#pragma unroll
          for (int ks = 0; ks < 8; ks++) {
            const bf16x8 af = *(const bf16x8*)&hl[(mt*16 + fr16)*264 + ks*32 + (khalf << 3)];
            dacc = __builtin_amdgcn_mfma_f32_16x16x32_bf16(af, bfr[ks], dacc, 0, 0, 0);
          }
          if (r < GG3) {
#pragma unroll
            for (int g = 0; g < 4; g++) {
              const int n2 = nid[mt*16 + (khalf << 2) + g];
              if (n2 >= 0) um[(size_t)n2*GG3 + r] = dacc[g];
            }
          } else {
            const int fr = r - GG3;
            const float bv = buf_[fr];
#pragma unroll
            for (int g = 0; g < 4; g++) {
              const int n2 = nid[mt*16 + (khalf << 2) + g];
              if (n2 >= 0) fm[(size_t)n2*HID + fr] = sigf(dacc[g] + bv) * cbuf[(size_t)n2*HID + fr];
            }
          }
        }
      }
    }
    __syncthreads();                     // phase B done before next level's A
  }
}

// ---------------- launch ------------------------------------------------------
extern "C" void kernel_launch(void* const* d_in, const int* in_sizes, int n_in,
                              void* d_out, int out_size, void* d_ws, size_t ws_size,
                              hipStream_t stream)
{
  const int*   embed_ids = (const int*)d_in[0];
  const int*   lengths   = (const int*)d_in[1];
  const int*   child_idx = (const int*)d_in[2];
  const int*   parent_idx= (const int*)d_in[3];
  const int*   tok_idx   = (const int*)d_in[4];
  const int*   node_level= (const int*)d_in[5];
  const float* emb  = (const float*)d_in[7];
  const float* wihf = (const float*)d_in[8];
  const float* whhf = (const float*)d_in[9];
  const float* bf   = (const float*)d_in[10];
  const float* wihb = (const float*)d_in[11];
  const float* whhb = (const float*)d_in[12];
  const float* bb   = (const float*)d_in[13];
  const float* Wiou = (const float*)d_in[14];
  const float* Uiou = (const float*)d_in[15];
  const float* biou = (const float*)d_in[16];
  const float* Uf   = (const float*)d_in[17];
  const float* buf_ = (const float*)d_in[18];
  const int E  = in_sizes[2];
  const int Nn = in_sizes[4];
  float* hout = (float*)d_out;

  char* w = (char*)d_ws;
  size_t off = 0;
  auto take = [&](size_t bytes) -> char* {
    char* p = w + off;
    off += (bytes + 255) & ~(size_t)255;
    return p;
  };
  int*      deg   = (int*)     take((size_t)(Nn+1)*4);     // zeroed
  size_t zero_end = off;
  ushort*   xh    = (ushort*)  take((size_t)8192*320*2);
  ushort*   wtihf = (ushort*)  take((size_t)1024*320*2);
  ushort*   wtihb = (ushort*)  take((size_t)1024*320*2);
  ushort*   wiouh = (ushort*)  take((size_t)768*512*2);
  float*    xgf   = (float*)   take((size_t)8192*1024*4);
  float*    xgb   = (float*)   take((size_t)8192*1024*4);
  _Float16* wtf   = (_Float16*)take((size_t)32*1024*8*2);
  _Float16* wtb   = (_Float16*)take((size_t)32*1024*8*2);
  float*    hsf   = (float*)   take((size_t)64*128*256*4);
  float*    hsb   = (float*)   take((size_t)64*128*256*4);
  ushort*   hxh   = (ushort*)  take((size_t)Nn*512*2);
  float*    iou   = (float*)   take((size_t)Nn*GG3*4);
  float*    um    = (float*)   take((size_t)Nn*GG3*4);
  float*    fm    = (float*)   take((size_t)Nn*HID*4);
  float*    cbuf  = (float*)   take((size_t)Nn*HID*4);
  ushort*   UTbf  = (ushort*)  take((size_t)1024*256*2);
  int*      tnlist= (int*)     take((size_t)64*128*4);
  int*      tlvloff=(int*)     take((size_t)64*130*4);
  int*      tnlv  = (int*)     take((size_t)64*4);
  int*      choff = (int*)     take((size_t)(Nn+1)*4);
  int*      chlist= (int*)     take((size_t)(E>0?E:1)*4);
  (void)ws_size; (void)n_in; (void)out_size;

  hipMemsetAsync(d_ws, 0, zero_end, stream);
  prep_kernel<<<1024, 256, 0, stream>>>(embed_ids, emb, xh, wihf, wtihf, wihb, wtihb,
                                        Wiou, wiouh, whhf, whhb, wtf, wtb, Uiou, Uf, UTbf);
  mfma_gemm2_kernel<<<dim3(64, 16), 256, 0, stream>>>(xh, wtihf, wtihb, bf, bb, xgf, xgb, 8192, 1024, 10);
  lstm_kernel<<<64, 512, 152576, stream>>>(xgf, xgb, wtf, wtb, lengths, hsf, hsb);
  gather_hx_kernel<<<(Nn*64 + 255)/256, 256, 0, stream>>>(tok_idx, hsf, hsb, hxh, Nn);
  mfma_gemm_kernel<<<dim3((Nn + 127)/128, 6), 256, 0, stream>>>(hxh, wiouh, iou, Nn, GG3, 16);
  graph_kernel<<<65, 1024, 0, stream>>>(lengths, node_level, child_idx, parent_idx,
                                        tnlist, tlvloff, tnlv, choff, chlist, deg, E, Nn);
  tree_kernel<<<64, 512, 68096, stream>>>(tnlist, tlvloff, tnlv, choff, chlist, UTbf,
                                          biou, buf_, iou, um, fm, cbuf, hout);
}